// Round 2
// baseline (8573.042 us; speedup 1.0000x reference)
//
#include <hip/hip_runtime.h>
#include <math.h>

#define NB 32
#define NT 16
#define NH 768
#define NV 32000

// Reduced-region geometry (only rows feeding memory[:, :196, :] are computed):
// conv1 out: [32][64][34][112]   (rows 0..33 of 112)
// pool  out: [32][64][17][56]    (rows 0..16 of 56)
// conv2 out: [32][128][16][56]   (rows 0..15 of 56)
// conv3 out: [32][256][8][28]    (rows 0..7 of 28)
// conv4 out -> memory [32][196][768]  (rows 0..6 of 28)

__device__ __forceinline__ float sigmoidf_(float x) { return 1.f / (1.f + expf(-x)); }

// ---------------- BN scale/bias precompute ----------------
__global__ void bn_prep(const float* __restrict__ g, const float* __restrict__ b,
                        const float* __restrict__ m, const float* __restrict__ v,
                        float* __restrict__ scale, float* __restrict__ bias, int C) {
    int i = blockIdx.x * 256 + threadIdx.x;
    if (i < C) {
        float inv = g[i] * rsqrtf(v[i] + 1e-5f);
        scale[i] = inv;
        bias[i] = b[i] - m[i] * inv;
    }
}

// ---------------- conv1: 7x7 s2 p3 + BN + ReLU ----------------
// grid (34, 64, 32), block 128 (x = output col, 112 active)
__global__ __launch_bounds__(128) void conv1_kernel(
    const float* __restrict__ img, const float* __restrict__ w,
    const float* __restrict__ scale, const float* __restrict__ bias,
    float* __restrict__ out) {
    int x = threadIdx.x;
    if (x >= 112) return;
    int y = blockIdx.x;      // 0..33
    int co = blockIdx.y;     // 0..63
    int b = blockIdx.z;      // 0..31
    float acc = 0.f;
    for (int ci = 0; ci < 3; ++ci) {
        const float* ip = img + ((size_t)(b * 3 + ci)) * 224 * 224;
        const float* wp = w + co * 147 + ci * 49;
        #pragma unroll
        for (int ky = 0; ky < 7; ++ky) {
            int iy = 2 * y - 3 + ky;
            if ((unsigned)iy < 224u) {
                const float* row = ip + iy * 224;
                #pragma unroll
                for (int kx = 0; kx < 7; ++kx) {
                    int ix = 2 * x - 3 + kx;
                    float val = ((unsigned)ix < 224u) ? row[ix] : 0.f;
                    acc = fmaf(val, wp[ky * 7 + kx], acc);
                }
            }
        }
    }
    float r = fmaxf(acc * scale[co] + bias[co], 0.f);
    out[(((size_t)(b * 64 + co)) * 34 + y) * 112 + x] = r;
}

// ---------------- maxpool 3x3 s2 p1 ----------------
__global__ __launch_bounds__(256) void pool_kernel(const float* __restrict__ in, float* __restrict__ out) {
    int idx = blockIdx.x * 256 + threadIdx.x;
    const int total = 32 * 64 * 17 * 56;
    if (idx >= total) return;
    int x = idx % 56;
    int y = (idx / 56) % 17;
    int c = (idx / (56 * 17)) % 64;
    int b = idx / (56 * 17 * 64);
    const float* p = in + ((size_t)(b * 64 + c)) * 34 * 112;
    float m = -INFINITY;
    #pragma unroll
    for (int ky = -1; ky <= 1; ++ky) {
        int iy = 2 * y + ky;
        if ((unsigned)iy < 34u) {
            #pragma unroll
            for (int kx = -1; kx <= 1; ++kx) {
                int ix = 2 * x + kx;
                if ((unsigned)ix < 112u) m = fmaxf(m, p[iy * 112 + ix]);
            }
        }
    }
    out[idx] = m;
}

// ---------------- generic 3x3 conv + BN + ReLU ----------------
template <int CIN, int HIN, int WIN, int HOUT, int WOUT, int STRIDE, int MEMOUT>
__global__ __launch_bounds__(256) void conv3x3_kernel(
    const float* __restrict__ in, const float* __restrict__ w,
    const float* __restrict__ scale, const float* __restrict__ bias,
    float* __restrict__ out, int COUT) {
    int idx = blockIdx.x * 256 + threadIdx.x;
    int total = 32 * COUT * HOUT * WOUT;
    if (idx >= total) return;
    int x = idx % WOUT;
    int y = (idx / WOUT) % HOUT;
    int co = (idx / (WOUT * HOUT)) % COUT;
    int b = idx / (WOUT * HOUT * COUT);
    int iy0 = STRIDE * y - 1;
    int ix0 = STRIDE * x - 1;
    float acc = 0.f;
    const float* wbase = w + (size_t)co * CIN * 9;
    const float* ibase = in + (size_t)b * CIN * HIN * WIN;
    for (int ci = 0; ci < CIN; ++ci) {
        const float* ip = ibase + (size_t)ci * HIN * WIN;
        const float* wp = wbase + ci * 9;
        #pragma unroll
        for (int ky = 0; ky < 3; ++ky) {
            int iy = iy0 + ky;
            if ((unsigned)iy < (unsigned)HIN) {
                const float* row = ip + iy * WIN;
                #pragma unroll
                for (int kx = 0; kx < 3; ++kx) {
                    int ix = ix0 + kx;
                    float val = ((unsigned)ix < (unsigned)WIN) ? row[ix] : 0.f;
                    acc = fmaf(val, wp[ky * 3 + kx], acc);
                }
            }
        }
    }
    float r = fmaxf(acc * scale[co] + bias[co], 0.f);
    if (MEMOUT) {
        // memory layout [b][m][768], m = y*WOUT + x  (WOUT=28, HOUT=7 -> m<196)
        out[((size_t)b * (HOUT * WOUT) + y * WOUT + x) * (size_t)COUT + co] = r;
    } else {
        out[idx] = r;
    }
}

// ---------------- embedding gather: e512[r][k], r = t*32+b ----------------
__global__ __launch_bounds__(256) void gather_emb(const int* __restrict__ caps,
                                                  const float* __restrict__ table,
                                                  float* __restrict__ e512) {
    int idx = blockIdx.x * 256 + threadIdx.x;  // 512*768
    int k = idx % NH;
    int r = idx / NH;
    int t = r >> 5;
    int b = r & 31;
    e512[idx] = table[(size_t)caps[b * NT + t] * NH + k];
}

// ---------------- tiled f32 GEMM: C[m][n] = sum_k A[m][k]*B[n][k] + bias ----------------
// block 256, tile 64x64, BK=16. M = gridDim.y*64 (exact), N = gridDim.x*64 (exact), K % 16 == 0.
template <int REMAP>
__global__ __launch_bounds__(256) void gemm_abt(
    const float* __restrict__ A, const float* __restrict__ B,
    const float* __restrict__ bias1, const float* __restrict__ bias2,
    float* __restrict__ C, int lda, int ldb, int N, int K) {
    __shared__ float As[16][68];
    __shared__ float Bs[16][68];
    int tid = threadIdx.x;
    int n0 = blockIdx.x * 64, m0 = blockIdx.y * 64;
    int lk = tid & 15, lr = tid >> 4;
    int ty = tid >> 4, tx = tid & 15;
    float acc[4][4] = {};
    for (int k0 = 0; k0 < K; k0 += 16) {
        #pragma unroll
        for (int it = 0; it < 4; ++it) {
            As[lk][lr + 16 * it] = A[(size_t)(m0 + lr + 16 * it) * lda + k0 + lk];
            Bs[lk][lr + 16 * it] = B[(size_t)(n0 + lr + 16 * it) * ldb + k0 + lk];
        }
        __syncthreads();
        #pragma unroll
        for (int kk = 0; kk < 16; ++kk) {
            float4 a = *(const float4*)&As[kk][ty * 4];
            float4 bv = *(const float4*)&Bs[kk][tx * 4];
            acc[0][0] = fmaf(a.x, bv.x, acc[0][0]);
            acc[0][1] = fmaf(a.x, bv.y, acc[0][1]);
            acc[0][2] = fmaf(a.x, bv.z, acc[0][2]);
            acc[0][3] = fmaf(a.x, bv.w, acc[0][3]);
            acc[1][0] = fmaf(a.y, bv.x, acc[1][0]);
            acc[1][1] = fmaf(a.y, bv.y, acc[1][1]);
            acc[1][2] = fmaf(a.y, bv.z, acc[1][2]);
            acc[1][3] = fmaf(a.y, bv.w, acc[1][3]);
            acc[2][0] = fmaf(a.z, bv.x, acc[2][0]);
            acc[2][1] = fmaf(a.z, bv.y, acc[2][1]);
            acc[2][2] = fmaf(a.z, bv.z, acc[2][2]);
            acc[2][3] = fmaf(a.z, bv.w, acc[2][3]);
            acc[3][0] = fmaf(a.w, bv.x, acc[3][0]);
            acc[3][1] = fmaf(a.w, bv.y, acc[3][1]);
            acc[3][2] = fmaf(a.w, bv.z, acc[3][2]);
            acc[3][3] = fmaf(a.w, bv.w, acc[3][3]);
        }
        __syncthreads();
    }
    #pragma unroll
    for (int i = 0; i < 4; ++i) {
        int m = m0 + ty * 4 + i;
        #pragma unroll
        for (int j = 0; j < 4; ++j) {
            int n = n0 + tx * 4 + j;
            float v = acc[i][j];
            if (bias1) v += bias1[n];
            if (bias2) v += bias2[n];
            if (REMAP) {  // A row r = t*32+b -> logits[(b*16+t)*NV + n]
                int t = m >> 5, b = m & 31;
                C[(size_t)((b << 4) + t) * NV + n] = v;
            } else {
                C[(size_t)m * N + n] = v;
            }
        }
    }
}

// ---------------- attention step: q = h@Wt, scores, softmax, ctx ----------------
// grid 32 (batch), block 768
__global__ __launch_bounds__(768) void attn_step(
    const float* __restrict__ h, const float* __restrict__ attn_w,
    const float* __restrict__ mem, float* __restrict__ ctx) {
    __shared__ float q[NH];
    __shared__ float p[196];
    __shared__ float red[16];
    int b = blockIdx.x, tid = threadIdx.x;
    const float4* h4 = (const float4*)(h + (size_t)b * NH);
    {
        const float4* w4 = (const float4*)(attn_w + (size_t)tid * NH);
        float acc = 0.f;
        #pragma unroll 4
        for (int k = 0; k < NH / 4; ++k) {
            float4 a = h4[k], w = w4[k];
            acc += a.x * w.x + a.y * w.y + a.z * w.z + a.w * w.w;
        }
        q[tid] = acc;
    }
    __syncthreads();
    float sc = -INFINITY;
    if (tid < 196) {
        const float4* m4 = (const float4*)(mem + ((size_t)b * 196 + tid) * NH);
        const float4* q4 = (const float4*)q;
        float acc = 0.f;
        #pragma unroll 4
        for (int k = 0; k < NH / 4; ++k) {
            float4 a = q4[k], w = m4[k];
            acc += a.x * w.x + a.y * w.y + a.z * w.z + a.w * w.w;
        }
        sc = acc;
    }
    // block max
    float v = sc;
    #pragma unroll
    for (int off = 32; off; off >>= 1) v = fmaxf(v, __shfl_down(v, off));
    if ((tid & 63) == 0) red[tid >> 6] = v;
    __syncthreads();
    if (tid == 0) {
        float m = red[0];
        for (int i = 1; i < 12; ++i) m = fmaxf(m, red[i]);
        red[12] = m;
    }
    __syncthreads();
    float mx = red[12];
    float e = (tid < 196) ? expf(sc - mx) : 0.f;
    __syncthreads();
    // block sum
    v = e;
    #pragma unroll
    for (int off = 32; off; off >>= 1) v += __shfl_down(v, off);
    if ((tid & 63) == 0) red[tid >> 6] = v;
    __syncthreads();
    if (tid == 0) {
        float s = red[0];
        for (int i = 1; i < 12; ++i) s += red[i];
        red[12] = 1.f / s;
    }
    __syncthreads();
    if (tid < 196) p[tid] = e * red[12];
    __syncthreads();
    {
        float acc = 0.f;
        const float* mbase = mem + (size_t)b * 196 * NH + tid;
        #pragma unroll 4
        for (int m = 0; m < 196; ++m) acc = fmaf(p[m], mbase[(size_t)m * NH], acc);
        ctx[(size_t)b * NH + tid] = acc;
    }
}

// ---------------- gate matvecs: gates = eg_t + ctx@w_ih[:,768:].T + h@w_hh.T ----------------
// grid (12, 32), block 256 -> thread per (b, j)
__global__ __launch_bounds__(256) void step_gates(
    const float* __restrict__ ctx, const float* __restrict__ h,
    const float* __restrict__ w_ih, const float* __restrict__ w_hh,
    const float* __restrict__ eg_t, float* __restrict__ gates) {
    int j = blockIdx.x * 256 + threadIdx.x;  // 0..3071
    int b = blockIdx.y;
    const float4* c4 = (const float4*)(ctx + (size_t)b * NH);
    const float4* h4 = (const float4*)(h + (size_t)b * NH);
    const float4* wi = (const float4*)(w_ih + (size_t)j * (2 * NH) + NH);
    const float4* wh = (const float4*)(w_hh + (size_t)j * NH);
    float acc = eg_t[(size_t)b * 3072 + j];
    float acc2 = 0.f;
    #pragma unroll 4
    for (int k = 0; k < NH / 4; ++k) {
        float4 a = c4[k], w = wi[k];
        acc += a.x * w.x + a.y * w.y + a.z * w.z + a.w * w.w;
        float4 a2 = h4[k], w2 = wh[k];
        acc2 += a2.x * w2.x + a2.y * w2.y + a2.z * w2.z + a2.w * w2.w;
    }
    gates[(size_t)b * 3072 + j] = acc + acc2;
}

// ---------------- LSTM cell pointwise ----------------
__global__ __launch_bounds__(256) void step_cell(
    const float* __restrict__ gates, float* __restrict__ h, float* __restrict__ c,
    float* __restrict__ hall_t) {
    int idx = blockIdx.x * 256 + threadIdx.x;
    if (idx >= NB * NH) return;
    int b = idx / NH;
    int k = idx % NH;
    const float* g = gates + (size_t)b * 3072;
    float gi = g[k], gf = g[NH + k], gg = g[2 * NH + k], go = g[3 * NH + k];
    float cn = sigmoidf_(gf) * c[idx] + sigmoidf_(gi) * tanhf(gg);
    float hn = sigmoidf_(go) * tanhf(cn);
    c[idx] = cn;
    h[idx] = hn;
    hall_t[idx] = hn;
}

__global__ __launch_bounds__(256) void zero_hc(float* __restrict__ h, float* __restrict__ c) {
    int i = blockIdx.x * 256 + threadIdx.x;
    if (i < NB * NH) { h[i] = 0.f; c[i] = 0.f; }
}

__global__ __launch_bounds__(256) void copy_hc(const float* __restrict__ h, const float* __restrict__ c,
                                               float* __restrict__ out) {
    int i = blockIdx.x * 256 + threadIdx.x;
    if (i < NB * NH) {
        out[(size_t)NB * NT * NV + i] = h[i];
        out[(size_t)NB * NT * NV + NB * NH + i] = c[i];
    }
}

extern "C" void kernel_launch(void* const* d_in, const int* in_sizes, int n_in,
                              void* d_out, int out_size, void* d_ws, size_t ws_size,
                              hipStream_t stream) {
    const float* images   = (const float*)d_in[0];
    const int*   captions = (const int*)d_in[1];
    const float* conv1_w  = (const float*)d_in[2];
    const float* bn1_g = (const float*)d_in[3], *bn1_b = (const float*)d_in[4];
    const float* bn1_m = (const float*)d_in[5], *bn1_v = (const float*)d_in[6];
    const float* conv2_w  = (const float*)d_in[7];
    const float* bn2_g = (const float*)d_in[8], *bn2_b = (const float*)d_in[9];
    const float* bn2_m = (const float*)d_in[10], *bn2_v = (const float*)d_in[11];
    const float* conv3_w  = (const float*)d_in[12];
    const float* bn3_g = (const float*)d_in[13], *bn3_b = (const float*)d_in[14];
    const float* bn3_m = (const float*)d_in[15], *bn3_v = (const float*)d_in[16];
    const float* conv4_w  = (const float*)d_in[17];
    const float* bn4_g = (const float*)d_in[18], *bn4_b = (const float*)d_in[19];
    const float* bn4_m = (const float*)d_in[20], *bn4_v = (const float*)d_in[21];
    const float* emb_table = (const float*)d_in[22];
    const float* attn_w   = (const float*)d_in[23];
    const float* w_ih     = (const float*)d_in[24];
    const float* w_hh     = (const float*)d_in[25];
    const float* b_ih     = (const float*)d_in[26];
    const float* b_hh     = (const float*)d_in[27];
    const float* fc_w     = (const float*)d_in[28];
    const float* fc_b     = (const float*)d_in[29];
    float* out = (float*)d_out;

    // ---- workspace layout (floats) ----
    float* ws = (float*)d_ws;
    size_t off = 0;
    auto alloc = [&](size_t n) { float* p = ws + off; off += (n + 63) & ~(size_t)63; return p; };
    float* s1 = alloc(64);  float* bb1 = alloc(64);
    float* s2 = alloc(128); float* bb2 = alloc(128);
    float* s3 = alloc(256); float* bb3 = alloc(256);
    float* s4 = alloc(768); float* bb4 = alloc(768);
    float* x1   = alloc(32 * 64 * 34 * 112);   // conv1 out; reused for conv2 out
    float* xp   = alloc(32 * 64 * 17 * 56);    // pool out; reused for conv3 out
    float* memv = alloc((size_t)32 * 196 * 768);
    float* e512 = alloc(512 * 768);
    float* eg   = alloc((size_t)512 * 3072);
    float* Hall = alloc(512 * 768);
    float* hbuf = alloc(NB * NH);
    float* cbuf = alloc(NB * NH);
    float* ctx  = alloc(NB * NH);
    float* gates = alloc(NB * 3072);
    float* x2 = x1;  // conv2 out (x1 dead after pool)
    float* x3 = xp;  // conv3 out (xp dead after conv2)

    // ---- BN params ----
    bn_prep<<<1, 256, 0, stream>>>(bn1_g, bn1_b, bn1_m, bn1_v, s1, bb1, 64);
    bn_prep<<<1, 256, 0, stream>>>(bn2_g, bn2_b, bn2_m, bn2_v, s2, bb2, 128);
    bn_prep<<<1, 256, 0, stream>>>(bn3_g, bn3_b, bn3_m, bn3_v, s3, bb3, 256);
    bn_prep<<<3, 256, 0, stream>>>(bn4_g, bn4_b, bn4_m, bn4_v, s4, bb4, 768);

    // ---- encoder (reduced region) ----
    conv1_kernel<<<dim3(34, 64, 32), 128, 0, stream>>>(images, conv1_w, s1, bb1, x1);
    pool_kernel<<<(32 * 64 * 17 * 56 + 255) / 256, 256, 0, stream>>>(x1, xp);
    conv3x3_kernel<64, 17, 56, 16, 56, 1, 0>
        <<<(32 * 128 * 16 * 56 + 255) / 256, 256, 0, stream>>>(xp, conv2_w, s2, bb2, x2, 128);
    conv3x3_kernel<128, 16, 56, 8, 28, 2, 0>
        <<<(32 * 256 * 8 * 28 + 255) / 256, 256, 0, stream>>>(x2, conv3_w, s3, bb3, x3, 256);
    conv3x3_kernel<256, 8, 28, 7, 28, 1, 1>
        <<<(32 * 768 * 7 * 28 + 255) / 256, 256, 0, stream>>>(x3, conv4_w, s4, bb4, memv, 768);

    // ---- decoder precompute ----
    gather_emb<<<(512 * 768) / 256, 256, 0, stream>>>(captions, emb_table, e512);
    // eg[r][j] = e512[r] . w_ih[j][0:768] + b_ih[j] + b_hh[j]
    gemm_abt<0><<<dim3(3072 / 64, 512 / 64), 256, 0, stream>>>(
        e512, w_ih, b_ih, b_hh, eg, NH, 2 * NH, 3072, NH);
    zero_hc<<<(NB * NH + 255) / 256, 256, 0, stream>>>(hbuf, cbuf);

    // ---- sequential decoder ----
    for (int t = 0; t < NT; ++t) {
        attn_step<<<NB, NH, 0, stream>>>(hbuf, attn_w, memv, ctx);
        step_gates<<<dim3(3072 / 256, NB), 256, 0, stream>>>(
            ctx, hbuf, w_ih, w_hh, eg + (size_t)t * NB * 3072, gates);
        step_cell<<<(NB * NH + 255) / 256, 256, 0, stream>>>(
            gates, hbuf, cbuf, Hall + (size_t)t * NB * NH);
    }

    // ---- vocab projection for all 16 steps at once ----
    gemm_abt<1><<<dim3(NV / 64, 512 / 64), 256, 0, stream>>>(
        Hall, fc_w, fc_b, nullptr, out, NH, NH, NV, NH);

    copy_hc<<<(NB * NH + 255) / 256, 256, 0, stream>>>(hbuf, cbuf, out);
}

// Round 3
// 3538.766 us; speedup vs baseline: 2.4226x; 2.4226x over previous
//
#include <hip/hip_runtime.h>
#include <math.h>

#define NB 32
#define NT 16
#define NH 768
#define NV 32000

typedef short bf16x8 __attribute__((ext_vector_type(8)));
typedef float floatx4 __attribute__((ext_vector_type(4)));
typedef unsigned short ushort_t;

__device__ __forceinline__ float bf2f(unsigned short h) {
    unsigned u = ((unsigned)h) << 16;
    return __builtin_bit_cast(float, u);
}
__device__ __forceinline__ unsigned short f2bf(float f) {
    unsigned u = __builtin_bit_cast(unsigned, f);
    u += 0x7fffu + ((u >> 16) & 1u);
    return (unsigned short)(u >> 16);
}
__device__ __forceinline__ float sigmoidf_(float x) { return 1.f / (1.f + expf(-x)); }

// ---------------- BN scale/bias precompute ----------------
__global__ void bn_prep(const float* __restrict__ g, const float* __restrict__ b,
                        const float* __restrict__ m, const float* __restrict__ v,
                        float* __restrict__ scale, float* __restrict__ bias, int C) {
    int i = blockIdx.x * 256 + threadIdx.x;
    if (i < C) {
        float inv = g[i] * rsqrtf(v[i] + 1e-5f);
        scale[i] = inv;
        bias[i] = b[i] - m[i] * inv;
    }
}

// ---------------- zero fill (halo borders) ----------------
__global__ __launch_bounds__(256) void zfill(unsigned long long* __restrict__ p, long long n) {
    long long i = (long long)blockIdx.x * 256 + threadIdx.x;
    if (i < n) p[i] = 0ULL;
}

// ---------------- conv weight transform: OIHW f32 -> [co][tap][ci] bf16 ----------------
__global__ __launch_bounds__(256) void cvt_w3x3(const float* __restrict__ w, ushort_t* __restrict__ wb,
                                                int CIN, int total) {
    int idx = blockIdx.x * 256 + threadIdx.x;
    if (idx >= total) return;
    int ci = idx % CIN;
    int t = (idx / CIN) % 9;
    int co = idx / (CIN * 9);
    wb[idx] = f2bf(w[((size_t)co * CIN + ci) * 9 + t]);
}

// ---------------- generic strided f32 -> bf16 row convert ----------------
__global__ __launch_bounds__(256) void cvt_rows(const float* __restrict__ src, ushort_t* __restrict__ dst,
                                                int cols, int ld, int srcoff, int total) {
    int idx = blockIdx.x * 256 + threadIdx.x;
    if (idx >= total) return;
    int r = idx / cols, c = idx % cols;
    dst[idx] = f2bf(src[(size_t)r * ld + srcoff + c]);
}

// ---------------- conv1: 7x7 s2 p3 + BN + ReLU, weights in LDS, NHWC bf16 out ----------------
// block 256 = 64 co x 4 x; grid (28, 34, 32)
__global__ __launch_bounds__(256) void conv1_kernel(
    const float* __restrict__ img, const float* __restrict__ w,
    const float* __restrict__ scale, const float* __restrict__ bias,
    ushort_t* __restrict__ out) {
    __shared__ float wlds[64 * 147];
    int tid = threadIdx.x;
    for (int i = tid; i < 64 * 147; i += 256) wlds[i] = w[i];
    __syncthreads();
    int co = tid & 63, xq = tid >> 6;
    int x = blockIdx.x * 4 + xq;      // 0..111
    int y = blockIdx.y;               // 0..33
    int b = blockIdx.z;
    const float* wp = wlds + co * 147;
    float acc = 0.f;
    for (int ci = 0; ci < 3; ++ci) {
        const float* ip = img + ((size_t)(b * 3 + ci)) * 224 * 224;
        #pragma unroll
        for (int ky = 0; ky < 7; ++ky) {
            int iy = 2 * y - 3 + ky;
            if ((unsigned)iy < 224u) {
                const float* row = ip + iy * 224;
                #pragma unroll
                for (int kx = 0; kx < 7; ++kx) {
                    int ix = 2 * x - 3 + kx;
                    float val = ((unsigned)ix < 224u) ? row[ix] : 0.f;
                    acc = fmaf(val, wp[ci * 49 + ky * 7 + kx], acc);
                }
            }
        }
    }
    float r = fmaxf(acc * scale[co] + bias[co], 0.f);
    out[(((size_t)(b * 34 + y)) * 112 + x) * 64 + co] = f2bf(r);
}

// ---------------- maxpool 3x3 s2 p1: NHWC bf16 -> halo'd NHWC bf16 ----------------
__global__ __launch_bounds__(256) void pool_kernel(const ushort_t* __restrict__ in,
                                                   ushort_t* __restrict__ hal2) {
    int idx = blockIdx.x * 256 + threadIdx.x;
    const int total = 32 * 17 * 56 * 8;
    if (idx >= total) return;
    int c8 = idx & 7;
    int rest = idx >> 3;
    int x = rest % 56; rest /= 56;
    int y = rest % 17; int b = rest / 17;
    float mx[8];
    #pragma unroll
    for (int j = 0; j < 8; ++j) mx[j] = -INFINITY;
    for (int dy = -1; dy <= 1; ++dy) {
        int iy = 2 * y + dy;
        if ((unsigned)iy >= 34u) continue;
        for (int dx = -1; dx <= 1; ++dx) {
            int ix = 2 * x + dx;
            if ((unsigned)ix >= 112u) continue;
            bf16x8 v = *(const bf16x8*)(in + (((size_t)(b * 34 + iy)) * 112 + ix) * 64 + c8 * 8);
            #pragma unroll
            for (int j = 0; j < 8; ++j) mx[j] = fmaxf(mx[j], bf2f((unsigned short)v[j]));
        }
    }
    bf16x8 o;
    #pragma unroll
    for (int j = 0; j < 8; ++j) o[j] = (short)f2bf(mx[j]);
    *(bf16x8*)(hal2 + (((size_t)(b * 19 + y + 1)) * 58 + (x + 1)) * 64 + c8 * 8) = o;
}

// ---------------- implicit-GEMM 3x3 conv via MFMA ----------------
// in: NHWC bf16 halo'd [32][HH][WH][CIN]; wt: [COUT][9][CIN] bf16.
// One wave per 64x64 (M x N) tile. M = 32*HOUT*WOUT, grid(M/64, COUT/64), block 64.
template <int CIN, int HH, int WH, int STRIDE, int HOUT, int WOUT, int COUT, int MEMOUT, int OH, int OW>
__global__ __launch_bounds__(64) void conv_mfma(
    const ushort_t* __restrict__ in, const ushort_t* __restrict__ wt,
    const float* __restrict__ scale, const float* __restrict__ bias,
    ushort_t* __restrict__ out) {
    int lane = threadIdx.x;
    int mt = blockIdx.x, nt = blockIdx.y;
    int lr = lane & 15, kl = (lane >> 4) * 8;
    int rowoff[4];
    #pragma unroll
    for (int i = 0; i < 4; ++i) {
        int m = mt * 64 + 16 * i + lr;
        int b = m / (HOUT * WOUT);
        int rm = m % (HOUT * WOUT);
        int y = rm / WOUT, x = rm % WOUT;
        rowoff[i] = ((b * HH + y * STRIDE) * WH + x * STRIDE) * CIN + kl;
    }
    floatx4 acc[4][4];
    #pragma unroll
    for (int i = 0; i < 4; ++i)
        #pragma unroll
        for (int j = 0; j < 4; ++j) acc[i][j] = 0.f;

    #pragma unroll
    for (int ky = 0; ky < 3; ++ky) {
        #pragma unroll
        for (int kx = 0; kx < 3; ++kx) {
            int ioff = (ky * WH + kx) * CIN;
            int t = ky * 3 + kx;
            #pragma unroll
            for (int k0 = 0; k0 < CIN; k0 += 32) {
                bf16x8 a[4], bb[4];
                #pragma unroll
                for (int i = 0; i < 4; ++i)
                    a[i] = *(const bf16x8*)(in + rowoff[i] + ioff + k0);
                #pragma unroll
                for (int j = 0; j < 4; ++j)
                    bb[j] = *(const bf16x8*)(wt + ((size_t)(nt * 64 + 16 * j + lr) * 9 + t) * CIN + kl + k0);
                #pragma unroll
                for (int i = 0; i < 4; ++i)
                    #pragma unroll
                    for (int j = 0; j < 4; ++j)
                        acc[i][j] = __builtin_amdgcn_mfma_f32_16x16x32_bf16(a[i], bb[j], acc[i][j], 0, 0, 0);
            }
        }
    }
    // epilogue: BN + ReLU, store bf16
    #pragma unroll
    for (int i = 0; i < 4; ++i) {
        #pragma unroll
        for (int r = 0; r < 4; ++r) {
            int m = mt * 64 + 16 * i + (lane >> 4) * 4 + r;
            int b = m / (HOUT * WOUT);
            int rm = m % (HOUT * WOUT);
            int y = rm / WOUT, x = rm % WOUT;
            #pragma unroll
            for (int j = 0; j < 4; ++j) {
                int n = nt * 64 + 16 * j + lr;
                float v = fmaxf(acc[i][j][r] * scale[n] + bias[n], 0.f);
                if (MEMOUT) {
                    out[(size_t)m * COUT + n] = f2bf(v);   // memory [b][196][768]
                } else {
                    out[((size_t)(b * OH + y + 1) * OW + (x + 1)) * COUT + n] = f2bf(v);
                }
            }
        }
    }
}

// ---------------- embedding gather -> bf16, rows r = t*32+b ----------------
__global__ __launch_bounds__(256) void gather_emb(const int* __restrict__ caps,
                                                  const float* __restrict__ table,
                                                  ushort_t* __restrict__ e512) {
    int idx = blockIdx.x * 256 + threadIdx.x;  // 512*768
    int k = idx % NH;
    int r = idx / NH;
    int t = r >> 5;
    int b = r & 31;
    e512[idx] = f2bf(table[(size_t)caps[b * NT + t] * NH + k]);
}

// ---------------- MFMA GEMM: C[m][n] = A_bf16[m][k] . bf16(B_f32[n][k]) + bias ----------------
// block 256 = 4 waves, each wave a 64x64 tile; grid(N/64, M/256). K % 32 == 0.
template <int REMAP>
__global__ __launch_bounds__(256) void gemm_mfma(
    const ushort_t* __restrict__ A, const float* __restrict__ B,
    const float* __restrict__ bias1, const float* __restrict__ bias2,
    float* __restrict__ C, int lda, int ldb, int N, int K) {
    int lane = threadIdx.x & 63, w = threadIdx.x >> 6;
    int m0 = (blockIdx.y * 4 + w) * 64, n0 = blockIdx.x * 64;
    int lr = lane & 15, kl = (lane >> 4) * 8;
    const ushort_t* ap[4];
    const float* bp[4];
    #pragma unroll
    for (int i = 0; i < 4; ++i) ap[i] = A + (size_t)(m0 + 16 * i + lr) * lda + kl;
    #pragma unroll
    for (int j = 0; j < 4; ++j) bp[j] = B + (size_t)(n0 + 16 * j + lr) * ldb + kl;
    floatx4 acc[4][4];
    #pragma unroll
    for (int i = 0; i < 4; ++i)
        #pragma unroll
        for (int j = 0; j < 4; ++j) acc[i][j] = 0.f;

    for (int k0 = 0; k0 < K; k0 += 32) {
        bf16x8 a[4], bb[4];
        #pragma unroll
        for (int i = 0; i < 4; ++i) a[i] = *(const bf16x8*)(ap[i] + k0);
        #pragma unroll
        for (int j = 0; j < 4; ++j) {
            float4 x0 = *(const float4*)(bp[j] + k0);
            float4 x1 = *(const float4*)(bp[j] + k0 + 4);
            bf16x8 t;
            t[0] = (short)f2bf(x0.x); t[1] = (short)f2bf(x0.y);
            t[2] = (short)f2bf(x0.z); t[3] = (short)f2bf(x0.w);
            t[4] = (short)f2bf(x1.x); t[5] = (short)f2bf(x1.y);
            t[6] = (short)f2bf(x1.z); t[7] = (short)f2bf(x1.w);
            bb[j] = t;
        }
        #pragma unroll
        for (int i = 0; i < 4; ++i)
            #pragma unroll
            for (int j = 0; j < 4; ++j)
                acc[i][j] = __builtin_amdgcn_mfma_f32_16x16x32_bf16(a[i], bb[j], acc[i][j], 0, 0, 0);
    }
    #pragma unroll
    for (int i = 0; i < 4; ++i) {
        #pragma unroll
        for (int r = 0; r < 4; ++r) {
            int m = m0 + 16 * i + (lane >> 4) * 4 + r;
            #pragma unroll
            for (int j = 0; j < 4; ++j) {
                int n = n0 + 16 * j + lr;
                float v = acc[i][j][r];
                if (bias1) v += bias1[n];
                if (bias2) v += bias2[n];
                if (REMAP) {  // A row m = t*32+b -> out[(b*16+t)*N + n]
                    int t = m >> 5, b = m & 31;
                    C[(size_t)((b << 4) + t) * N + n] = v;
                } else {
                    C[(size_t)m * N + n] = v;
                }
            }
        }
    }
}

// ---------------- attention step (f32 math, bf16 memory) ----------------
__global__ __launch_bounds__(768) void attn_step(
    const float* __restrict__ h, const float* __restrict__ attn_w,
    const ushort_t* __restrict__ mem, float* __restrict__ ctx) {
    __shared__ float q[NH];
    __shared__ float p[196];
    __shared__ float red[16];
    int b = blockIdx.x, tid = threadIdx.x;
    const float4* h4 = (const float4*)(h + (size_t)b * NH);
    {
        const float4* w4 = (const float4*)(attn_w + (size_t)tid * NH);
        float acc = 0.f;
        #pragma unroll 4
        for (int k = 0; k < NH / 4; ++k) {
            float4 a = h4[k], w = w4[k];
            acc += a.x * w.x + a.y * w.y + a.z * w.z + a.w * w.w;
        }
        q[tid] = acc;
    }
    __syncthreads();
    float sc = -INFINITY;
    if (tid < 196) {
        const bf16x8* m8 = (const bf16x8*)(mem + ((size_t)b * 196 + tid) * NH);
        float acc = 0.f;
        #pragma unroll 4
        for (int k8 = 0; k8 < NH / 8; ++k8) {
            bf16x8 v = m8[k8];
            #pragma unroll
            for (int j = 0; j < 8; ++j) acc = fmaf(bf2f((unsigned short)v[j]), q[k8 * 8 + j], acc);
        }
        sc = acc;
    }
    float v = sc;
    #pragma unroll
    for (int off = 32; off; off >>= 1) v = fmaxf(v, __shfl_down(v, off));
    if ((tid & 63) == 0) red[tid >> 6] = v;
    __syncthreads();
    if (tid == 0) {
        float m = red[0];
        for (int i = 1; i < 12; ++i) m = fmaxf(m, red[i]);
        red[12] = m;
    }
    __syncthreads();
    float mx = red[12];
    float e = (tid < 196) ? expf(sc - mx) : 0.f;
    __syncthreads();
    v = e;
    #pragma unroll
    for (int off = 32; off; off >>= 1) v += __shfl_down(v, off);
    if ((tid & 63) == 0) red[tid >> 6] = v;
    __syncthreads();
    if (tid == 0) {
        float s = red[0];
        for (int i = 1; i < 12; ++i) s += red[i];
        red[12] = 1.f / s;
    }
    __syncthreads();
    if (tid < 196) p[tid] = e * red[12];
    __syncthreads();
    {
        float acc = 0.f;
        const ushort_t* mb = mem + (size_t)b * 196 * NH + tid;
        #pragma unroll 4
        for (int m = 0; m < 196; ++m) acc = fmaf(p[m], bf2f(mb[(size_t)m * NH]), acc);
        ctx[(size_t)b * NH + tid] = acc;
    }
}

// ---------------- gate matvecs (bf16 weights) ----------------
__global__ __launch_bounds__(256) void step_gates(
    const float* __restrict__ ctx, const float* __restrict__ h,
    const ushort_t* __restrict__ wi_bf, const ushort_t* __restrict__ wh_bf,
    const float* __restrict__ eg_t, float* __restrict__ gates) {
    int j = blockIdx.x * 256 + threadIdx.x;  // 0..3071
    int b = blockIdx.y;
    const float4* c4 = (const float4*)(ctx + (size_t)b * NH);
    const float4* h4 = (const float4*)(h + (size_t)b * NH);
    const bf16x8* wi = (const bf16x8*)(wi_bf + (size_t)j * NH);
    const bf16x8* wh = (const bf16x8*)(wh_bf + (size_t)j * NH);
    float acc = eg_t[(size_t)b * 3072 + j];
    float acc2 = 0.f;
    #pragma unroll 4
    for (int k8 = 0; k8 < NH / 8; ++k8) {
        float4 a0 = c4[k8 * 2], a1 = c4[k8 * 2 + 1];
        bf16x8 wv = wi[k8];
        acc = fmaf(a0.x, bf2f((unsigned short)wv[0]), acc);
        acc = fmaf(a0.y, bf2f((unsigned short)wv[1]), acc);
        acc = fmaf(a0.z, bf2f((unsigned short)wv[2]), acc);
        acc = fmaf(a0.w, bf2f((unsigned short)wv[3]), acc);
        acc = fmaf(a1.x, bf2f((unsigned short)wv[4]), acc);
        acc = fmaf(a1.y, bf2f((unsigned short)wv[5]), acc);
        acc = fmaf(a1.z, bf2f((unsigned short)wv[6]), acc);
        acc = fmaf(a1.w, bf2f((unsigned short)wv[7]), acc);
        float4 b0 = h4[k8 * 2], b1 = h4[k8 * 2 + 1];
        bf16x8 wv2 = wh[k8];
        acc2 = fmaf(b0.x, bf2f((unsigned short)wv2[0]), acc2);
        acc2 = fmaf(b0.y, bf2f((unsigned short)wv2[1]), acc2);
        acc2 = fmaf(b0.z, bf2f((unsigned short)wv2[2]), acc2);
        acc2 = fmaf(b0.w, bf2f((unsigned short)wv2[3]), acc2);
        acc2 = fmaf(b1.x, bf2f((unsigned short)wv2[4]), acc2);
        acc2 = fmaf(b1.y, bf2f((unsigned short)wv2[5]), acc2);
        acc2 = fmaf(b1.z, bf2f((unsigned short)wv2[6]), acc2);
        acc2 = fmaf(b1.w, bf2f((unsigned short)wv2[7]), acc2);
    }
    gates[(size_t)b * 3072 + j] = acc + acc2;
}

// ---------------- LSTM cell pointwise ----------------
__global__ __launch_bounds__(256) void step_cell(
    const float* __restrict__ gates, float* __restrict__ h, float* __restrict__ c,
    ushort_t* __restrict__ hall_t) {
    int idx = blockIdx.x * 256 + threadIdx.x;
    if (idx >= NB * NH) return;
    int b = idx / NH;
    int k = idx % NH;
    const float* g = gates + (size_t)b * 3072;
    float gi = g[k], gf = g[NH + k], gg = g[2 * NH + k], go = g[3 * NH + k];
    float cn = sigmoidf_(gf) * c[idx] + sigmoidf_(gi) * tanhf(gg);
    float hn = sigmoidf_(go) * tanhf(cn);
    c[idx] = cn;
    h[idx] = hn;
    hall_t[idx] = f2bf(hn);
}

__global__ __launch_bounds__(256) void zero_hc(float* __restrict__ h, float* __restrict__ c) {
    int i = blockIdx.x * 256 + threadIdx.x;
    if (i < NB * NH) { h[i] = 0.f; c[i] = 0.f; }
}

__global__ __launch_bounds__(256) void copy_hc(const float* __restrict__ h, const float* __restrict__ c,
                                               float* __restrict__ out) {
    int i = blockIdx.x * 256 + threadIdx.x;
    if (i < NB * NH) {
        out[(size_t)NB * NT * NV + i] = h[i];
        out[(size_t)NB * NT * NV + NB * NH + i] = c[i];
    }
}

extern "C" void kernel_launch(void* const* d_in, const int* in_sizes, int n_in,
                              void* d_out, int out_size, void* d_ws, size_t ws_size,
                              hipStream_t stream) {
    const float* images   = (const float*)d_in[0];
    const int*   captions = (const int*)d_in[1];
    const float* conv1_w  = (const float*)d_in[2];
    const float* bn1_g = (const float*)d_in[3], *bn1_b = (const float*)d_in[4];
    const float* bn1_m = (const float*)d_in[5], *bn1_v = (const float*)d_in[6];
    const float* conv2_w  = (const float*)d_in[7];
    const float* bn2_g = (const float*)d_in[8], *bn2_b = (const float*)d_in[9];
    const float* bn2_m = (const float*)d_in[10], *bn2_v = (const float*)d_in[11];
    const float* conv3_w  = (const float*)d_in[12];
    const float* bn3_g = (const float*)d_in[13], *bn3_b = (const float*)d_in[14];
    const float* bn3_m = (const float*)d_in[15], *bn3_v = (const float*)d_in[16];
    const float* conv4_w  = (const float*)d_in[17];
    const float* bn4_g = (const float*)d_in[18], *bn4_b = (const float*)d_in[19];
    const float* bn4_m = (const float*)d_in[20], *bn4_v = (const float*)d_in[21];
    const float* emb_table = (const float*)d_in[22];
    const float* attn_w   = (const float*)d_in[23];
    const float* w_ih     = (const float*)d_in[24];
    const float* w_hh     = (const float*)d_in[25];
    const float* b_ih     = (const float*)d_in[26];
    const float* b_hh     = (const float*)d_in[27];
    const float* fc_w     = (const float*)d_in[28];
    const float* fc_b     = (const float*)d_in[29];
    float* out = (float*)d_out;

    // ---- workspace layout (bytes, 256B aligned) ----
    char* base = (char*)d_ws;
    size_t off = 0;
    auto alloc = [&](size_t bytes) { char* p = base + off; off += (bytes + 255) & ~(size_t)255; return p; };
    float* s1 = (float*)alloc(64 * 4);   float* bb1 = (float*)alloc(64 * 4);
    float* s2 = (float*)alloc(128 * 4);  float* bb2 = (float*)alloc(128 * 4);
    float* s3 = (float*)alloc(256 * 4);  float* bb3 = (float*)alloc(256 * 4);
    float* s4 = (float*)alloc(768 * 4);  float* bb4 = (float*)alloc(768 * 4);
    ushort_t* c1out = (ushort_t*)alloc((size_t)32 * 34 * 112 * 64 * 2);
    size_t halo_start = off;
    ushort_t* hal2 = (ushort_t*)alloc((size_t)32 * 19 * 58 * 64 * 2);
    ushort_t* hal3 = (ushort_t*)alloc((size_t)32 * 18 * 58 * 128 * 2);
    ushort_t* hal4 = (ushort_t*)alloc((size_t)32 * 10 * 30 * 256 * 2);
    size_t halo_bytes = off - halo_start;
    ushort_t* memv = (ushort_t*)alloc((size_t)32 * 196 * 768 * 2);
    ushort_t* wb2 = (ushort_t*)alloc((size_t)128 * 9 * 64 * 2);
    ushort_t* wb3 = (ushort_t*)alloc((size_t)256 * 9 * 128 * 2);
    ushort_t* wb4 = (ushort_t*)alloc((size_t)768 * 9 * 256 * 2);
    ushort_t* wih2 = (ushort_t*)alloc((size_t)3072 * 768 * 2);
    ushort_t* whhb = (ushort_t*)alloc((size_t)3072 * 768 * 2);
    ushort_t* e512 = (ushort_t*)alloc((size_t)512 * 768 * 2);
    float* eg   = (float*)alloc((size_t)512 * 3072 * 4);
    ushort_t* Hall = (ushort_t*)alloc((size_t)512 * 768 * 2);
    float* hbuf = (float*)alloc(NB * NH * 4);
    float* cbuf = (float*)alloc(NB * NH * 4);
    float* ctx  = (float*)alloc(NB * NH * 4);
    float* gates = (float*)alloc((size_t)NB * 3072 * 4);

    // ---- one-time transforms ----
    bn_prep<<<1, 256, 0, stream>>>(bn1_g, bn1_b, bn1_m, bn1_v, s1, bb1, 64);
    bn_prep<<<1, 256, 0, stream>>>(bn2_g, bn2_b, bn2_m, bn2_v, s2, bb2, 128);
    bn_prep<<<1, 256, 0, stream>>>(bn3_g, bn3_b, bn3_m, bn3_v, s3, bb3, 256);
    bn_prep<<<3, 256, 0, stream>>>(bn4_g, bn4_b, bn4_m, bn4_v, s4, bb4, 768);
    cvt_w3x3<<<(128 * 9 * 64 + 255) / 256, 256, 0, stream>>>(conv2_w, wb2, 64, 128 * 9 * 64);
    cvt_w3x3<<<(256 * 9 * 128 + 255) / 256, 256, 0, stream>>>(conv3_w, wb3, 128, 256 * 9 * 128);
    cvt_w3x3<<<(768 * 9 * 256 + 255) / 256, 256, 0, stream>>>(conv4_w, wb4, 256, 768 * 9 * 256);
    cvt_rows<<<(3072 * 768 + 255) / 256, 256, 0, stream>>>(w_ih, wih2, 768, 1536, 768, 3072 * 768);
    cvt_rows<<<(3072 * 768 + 255) / 256, 256, 0, stream>>>(w_hh, whhb, 768, 768, 0, 3072 * 768);
    {
        long long n8 = (long long)(halo_bytes / 8);
        zfill<<<(unsigned)((n8 + 255) / 256), 256, 0, stream>>>((unsigned long long*)hal2, n8);
    }

    // ---- encoder ----
    conv1_kernel<<<dim3(28, 34, 32), 256, 0, stream>>>(images, conv1_w, s1, bb1, c1out);
    pool_kernel<<<(32 * 17 * 56 * 8 + 255) / 256, 256, 0, stream>>>(c1out, hal2);
    conv_mfma<64, 19, 58, 1, 16, 56, 128, 0, 18, 58>
        <<<dim3(448, 2), 64, 0, stream>>>(hal2, wb2, s2, bb2, hal3);
    conv_mfma<128, 18, 58, 2, 8, 28, 256, 0, 10, 30>
        <<<dim3(112, 4), 64, 0, stream>>>(hal3, wb3, s3, bb3, hal4);
    conv_mfma<256, 10, 30, 1, 7, 28, 768, 1, 1, 1>
        <<<dim3(98, 12), 64, 0, stream>>>(hal4, wb4, s4, bb4, memv);

    // ---- decoder precompute ----
    gather_emb<<<(512 * 768) / 256, 256, 0, stream>>>(captions, emb_table, e512);
    gemm_mfma<0><<<dim3(3072 / 64, 2), 256, 0, stream>>>(
        e512, w_ih, b_ih, b_hh, eg, NH, 2 * NH, 3072, NH);
    zero_hc<<<(NB * NH + 255) / 256, 256, 0, stream>>>(hbuf, cbuf);

    // ---- sequential decoder ----
    for (int t = 0; t < NT; ++t) {
        attn_step<<<NB, NH, 0, stream>>>(hbuf, attn_w, memv, ctx);
        step_gates<<<dim3(3072 / 256, NB), 256, 0, stream>>>(
            ctx, hbuf, wih2, whhb, eg + (size_t)t * NB * 3072, gates);
        step_cell<<<(NB * NH + 255) / 256, 256, 0, stream>>>(
            gates, hbuf, cbuf, Hall + (size_t)t * NB * NH);
    }

    // ---- vocab projection for all 16 steps at once ----
    gemm_mfma<1><<<dim3(NV / 64, 2), 256, 0, stream>>>(
        Hall, fc_w, fc_b, nullptr, out, NH, NH, NV, NH);

    copy_hc<<<(NB * NH + 255) / 256, 256, 0, stream>>>(hbuf, cbuf, out);
}

// Round 4
// 1957.758 us; speedup vs baseline: 4.3790x; 1.8076x over previous
//
#include <hip/hip_runtime.h>
#include <math.h>

#define NB 32
#define NT 16
#define NH 768
#define NV 32000

typedef short bf16x8 __attribute__((ext_vector_type(8)));
typedef float floatx4 __attribute__((ext_vector_type(4)));
typedef unsigned short ushort_t;

__device__ __forceinline__ float bf2f(unsigned short h) {
    unsigned u = ((unsigned)h) << 16;
    return __builtin_bit_cast(float, u);
}
__device__ __forceinline__ unsigned short f2bf(float f) {
    unsigned u = __builtin_bit_cast(unsigned, f);
    u += 0x7fffu + ((u >> 16) & 1u);
    return (unsigned short)(u >> 16);
}
__device__ __forceinline__ float sigmoidf_(float x) { return 1.f / (1.f + expf(-x)); }

// ---------------- BN scale/bias precompute ----------------
__global__ void bn_prep(const float* __restrict__ g, const float* __restrict__ b,
                        const float* __restrict__ m, const float* __restrict__ v,
                        float* __restrict__ scale, float* __restrict__ bias, int C) {
    int i = blockIdx.x * 256 + threadIdx.x;
    if (i < C) {
        float inv = g[i] * rsqrtf(v[i] + 1e-5f);
        scale[i] = inv;
        bias[i] = b[i] - m[i] * inv;
    }
}

// ---------------- zero fill ----------------
__global__ __launch_bounds__(256) void zfill(unsigned long long* __restrict__ p, long long n) {
    long long i = (long long)blockIdx.x * 256 + threadIdx.x;
    if (i < n) p[i] = 0ULL;
}

// ---------------- conv weight transform: OIHW f32 -> [co][tap][ci] bf16 ----------------
__global__ __launch_bounds__(256) void cvt_w3x3(const float* __restrict__ w, ushort_t* __restrict__ wb,
                                                int CIN, int total) {
    int idx = blockIdx.x * 256 + threadIdx.x;
    if (idx >= total) return;
    int ci = idx % CIN;
    int t = (idx / CIN) % 9;
    int co = idx / (CIN * 9);
    wb[idx] = f2bf(w[((size_t)co * CIN + ci) * 9 + t]);
}

// ---------------- strided f32 -> bf16 row convert ----------------
__global__ __launch_bounds__(256) void cvt_rows(const float* __restrict__ src, ushort_t* __restrict__ dst,
                                                int cols, int ld, int srcoff, int total) {
    int idx = blockIdx.x * 256 + threadIdx.x;
    if (idx >= total) return;
    int r = idx / cols, c = idx % cols;
    dst[idx] = f2bf(src[(size_t)r * ld + srcoff + c]);
}

// ---------------- wcomb[j][k]: k<768 -> w_ih[j][768+k] (ctx), k>=768 -> w_hh[j][k-768] (h) ----------------
__global__ __launch_bounds__(256) void cvt_wcomb(const float* __restrict__ w_ih, const float* __restrict__ w_hh,
                                                 ushort_t* __restrict__ dst) {
    int idx = blockIdx.x * 256 + threadIdx.x;  // 3072*1536
    if (idx >= 3072 * 1536) return;
    int j = idx / 1536, k = idx % 1536;
    float v = (k < NH) ? w_ih[(size_t)j * (2 * NH) + NH + k] : w_hh[(size_t)j * NH + (k - NH)];
    dst[idx] = f2bf(v);
}

// ---------------- conv1 weights: [64][147] f32 -> [64][160] bf16 (zero pad) ----------------
__global__ __launch_bounds__(256) void cvt_pad(const float* __restrict__ src, ushort_t* __restrict__ dst) {
    int idx = blockIdx.x * 256 + threadIdx.x;  // 64*160
    if (idx >= 64 * 160) return;
    int co = idx / 160, k = idx % 160;
    dst[idx] = (k < 147) ? f2bf(src[co * 147 + k]) : (ushort_t)0;
}

// ---------------- conv1 im2col: [121856][160] bf16, k = ci*49+ky*7+kx ----------------
__global__ __launch_bounds__(256) void im2col1(const float* __restrict__ img, ushort_t* __restrict__ A) {
    int idx = blockIdx.x * 256 + threadIdx.x;
    const int total = 121856 * 160;
    if (idx >= total) return;
    int k = idx % 160;
    int m = idx / 160;
    ushort_t v = 0;
    if (k < 147) {
        int b = m / 3808;
        int rm = m % 3808;
        int y = rm / 112, x = rm % 112;
        int ci = k / 49;
        int r = k % 49;
        int ky = r / 7, kx = r % 7;
        int iy = 2 * y - 3 + ky;
        int ix = 2 * x - 3 + kx;
        if ((unsigned)iy < 224u && (unsigned)ix < 224u)
            v = f2bf(img[((size_t)(b * 3 + ci) * 224 + iy) * 224 + ix]);
    }
    A[idx] = v;
}

// ---------------- conv1 GEMM: [121856][160] x [64][160]^T, BN+ReLU, NHWC bf16 out ----------------
// grid 476 blocks x 4 waves; wave = one 64-row m-tile, n = all 64 co.
__global__ __launch_bounds__(256) void conv1_gemm(
    const ushort_t* __restrict__ A, const ushort_t* __restrict__ Bw,
    const float* __restrict__ scale, const float* __restrict__ bias,
    ushort_t* __restrict__ out) {
    int lane = threadIdx.x & 63, w = threadIdx.x >> 6;
    int m0 = (blockIdx.x * 4 + w) * 64;
    int lr = lane & 15, kl = (lane >> 4) * 8;
    floatx4 acc[4][4];
    #pragma unroll
    for (int i = 0; i < 4; ++i)
        #pragma unroll
        for (int j = 0; j < 4; ++j) acc[i][j] = 0.f;
    #pragma unroll
    for (int k0 = 0; k0 < 160; k0 += 32) {
        bf16x8 a[4], bb[4];
        #pragma unroll
        for (int i = 0; i < 4; ++i) a[i] = *(const bf16x8*)(A + (size_t)(m0 + 16 * i + lr) * 160 + kl + k0);
        #pragma unroll
        for (int j = 0; j < 4; ++j) bb[j] = *(const bf16x8*)(Bw + (size_t)(16 * j + lr) * 160 + kl + k0);
        #pragma unroll
        for (int i = 0; i < 4; ++i)
            #pragma unroll
            for (int j = 0; j < 4; ++j)
                acc[i][j] = __builtin_amdgcn_mfma_f32_16x16x32_bf16(a[i], bb[j], acc[i][j], 0, 0, 0);
    }
    #pragma unroll
    for (int i = 0; i < 4; ++i) {
        #pragma unroll
        for (int r = 0; r < 4; ++r) {
            int m = m0 + 16 * i + (lane >> 4) * 4 + r;
            int b = m / 3808;
            int rm = m % 3808;
            int y = rm / 112, x = rm % 112;
            #pragma unroll
            for (int j = 0; j < 4; ++j) {
                int n = 16 * j + lr;
                float v = fmaxf(acc[i][j][r] * scale[n] + bias[n], 0.f);
                out[((size_t)(b * 34 + y) * 112 + x) * 64 + n] = f2bf(v);
            }
        }
    }
}

// ---------------- maxpool 3x3 s2 p1: NHWC bf16 -> halo'd NHWC bf16 ----------------
__global__ __launch_bounds__(256) void pool_kernel(const ushort_t* __restrict__ in,
                                                   ushort_t* __restrict__ hal2) {
    int idx = blockIdx.x * 256 + threadIdx.x;
    const int total = 32 * 17 * 56 * 8;
    if (idx >= total) return;
    int c8 = idx & 7;
    int rest = idx >> 3;
    int x = rest % 56; rest /= 56;
    int y = rest % 17; int b = rest / 17;
    float mx[8];
    #pragma unroll
    for (int j = 0; j < 8; ++j) mx[j] = -INFINITY;
    for (int dy = -1; dy <= 1; ++dy) {
        int iy = 2 * y + dy;
        if ((unsigned)iy >= 34u) continue;
        for (int dx = -1; dx <= 1; ++dx) {
            int ix = 2 * x + dx;
            if ((unsigned)ix >= 112u) continue;
            bf16x8 v = *(const bf16x8*)(in + (((size_t)(b * 34 + iy)) * 112 + ix) * 64 + c8 * 8);
            #pragma unroll
            for (int j = 0; j < 8; ++j) mx[j] = fmaxf(mx[j], bf2f((unsigned short)v[j]));
        }
    }
    bf16x8 o;
    #pragma unroll
    for (int j = 0; j < 8; ++j) o[j] = (short)f2bf(mx[j]);
    *(bf16x8*)(hal2 + (((size_t)(b * 19 + y + 1)) * 58 + (x + 1)) * 64 + c8 * 8) = o;
}

// ---------------- implicit-GEMM 3x3 conv via MFMA (halo'd NHWC in) ----------------
template <int CIN, int HH, int WH, int STRIDE, int HOUT, int WOUT, int COUT, int MEMOUT, int OH, int OW>
__global__ __launch_bounds__(64) void conv_mfma(
    const ushort_t* __restrict__ in, const ushort_t* __restrict__ wt,
    const float* __restrict__ scale, const float* __restrict__ bias,
    ushort_t* __restrict__ out) {
    int lane = threadIdx.x;
    int mt = blockIdx.x, nt = blockIdx.y;
    int lr = lane & 15, kl = (lane >> 4) * 8;
    int rowoff[4];
    #pragma unroll
    for (int i = 0; i < 4; ++i) {
        int m = mt * 64 + 16 * i + lr;
        int b = m / (HOUT * WOUT);
        int rm = m % (HOUT * WOUT);
        int y = rm / WOUT, x = rm % WOUT;
        rowoff[i] = ((b * HH + y * STRIDE) * WH + x * STRIDE) * CIN + kl;
    }
    floatx4 acc[4][4];
    #pragma unroll
    for (int i = 0; i < 4; ++i)
        #pragma unroll
        for (int j = 0; j < 4; ++j) acc[i][j] = 0.f;

    #pragma unroll
    for (int ky = 0; ky < 3; ++ky) {
        #pragma unroll
        for (int kx = 0; kx < 3; ++kx) {
            int ioff = (ky * WH + kx) * CIN;
            int t = ky * 3 + kx;
            #pragma unroll
            for (int k0 = 0; k0 < CIN; k0 += 32) {
                bf16x8 a[4], bb[4];
                #pragma unroll
                for (int i = 0; i < 4; ++i)
                    a[i] = *(const bf16x8*)(in + rowoff[i] + ioff + k0);
                #pragma unroll
                for (int j = 0; j < 4; ++j)
                    bb[j] = *(const bf16x8*)(wt + ((size_t)(nt * 64 + 16 * j + lr) * 9 + t) * CIN + kl + k0);
                #pragma unroll
                for (int i = 0; i < 4; ++i)
                    #pragma unroll
                    for (int j = 0; j < 4; ++j)
                        acc[i][j] = __builtin_amdgcn_mfma_f32_16x16x32_bf16(a[i], bb[j], acc[i][j], 0, 0, 0);
            }
        }
    }
    #pragma unroll
    for (int i = 0; i < 4; ++i) {
        #pragma unroll
        for (int r = 0; r < 4; ++r) {
            int m = mt * 64 + 16 * i + (lane >> 4) * 4 + r;
            int b = m / (HOUT * WOUT);
            int rm = m % (HOUT * WOUT);
            int y = rm / WOUT, x = rm % WOUT;
            #pragma unroll
            for (int j = 0; j < 4; ++j) {
                int n = nt * 64 + 16 * j + lr;
                float v = fmaxf(acc[i][j][r] * scale[n] + bias[n], 0.f);
                if (MEMOUT) {
                    out[(size_t)m * COUT + n] = f2bf(v);   // memory [b][196][768]
                } else {
                    out[((size_t)(b * OH + y + 1) * OW + (x + 1)) * COUT + n] = f2bf(v);
                }
            }
        }
    }
}

// ---------------- embedding gather -> bf16, rows r = t*32+b ----------------
__global__ __launch_bounds__(256) void gather_emb(const int* __restrict__ caps,
                                                  const float* __restrict__ table,
                                                  ushort_t* __restrict__ e512) {
    int idx = blockIdx.x * 256 + threadIdx.x;  // 512*768
    int k = idx % NH;
    int r = idx / NH;
    int t = r >> 5;
    int b = r & 31;
    e512[idx] = f2bf(table[(size_t)caps[b * NT + t] * NH + k]);
}

// ---------------- MFMA GEMM, both operands bf16: C = A . B^T + bias ----------------
// block 256 = 4 waves, each wave a 64x64 tile; grid(N/64, M/256). K % 32 == 0.
template <int REMAP>
__global__ __launch_bounds__(256) void gemm_bf16(
    const ushort_t* __restrict__ A, const ushort_t* __restrict__ B,
    const float* __restrict__ bias1, const float* __restrict__ bias2,
    float* __restrict__ C, int lda, int ldb, int N, int K) {
    int lane = threadIdx.x & 63, w = threadIdx.x >> 6;
    int m0 = (blockIdx.y * 4 + w) * 64, n0 = blockIdx.x * 64;
    int lr = lane & 15, kl = (lane >> 4) * 8;
    floatx4 acc[4][4];
    #pragma unroll
    for (int i = 0; i < 4; ++i)
        #pragma unroll
        for (int j = 0; j < 4; ++j) acc[i][j] = 0.f;
    for (int k0 = 0; k0 < K; k0 += 32) {
        bf16x8 a[4], bb[4];
        #pragma unroll
        for (int i = 0; i < 4; ++i) a[i] = *(const bf16x8*)(A + (size_t)(m0 + 16 * i + lr) * lda + kl + k0);
        #pragma unroll
        for (int j = 0; j < 4; ++j) bb[j] = *(const bf16x8*)(B + (size_t)(n0 + 16 * j + lr) * ldb + kl + k0);
        #pragma unroll
        for (int i = 0; i < 4; ++i)
            #pragma unroll
            for (int j = 0; j < 4; ++j)
                acc[i][j] = __builtin_amdgcn_mfma_f32_16x16x32_bf16(a[i], bb[j], acc[i][j], 0, 0, 0);
    }
    #pragma unroll
    for (int i = 0; i < 4; ++i) {
        #pragma unroll
        for (int r = 0; r < 4; ++r) {
            int m = m0 + 16 * i + (lane >> 4) * 4 + r;
            #pragma unroll
            for (int j = 0; j < 4; ++j) {
                int n = n0 + 16 * j + lr;
                float v = acc[i][j][r];
                if (bias1) v += bias1[n];
                if (bias2) v += bias2[n];
                if (REMAP) {  // A row m = t*32+b -> out[(b*16+t)*N + n]
                    int t = m >> 5, b = m & 31;
                    C[(size_t)((b << 4) + t) * N + n] = v;
                } else {
                    C[(size_t)m * N + n] = v;
                }
            }
        }
    }
}

// ---------------- fused attention: q = h@Wt, scores, softmax, ctx -> xin[:,0:768] bf16 ----------------
// grid 32 (batch), block 768. xin = [ctx | h] bf16 [32][1536].
__global__ __launch_bounds__(768) void attn_fused(
    ushort_t* __restrict__ xin, const ushort_t* __restrict__ wattn,
    const ushort_t* __restrict__ mem) {
    __shared__ float q[NH];
    __shared__ float sl[196];
    __shared__ float red[16];
    int b = blockIdx.x, tid = threadIdx.x;
    // phase 1: q[tid] = h . wattn[tid]
    {
        const bf16x8* h8 = (const bf16x8*)(xin + (size_t)b * 1536 + NH);
        const bf16x8* w8 = (const bf16x8*)(wattn + (size_t)tid * NH);
        float acc = 0.f;
        #pragma unroll 4
        for (int k8 = 0; k8 < NH / 8; ++k8) {
            bf16x8 a = h8[k8], w = w8[k8];
            #pragma unroll
            for (int j = 0; j < 8; ++j)
                acc = fmaf(bf2f((unsigned short)a[j]), bf2f((unsigned short)w[j]), acc);
        }
        q[tid] = acc;
    }
    __syncthreads();
    // phase 2: scores, 2 threads per m (K split 384/384), shuffle combine
    if (tid < 392) {
        int m = tid >> 1, half = tid & 1;
        const bf16x8* m8 = (const bf16x8*)(mem + ((size_t)b * 196 + m) * NH + half * 384);
        const float* qp = q + half * 384;
        float acc = 0.f;
        #pragma unroll 4
        for (int k8 = 0; k8 < 48; ++k8) {
            bf16x8 v = m8[k8];
            #pragma unroll
            for (int j = 0; j < 8; ++j)
                acc = fmaf(bf2f((unsigned short)v[j]), qp[k8 * 8 + j], acc);
        }
        acc += __shfl_xor(acc, 1);
        if (!half) sl[m] = acc;
    }
    __syncthreads();
    // phase 3: softmax over 196
    float sc = (tid < 196) ? sl[tid] : -INFINITY;
    float v = sc;
    #pragma unroll
    for (int off = 32; off; off >>= 1) v = fmaxf(v, __shfl_down(v, off));
    if ((tid & 63) == 0) red[tid >> 6] = v;
    __syncthreads();
    if (tid == 0) {
        float m = red[0];
        for (int i = 1; i < 12; ++i) m = fmaxf(m, red[i]);
        red[12] = m;
    }
    __syncthreads();
    float mx = red[12];
    float e = (tid < 196) ? expf(sc - mx) : 0.f;
    __syncthreads();
    v = e;
    #pragma unroll
    for (int off = 32; off; off >>= 1) v += __shfl_down(v, off);
    if ((tid & 63) == 0) red[tid >> 6] = v;
    __syncthreads();
    if (tid == 0) {
        float s = red[0];
        for (int i = 1; i < 12; ++i) s += red[i];
        red[12] = 1.f / s;
    }
    __syncthreads();
    if (tid < 196) sl[tid] = e * red[12];
    __syncthreads();
    // phase 4: ctx[tid] = sum_m p[m]*mem[b][m][tid] -> xin ctx half
    {
        float acc = 0.f;
        const ushort_t* mb = mem + (size_t)b * 196 * NH + tid;
        #pragma unroll 4
        for (int m = 0; m < 196; ++m) acc = fmaf(sl[m], bf2f(mb[(size_t)m * NH]), acc);
        xin[(size_t)b * 1536 + tid] = f2bf(acc);
    }
}

// ---------------- gates MFMA: gates[32][3072] = xin[32][1536] . wcomb^T + eg_t ----------------
// grid 12 blocks x 4 waves; wave: n-tile 64, m = 32 (2 m-frags), K = 1536.
__global__ __launch_bounds__(256) void gates_mfma(
    const ushort_t* __restrict__ xin, const ushort_t* __restrict__ wcomb,
    const float* __restrict__ eg_t, float* __restrict__ gates) {
    int lane = threadIdx.x & 63, w = threadIdx.x >> 6;
    int n0 = blockIdx.x * 256 + w * 64;
    int lr = lane & 15, kl = (lane >> 4) * 8;
    floatx4 acc[2][4];
    #pragma unroll
    for (int i = 0; i < 2; ++i)
        #pragma unroll
        for (int j = 0; j < 4; ++j) acc[i][j] = 0.f;
    for (int k0 = 0; k0 < 1536; k0 += 32) {
        bf16x8 a[2], bb[4];
        #pragma unroll
        for (int i = 0; i < 2; ++i) a[i] = *(const bf16x8*)(xin + (size_t)(16 * i + lr) * 1536 + kl + k0);
        #pragma unroll
        for (int j = 0; j < 4; ++j) bb[j] = *(const bf16x8*)(wcomb + (size_t)(n0 + 16 * j + lr) * 1536 + kl + k0);
        #pragma unroll
        for (int i = 0; i < 2; ++i)
            #pragma unroll
            for (int j = 0; j < 4; ++j)
                acc[i][j] = __builtin_amdgcn_mfma_f32_16x16x32_bf16(a[i], bb[j], acc[i][j], 0, 0, 0);
    }
    #pragma unroll
    for (int i = 0; i < 2; ++i) {
        #pragma unroll
        for (int r = 0; r < 4; ++r) {
            int m = 16 * i + (lane >> 4) * 4 + r;   // = b index, 0..31
            #pragma unroll
            for (int j = 0; j < 4; ++j) {
                int n = n0 + 16 * j + lr;
                gates[(size_t)m * 3072 + n] = acc[i][j][r] + eg_t[(size_t)m * 3072 + n];
            }
        }
    }
}

// ---------------- LSTM cell pointwise ----------------
__global__ __launch_bounds__(256) void step_cell(
    const float* __restrict__ gates, float* __restrict__ h, float* __restrict__ c,
    ushort_t* __restrict__ xin, ushort_t* __restrict__ hall_t) {
    int idx = blockIdx.x * 256 + threadIdx.x;
    if (idx >= NB * NH) return;
    int b = idx / NH;
    int k = idx % NH;
    const float* g = gates + (size_t)b * 3072;
    float gi = g[k], gf = g[NH + k], gg = g[2 * NH + k], go = g[3 * NH + k];
    float cn = sigmoidf_(gf) * c[idx] + sigmoidf_(gi) * tanhf(gg);
    float hn = sigmoidf_(go) * tanhf(cn);
    c[idx] = cn;
    h[idx] = hn;
    ushort_t hb = f2bf(hn);
    xin[(size_t)b * 1536 + NH + k] = hb;
    hall_t[idx] = hb;
}

__global__ __launch_bounds__(256) void zero_state(float* __restrict__ h, float* __restrict__ c,
                                                  ushort_t* __restrict__ xin) {
    int i = blockIdx.x * 256 + threadIdx.x;
    if (i < NB * 1536) xin[i] = 0;
    if (i < NB * NH) { h[i] = 0.f; c[i] = 0.f; }
}

__global__ __launch_bounds__(256) void copy_hc(const float* __restrict__ h, const float* __restrict__ c,
                                               float* __restrict__ out) {
    int i = blockIdx.x * 256 + threadIdx.x;
    if (i < NB * NH) {
        out[(size_t)NB * NT * NV + i] = h[i];
        out[(size_t)NB * NT * NV + NB * NH + i] = c[i];
    }
}

extern "C" void kernel_launch(void* const* d_in, const int* in_sizes, int n_in,
                              void* d_out, int out_size, void* d_ws, size_t ws_size,
                              hipStream_t stream) {
    const float* images   = (const float*)d_in[0];
    const int*   captions = (const int*)d_in[1];
    const float* conv1_w  = (const float*)d_in[2];
    const float* bn1_g = (const float*)d_in[3], *bn1_b = (const float*)d_in[4];
    const float* bn1_m = (const float*)d_in[5], *bn1_v = (const float*)d_in[6];
    const float* conv2_w  = (const float*)d_in[7];
    const float* bn2_g = (const float*)d_in[8], *bn2_b = (const float*)d_in[9];
    const float* bn2_m = (const float*)d_in[10], *bn2_v = (const float*)d_in[11];
    const float* conv3_w  = (const float*)d_in[12];
    const float* bn3_g = (const float*)d_in[13], *bn3_b = (const float*)d_in[14];
    const float* bn3_m = (const float*)d_in[15], *bn3_v = (const float*)d_in[16];
    const float* conv4_w  = (const float*)d_in[17];
    const float* bn4_g = (const float*)d_in[18], *bn4_b = (const float*)d_in[19];
    const float* bn4_m = (const float*)d_in[20], *bn4_v = (const float*)d_in[21];
    const float* emb_table = (const float*)d_in[22];
    const float* attn_w   = (const float*)d_in[23];
    const float* w_ih     = (const float*)d_in[24];
    const float* w_hh     = (const float*)d_in[25];
    const float* b_ih     = (const float*)d_in[26];
    const float* b_hh     = (const float*)d_in[27];
    const float* fc_w     = (const float*)d_in[28];
    const float* fc_b     = (const float*)d_in[29];
    float* out = (float*)d_out;

    // ---- workspace layout (bytes, 256B aligned) ----
    char* base = (char*)d_ws;
    size_t off = 0;
    auto alloc = [&](size_t bytes) { char* p = base + off; off += (bytes + 255) & ~(size_t)255; return p; };
    float* s1 = (float*)alloc(64 * 4);   float* bb1 = (float*)alloc(64 * 4);
    float* s2 = (float*)alloc(128 * 4);  float* bb2 = (float*)alloc(128 * 4);
    float* s3 = (float*)alloc(256 * 4);  float* bb3 = (float*)alloc(256 * 4);
    float* s4 = (float*)alloc(768 * 4);  float* bb4 = (float*)alloc(768 * 4);
    ushort_t* c1out = (ushort_t*)alloc((size_t)32 * 34 * 112 * 64 * 2);
    size_t halo_start = off;
    ushort_t* hal2 = (ushort_t*)alloc((size_t)32 * 19 * 58 * 64 * 2);
    ushort_t* hal3 = (ushort_t*)alloc((size_t)32 * 18 * 58 * 128 * 2);
    ushort_t* hal4 = (ushort_t*)alloc((size_t)32 * 10 * 30 * 256 * 2);
    size_t halo_bytes = off - halo_start;
    ushort_t* memv = (ushort_t*)alloc((size_t)32 * 196 * 768 * 2);
    ushort_t* wb1 = (ushort_t*)alloc((size_t)64 * 160 * 2);
    ushort_t* wb2 = (ushort_t*)alloc((size_t)128 * 9 * 64 * 2);
    ushort_t* wb3 = (ushort_t*)alloc((size_t)256 * 9 * 128 * 2);
    ushort_t* wb4 = (ushort_t*)alloc((size_t)768 * 9 * 256 * 2);
    ushort_t* wattn = (ushort_t*)alloc((size_t)768 * 768 * 2);
    ushort_t* wcomb = (ushort_t*)alloc((size_t)3072 * 1536 * 2);
    ushort_t* wihL = (ushort_t*)alloc((size_t)3072 * 768 * 2);
    ushort_t* e512 = (ushort_t*)alloc((size_t)512 * 768 * 2);
    float* eg   = (float*)alloc((size_t)512 * 3072 * 4);
    ushort_t* Hall = (ushort_t*)alloc((size_t)512 * 768 * 2);
    float* hbuf = (float*)alloc(NB * NH * 4);
    float* cbuf = (float*)alloc(NB * NH * 4);
    ushort_t* xin = (ushort_t*)alloc((size_t)NB * 1536 * 2);
    float* gates = (float*)alloc((size_t)NB * 3072 * 4);
    // big union buffer: im2col (39 MB, dead after conv1_gemm) then fc_w bf16 (49.2 MB)
    char* ubig = alloc((size_t)NV * NH * 2);
    ushort_t* imcol = (ushort_t*)ubig;
    ushort_t* fcwb  = (ushort_t*)ubig;

    // ---- one-time transforms ----
    bn_prep<<<1, 256, 0, stream>>>(bn1_g, bn1_b, bn1_m, bn1_v, s1, bb1, 64);
    bn_prep<<<1, 256, 0, stream>>>(bn2_g, bn2_b, bn2_m, bn2_v, s2, bb2, 128);
    bn_prep<<<1, 256, 0, stream>>>(bn3_g, bn3_b, bn3_m, bn3_v, s3, bb3, 256);
    bn_prep<<<3, 256, 0, stream>>>(bn4_g, bn4_b, bn4_m, bn4_v, s4, bb4, 768);
    cvt_pad<<<(64 * 160 + 255) / 256, 256, 0, stream>>>(conv1_w, wb1);
    cvt_w3x3<<<(128 * 9 * 64 + 255) / 256, 256, 0, stream>>>(conv2_w, wb2, 64, 128 * 9 * 64);
    cvt_w3x3<<<(256 * 9 * 128 + 255) / 256, 256, 0, stream>>>(conv3_w, wb3, 128, 256 * 9 * 128);
    cvt_w3x3<<<(768 * 9 * 256 + 255) / 256, 256, 0, stream>>>(conv4_w, wb4, 256, 768 * 9 * 256);
    cvt_rows<<<(768 * 768 + 255) / 256, 256, 0, stream>>>(attn_w, wattn, 768, 768, 0, 768 * 768);
    cvt_wcomb<<<(3072 * 1536 + 255) / 256, 256, 0, stream>>>(w_ih, w_hh, wcomb);
    cvt_rows<<<(3072 * 768 + 255) / 256, 256, 0, stream>>>(w_ih, wihL, 768, 1536, 0, 3072 * 768);
    {
        long long n8 = (long long)(halo_bytes / 8);
        zfill<<<(unsigned)((n8 + 255) / 256), 256, 0, stream>>>((unsigned long long*)hal2, n8);
    }

    // ---- encoder ----
    im2col1<<<(121856 * 160 + 255) / 256, 256, 0, stream>>>(images, imcol);
    conv1_gemm<<<476, 256, 0, stream>>>(imcol, wb1, s1, bb1, c1out);
    // im2col now dead -> convert fc_w into the same buffer
    cvt_rows<<<(NV * NH + 255) / 256, 256, 0, stream>>>(fc_w, fcwb, 768, 768, 0, NV * NH);
    pool_kernel<<<(32 * 17 * 56 * 8 + 255) / 256, 256, 0, stream>>>(c1out, hal2);
    conv_mfma<64, 19, 58, 1, 16, 56, 128, 0, 18, 58>
        <<<dim3(448, 2), 64, 0, stream>>>(hal2, wb2, s2, bb2, hal3);
    conv_mfma<128, 18, 58, 2, 8, 28, 256, 0, 10, 30>
        <<<dim3(112, 4), 64, 0, stream>>>(hal3, wb3, s3, bb3, hal4);
    conv_mfma<256, 10, 30, 1, 7, 28, 768, 1, 1, 1>
        <<<dim3(98, 12), 64, 0, stream>>>(hal4, wb4, s4, bb4, memv);

    // ---- decoder precompute ----
    gather_emb<<<(512 * 768) / 256, 256, 0, stream>>>(captions, emb_table, e512);
    gemm_bf16<0><<<dim3(3072 / 64, 2), 256, 0, stream>>>(
        e512, wihL, b_ih, b_hh, eg, NH, NH, 3072, NH);
    zero_state<<<(NB * 1536 + 255) / 256, 256, 0, stream>>>(hbuf, cbuf, xin);

    // ---- sequential decoder ----
    for (int t = 0; t < NT; ++t) {
        attn_fused<<<NB, NH, 0, stream>>>(xin, wattn, memv);
        gates_mfma<<<12, 256, 0, stream>>>(xin, wcomb, eg + (size_t)t * NB * 3072, gates);
        step_cell<<<(NB * NH + 255) / 256, 256, 0, stream>>>(
            gates, hbuf, cbuf, xin, Hall + (size_t)t * NB * NH);
    }

    // ---- vocab projection for all 16 steps at once ----
    gemm_bf16<1><<<dim3(NV / 64, 2), 256, 0, stream>>>(
        Hall, fcwb, fc_b, nullptr, out, NH, NH, NV, NH);

    copy_hc<<<(NB * NH + 255) / 256, 256, 0, stream>>>(hbuf, cbuf, out);
}

// Round 5
// 1166.972 us; speedup vs baseline: 7.3464x; 1.6776x over previous
//
#include <hip/hip_runtime.h>
#include <math.h>

#define NB 32
#define NT 16
#define NH 768
#define NV 32000

typedef short bf16x8 __attribute__((ext_vector_type(8)));
typedef float floatx4 __attribute__((ext_vector_type(4)));
typedef unsigned short ushort_t;

__device__ __forceinline__ float bf2f(unsigned short h) {
    unsigned u = ((unsigned)h) << 16;
    return __builtin_bit_cast(float, u);
}
__device__ __forceinline__ unsigned short f2bf(float f) {
    unsigned u = __builtin_bit_cast(unsigned, f);
    u += 0x7fffu + ((u >> 16) & 1u);
    return (unsigned short)(u >> 16);
}
__device__ __forceinline__ float sigmoidf_(float x) { return 1.f / (1.f + expf(-x)); }

// ---------------- BN scale/bias precompute ----------------
__global__ void bn_prep(const float* __restrict__ g, const float* __restrict__ b,
                        const float* __restrict__ m, const float* __restrict__ v,
                        float* __restrict__ scale, float* __restrict__ bias, int C) {
    int i = blockIdx.x * 256 + threadIdx.x;
    if (i < C) {
        float inv = g[i] * rsqrtf(v[i] + 1e-5f);
        scale[i] = inv;
        bias[i] = b[i] - m[i] * inv;
    }
}

__global__ __launch_bounds__(256) void zfill(unsigned long long* __restrict__ p, long long n) {
    long long i = (long long)blockIdx.x * 256 + threadIdx.x;
    if (i < n) p[i] = 0ULL;
}

// ======== packing: MFMA-fragment order. dst idx = (((tile*KQ+kq)*4+j)*64+lane)*8+e
// holds src[tile*64 + j*16 + (lane&15)][kq*32 + (lane>>4)*8 + e]  (row-major [N][K] src)
__global__ __launch_bounds__(256) void cvt_packB_f32(const float* __restrict__ src, ushort_t* __restrict__ dst,
                                                     int ldb, int K, int total) {
    int idx = blockIdx.x * 256 + threadIdx.x;
    if (idx >= total) return;
    int e = idx & 7, lane = (idx >> 3) & 63, j = (idx >> 9) & 3;
    int t = idx >> 11;
    int KQ = K >> 5;
    int kq = t % KQ, nt = t / KQ;
    int n = nt * 64 + j * 16 + (lane & 15);
    int k = kq * 32 + (lane >> 4) * 8 + e;
    dst[idx] = f2bf(src[(size_t)n * ldb + k]);
}

__global__ __launch_bounds__(256) void cvt_packB_bf16(const ushort_t* __restrict__ src, ushort_t* __restrict__ dst,
                                                      int ldb, int K, int total) {
    int idx = blockIdx.x * 256 + threadIdx.x;
    if (idx >= total) return;
    int e = idx & 7, lane = (idx >> 3) & 63, j = (idx >> 9) & 3;
    int t = idx >> 11;
    int KQ = K >> 5;
    int kq = t % KQ, nt = t / KQ;
    int n = nt * 64 + j * 16 + (lane & 15);
    int k = kq * 32 + (lane >> 4) * 8 + e;
    dst[idx] = src[(size_t)n * ldb + k];
}

// conv weights OIHW f32 -> packed per (nt, tap, kq): idx = ((((nt*9+t)*KQ+kq)*4+j)*64+lane)*8+e
__global__ __launch_bounds__(256) void cvt_packW_conv(const float* __restrict__ w, ushort_t* __restrict__ dst,
                                                      int CIN, int total) {
    int idx = blockIdx.x * 256 + threadIdx.x;
    if (idx >= total) return;
    int e = idx & 7, lane = (idx >> 3) & 63, j = (idx >> 9) & 3;
    int r = idx >> 11;
    int KQ = CIN >> 5;
    int kq = r % KQ; r /= KQ;
    int tap = r % 9; int nt = r / 9;
    int co = nt * 64 + j * 16 + (lane & 15);
    int ci = kq * 32 + (lane >> 4) * 8 + e;
    dst[idx] = f2bf(w[((size_t)co * CIN + ci) * 9 + tap]);
}

// wcombP: block bx (48), gate g (4), kq (48), lane: row = g*768+bx*16+(lane&15); k<768->w_ih ctx-half, else w_hh
__global__ __launch_bounds__(256) void cvt_wcombP(const float* __restrict__ w_ih, const float* __restrict__ w_hh,
                                                  ushort_t* __restrict__ dst) {
    int idx = blockIdx.x * 256 + threadIdx.x;
    if (idx >= 3072 * 1536) return;
    int e = idx & 7, lane = (idx >> 3) & 63;
    int t = idx >> 9;
    int kq = t % 48, gg = t / 48;
    int g = gg & 3, bx = gg >> 2;
    int j = g * 768 + bx * 16 + (lane & 15);
    int k = kq * 32 + (lane >> 4) * 8 + e;
    float v = (k < NH) ? w_ih[(size_t)j * (2 * NH) + NH + k] : w_hh[(size_t)j * NH + (k - NH)];
    dst[idx] = f2bf(v);
}

// wattnP[(k8*768 + tid)*8 + e] = attn_w[tid][k8*8+e]
__global__ __launch_bounds__(256) void cvt_wattnP(const float* __restrict__ w, ushort_t* __restrict__ dst) {
    int idx = blockIdx.x * 256 + threadIdx.x;
    if (idx >= 768 * 768) return;
    int e = idx & 7;
    int tid = (idx >> 3) % 768;
    int k8 = idx / (8 * 768);
    dst[idx] = f2bf(w[(size_t)tid * 768 + k8 * 8 + e]);
}

// strided f32 -> bf16 row convert (kept for wihL)
__global__ __launch_bounds__(256) void cvt_rows(const float* __restrict__ src, ushort_t* __restrict__ dst,
                                                int cols, int ld, int srcoff, int total) {
    int idx = blockIdx.x * 256 + threadIdx.x;
    if (idx >= total) return;
    int r = idx / cols, c = idx % cols;
    dst[idx] = f2bf(src[(size_t)r * ld + srcoff + c]);
}

// conv1 weights: [64][147] f32 -> [64][160] bf16 (zero pad)
__global__ __launch_bounds__(256) void cvt_pad(const float* __restrict__ src, ushort_t* __restrict__ dst) {
    int idx = blockIdx.x * 256 + threadIdx.x;
    if (idx >= 64 * 160) return;
    int co = idx / 160, k = idx % 160;
    dst[idx] = (k < 147) ? f2bf(src[co * 147 + k]) : (ushort_t)0;
}

// ---------------- conv1 im2col: [121856][160] bf16 ----------------
__global__ __launch_bounds__(256) void im2col1(const float* __restrict__ img, ushort_t* __restrict__ A) {
    int idx = blockIdx.x * 256 + threadIdx.x;
    const int total = 121856 * 160;
    if (idx >= total) return;
    int k = idx % 160;
    int m = idx / 160;
    ushort_t v = 0;
    if (k < 147) {
        int b = m / 3808;
        int rm = m % 3808;
        int y = rm / 112, x = rm % 112;
        int ci = k / 49;
        int r = k % 49;
        int ky = r / 7, kx = r % 7;
        int iy = 2 * y - 3 + ky;
        int ix = 2 * x - 3 + kx;
        if ((unsigned)iy < 224u && (unsigned)ix < 224u)
            v = f2bf(img[((size_t)(b * 3 + ci) * 224 + iy) * 224 + ix]);
    }
    A[idx] = v;
}

// ---------------- conv1 GEMM: [121856][160] x [64][160]^T ----------------
__global__ __launch_bounds__(256) void conv1_gemm(
    const ushort_t* __restrict__ A, const ushort_t* __restrict__ Bw,
    const float* __restrict__ scale, const float* __restrict__ bias,
    ushort_t* __restrict__ out) {
    int lane = threadIdx.x & 63, w = threadIdx.x >> 6;
    int m0 = (blockIdx.x * 4 + w) * 64;
    int lr = lane & 15, kl = (lane >> 4) * 8;
    floatx4 acc[4][4];
    #pragma unroll
    for (int i = 0; i < 4; ++i)
        #pragma unroll
        for (int j = 0; j < 4; ++j) acc[i][j] = 0.f;
    #pragma unroll
    for (int k0 = 0; k0 < 160; k0 += 32) {
        bf16x8 a[4], bb[4];
        #pragma unroll
        for (int i = 0; i < 4; ++i) a[i] = *(const bf16x8*)(A + (size_t)(m0 + 16 * i + lr) * 160 + kl + k0);
        #pragma unroll
        for (int j = 0; j < 4; ++j) bb[j] = *(const bf16x8*)(Bw + (size_t)(16 * j + lr) * 160 + kl + k0);
        #pragma unroll
        for (int i = 0; i < 4; ++i)
            #pragma unroll
            for (int j = 0; j < 4; ++j)
                acc[i][j] = __builtin_amdgcn_mfma_f32_16x16x32_bf16(a[i], bb[j], acc[i][j], 0, 0, 0);
    }
    #pragma unroll
    for (int i = 0; i < 4; ++i) {
        #pragma unroll
        for (int r = 0; r < 4; ++r) {
            int m = m0 + 16 * i + (lane >> 4) * 4 + r;
            int b = m / 3808;
            int rm = m % 3808;
            int y = rm / 112, x = rm % 112;
            #pragma unroll
            for (int j = 0; j < 4; ++j) {
                int n = 16 * j + lr;
                float v = fmaxf(acc[i][j][r] * scale[n] + bias[n], 0.f);
                out[((size_t)(b * 34 + y) * 112 + x) * 64 + n] = f2bf(v);
            }
        }
    }
}

// ---------------- maxpool 3x3 s2 p1 ----------------
__global__ __launch_bounds__(256) void pool_kernel(const ushort_t* __restrict__ in,
                                                   ushort_t* __restrict__ hal2) {
    int idx = blockIdx.x * 256 + threadIdx.x;
    const int total = 32 * 17 * 56 * 8;
    if (idx >= total) return;
    int c8 = idx & 7;
    int rest = idx >> 3;
    int x = rest % 56; rest /= 56;
    int y = rest % 17; int b = rest / 17;
    float mx[8];
    #pragma unroll
    for (int j = 0; j < 8; ++j) mx[j] = -INFINITY;
    for (int dy = -1; dy <= 1; ++dy) {
        int iy = 2 * y + dy;
        if ((unsigned)iy >= 34u) continue;
        for (int dx = -1; dx <= 1; ++dx) {
            int ix = 2 * x + dx;
            if ((unsigned)ix >= 112u) continue;
            bf16x8 v = *(const bf16x8*)(in + (((size_t)(b * 34 + iy)) * 112 + ix) * 64 + c8 * 8);
            #pragma unroll
            for (int j = 0; j < 8; ++j) mx[j] = fmaxf(mx[j], bf2f((unsigned short)v[j]));
        }
    }
    bf16x8 o;
    #pragma unroll
    for (int j = 0; j < 8; ++j) o[j] = (short)f2bf(mx[j]);
    *(bf16x8*)(hal2 + (((size_t)(b * 19 + y + 1)) * 58 + (x + 1)) * 64 + c8 * 8) = o;
}

// ---------------- implicit-GEMM 3x3 conv via MFMA, packed weights ----------------
template <int CIN, int HH, int WH, int STRIDE, int HOUT, int WOUT, int COUT, int MEMOUT, int OH, int OW>
__global__ __launch_bounds__(64) void conv_mfma(
    const ushort_t* __restrict__ in, const ushort_t* __restrict__ wtP,
    const float* __restrict__ scale, const float* __restrict__ bias,
    ushort_t* __restrict__ out, ushort_t* __restrict__ memT) {
    int lane = threadIdx.x;
    int mt = blockIdx.x, nt = blockIdx.y;
    int lr = lane & 15, kl = (lane >> 4) * 8;
    int rowoff[4];
    #pragma unroll
    for (int i = 0; i < 4; ++i) {
        int m = mt * 64 + 16 * i + lr;
        int b = m / (HOUT * WOUT);
        int rm = m % (HOUT * WOUT);
        int y = rm / WOUT, x = rm % WOUT;
        rowoff[i] = ((b * HH + y * STRIDE) * WH + x * STRIDE) * CIN + kl;
    }
    floatx4 acc[4][4];
    #pragma unroll
    for (int i = 0; i < 4; ++i)
        #pragma unroll
        for (int j = 0; j < 4; ++j) acc[i][j] = 0.f;

    #pragma unroll
    for (int ky = 0; ky < 3; ++ky) {
        #pragma unroll
        for (int kx = 0; kx < 3; ++kx) {
            int ioff = (ky * WH + kx) * CIN;
            int t = ky * 3 + kx;
            #pragma unroll
            for (int k0 = 0; k0 < CIN; k0 += 32) {
                bf16x8 a[4], bb[4];
                #pragma unroll
                for (int i = 0; i < 4; ++i)
                    a[i] = *(const bf16x8*)(in + rowoff[i] + ioff + k0);
                #pragma unroll
                for (int j = 0; j < 4; ++j)
                    bb[j] = *(const bf16x8*)(wtP + ((((size_t)(nt * 9 + t) * (CIN / 32) + (k0 >> 5)) * 4 + j) * 64 + lane) * 8);
                #pragma unroll
                for (int i = 0; i < 4; ++i)
                    #pragma unroll
                    for (int j = 0; j < 4; ++j)
                        acc[i][j] = __builtin_amdgcn_mfma_f32_16x16x32_bf16(a[i], bb[j], acc[i][j], 0, 0, 0);
            }
        }
    }
    #pragma unroll
    for (int i = 0; i < 4; ++i) {
        #pragma unroll
        for (int r = 0; r < 4; ++r) {
            int m = mt * 64 + 16 * i + (lane >> 4) * 4 + r;
            int b = m / (HOUT * WOUT);
            int rm = m % (HOUT * WOUT);
            int y = rm / WOUT, x = rm % WOUT;
            #pragma unroll
            for (int j = 0; j < 4; ++j) {
                int n = nt * 64 + 16 * j + lr;
                float v = fmaxf(acc[i][j][r] * scale[n] + bias[n], 0.f);
                ushort_t hv = f2bf(v);
                if (MEMOUT) {
                    out[(size_t)m * COUT + n] = hv;   // memory [b][196][768]
                    memT[(((size_t)b * 96 + (n >> 3)) * 196 + rm) * 8 + (n & 7)] = hv;
                } else {
                    out[((size_t)(b * OH + y + 1) * OW + (x + 1)) * COUT + n] = hv;
                }
            }
        }
    }
}

// ---------------- embedding gather -> bf16, rows r = t*32+b ----------------
__global__ __launch_bounds__(256) void gather_emb(const int* __restrict__ caps,
                                                  const float* __restrict__ table,
                                                  ushort_t* __restrict__ e512) {
    int idx = blockIdx.x * 256 + threadIdx.x;  // 512*768
    int k = idx % NH;
    int r = idx / NH;
    int t = r >> 5;
    int b = r & 31;
    e512[idx] = f2bf(table[(size_t)caps[b * NT + t] * NH + k]);
}

// ---------------- generic MFMA GEMM (unpacked B), used for eg precompute ----------------
__global__ __launch_bounds__(256) void gemm_bf16(
    const ushort_t* __restrict__ A, const ushort_t* __restrict__ B,
    const float* __restrict__ bias1, const float* __restrict__ bias2,
    float* __restrict__ C, int lda, int ldb, int N, int K) {
    int lane = threadIdx.x & 63, w = threadIdx.x >> 6;
    int m0 = (blockIdx.y * 4 + w) * 64, n0 = blockIdx.x * 64;
    int lr = lane & 15, kl = (lane >> 4) * 8;
    floatx4 acc[4][4];
    #pragma unroll
    for (int i = 0; i < 4; ++i)
        #pragma unroll
        for (int j = 0; j < 4; ++j) acc[i][j] = 0.f;
    for (int k0 = 0; k0 < K; k0 += 32) {
        bf16x8 a[4], bb[4];
        #pragma unroll
        for (int i = 0; i < 4; ++i) a[i] = *(const bf16x8*)(A + (size_t)(m0 + 16 * i + lr) * lda + kl + k0);
        #pragma unroll
        for (int j = 0; j < 4; ++j) bb[j] = *(const bf16x8*)(B + (size_t)(n0 + 16 * j + lr) * ldb + kl + k0);
        #pragma unroll
        for (int i = 0; i < 4; ++i)
            #pragma unroll
            for (int j = 0; j < 4; ++j)
                acc[i][j] = __builtin_amdgcn_mfma_f32_16x16x32_bf16(a[i], bb[j], acc[i][j], 0, 0, 0);
    }
    #pragma unroll
    for (int i = 0; i < 4; ++i) {
        #pragma unroll
        for (int r = 0; r < 4; ++r) {
            int m = m0 + 16 * i + (lane >> 4) * 4 + r;
            #pragma unroll
            for (int j = 0; j < 4; ++j) {
                int n = n0 + 16 * j + lr;
                float v = acc[i][j][r];
                if (bias1) v += bias1[n];
                if (bias2) v += bias2[n];
                C[(size_t)m * N + n] = v;
            }
        }
    }
}

// ---------------- fc GEMM, both operands packed; REMAP epilogue ----------------
// grid dim3(2, 500): x = m-group (4 waves -> mt = x*4+w), y = nt
__global__ __launch_bounds__(256) void gemm_fc(
    const ushort_t* __restrict__ Ap, const ushort_t* __restrict__ Bp,
    const float* __restrict__ bias, float* __restrict__ C) {
    int lane = threadIdx.x & 63, w = threadIdx.x >> 6;
    int mt = blockIdx.x * 4 + w;   // 0..7
    int nt = blockIdx.y;           // 0..499
    floatx4 acc[4][4];
    #pragma unroll
    for (int i = 0; i < 4; ++i)
        #pragma unroll
        for (int j = 0; j < 4; ++j) acc[i][j] = 0.f;
    for (int kq = 0; kq < 24; ++kq) {
        bf16x8 a[4], bb[4];
        #pragma unroll
        for (int i = 0; i < 4; ++i)
            a[i] = *(const bf16x8*)(Ap + (((size_t)(mt * 24 + kq) * 4 + i) * 64 + lane) * 8);
        #pragma unroll
        for (int j = 0; j < 4; ++j)
            bb[j] = *(const bf16x8*)(Bp + (((size_t)(nt * 24 + kq) * 4 + j) * 64 + lane) * 8);
        #pragma unroll
        for (int i = 0; i < 4; ++i)
            #pragma unroll
            for (int j = 0; j < 4; ++j)
                acc[i][j] = __builtin_amdgcn_mfma_f32_16x16x32_bf16(a[i], bb[j], acc[i][j], 0, 0, 0);
    }
    int lr = lane & 15;
    #pragma unroll
    for (int i = 0; i < 4; ++i) {
        #pragma unroll
        for (int r = 0; r < 4; ++r) {
            int m = mt * 64 + 16 * i + (lane >> 4) * 4 + r;   // m = t*32+b
            int t = m >> 5, b = m & 31;
            #pragma unroll
            for (int j = 0; j < 4; ++j) {
                int n = nt * 64 + 16 * j + lr;
                C[(size_t)((b << 4) + t) * NV + n] = acc[i][j][r] + bias[n];
            }
        }
    }
}

// ---------------- fused attention ----------------
// grid 32 (batch), block 768. xin = [ctx | h] bf16 [32][1536] (reads h, writes ctx).
__global__ __launch_bounds__(768) void attn_fused(
    ushort_t* __restrict__ xin, const ushort_t* __restrict__ wattnP,
    const ushort_t* __restrict__ mem, const ushort_t* __restrict__ memT) {
    __shared__ float q[NH];
    __shared__ float sl[196];
    __shared__ float red[16];
    int b = blockIdx.x, tid = threadIdx.x;
    // phase 1: q[tid] = h . attn_w[tid]  (wattnP coalesced per k8)
    {
        const bf16x8* h8 = (const bf16x8*)(xin + (size_t)b * 1536 + NH);
        float acc = 0.f;
        #pragma unroll 4
        for (int k8 = 0; k8 < 96; ++k8) {
            bf16x8 a = h8[k8];
            bf16x8 w = *(const bf16x8*)(wattnP + ((size_t)k8 * 768 + tid) * 8);
            #pragma unroll
            for (int j = 0; j < 8; ++j)
                acc = fmaf(bf2f((unsigned short)a[j]), bf2f((unsigned short)w[j]), acc);
        }
        q[tid] = acc;
    }
    __syncthreads();
    // phase 2: scores via memT (coalesced over m), 2 threads per m
    if (tid < 392) {
        int m = tid >> 1, half = tid & 1;
        const ushort_t* basep = memT + (((size_t)b * 96 + half * 48) * 196 + m) * 8;
        float acc = 0.f;
        #pragma unroll 4
        for (int k8 = 0; k8 < 48; ++k8) {
            bf16x8 v = *(const bf16x8*)(basep + (size_t)k8 * 196 * 8);
            const float* qp = q + (half * 48 + k8) * 8;
            #pragma unroll
            for (int j = 0; j < 8; ++j)
                acc = fmaf(bf2f((unsigned short)v[j]), qp[j], acc);
        }
        acc += __shfl_xor(acc, 1);
        if (!half) sl[m] = acc;
    }
    __syncthreads();
    // phase 3: softmax over 196
    float sc = (tid < 196) ? sl[tid] : -INFINITY;
    float v = sc;
    #pragma unroll
    for (int off = 32; off; off >>= 1) v = fmaxf(v, __shfl_down(v, off));
    if ((tid & 63) == 0) red[tid >> 6] = v;
    __syncthreads();
    if (tid == 0) {
        float m = red[0];
        for (int i = 1; i < 12; ++i) m = fmaxf(m, red[i]);
        red[12] = m;
    }
    __syncthreads();
    float mx = red[12];
    float e = (tid < 196) ? expf(sc - mx) : 0.f;
    __syncthreads();
    v = e;
    #pragma unroll
    for (int off = 32; off; off >>= 1) v += __shfl_down(v, off);
    if ((tid & 63) == 0) red[tid >> 6] = v;
    __syncthreads();
    if (tid == 0) {
        float s = red[0];
        for (int i = 1; i < 12; ++i) s += red[i];
        red[12] = 1.f / s;
    }
    __syncthreads();
    if (tid < 196) sl[tid] = e * red[12];
    __syncthreads();
    // phase 4: ctx[tid] = sum_m p[m]*mem[b][m][tid]
    {
        float acc = 0.f;
        const ushort_t* mb = mem + (size_t)b * 196 * NH + tid;
        #pragma unroll 4
        for (int m = 0; m < 196; ++m) acc = fmaf(sl[m], bf2f(mb[(size_t)m * NH]), acc);
        xin[(size_t)b * 1536 + tid] = f2bf(acc);
    }
}

// ---------------- fused gates GEMM + LSTM cell ----------------
// grid 48, block 256 (4 waves = 4-way K split). Block bx covers cols bx*16..bx*16+15 of each gate.
__global__ __launch_bounds__(256) void step_fused(
    const ushort_t* __restrict__ xin_r, const ushort_t* __restrict__ wcombP,
    const float* __restrict__ eg_t,
    float* __restrict__ cbuf, float* __restrict__ hbuf,
    ushort_t* __restrict__ xin_w, ushort_t* __restrict__ hall_t) {
    __shared__ float pbuf[4][64][33];
    int lane = threadIdx.x & 63, w = threadIdx.x >> 6;
    int bx = blockIdx.x;
    int lr = lane & 15, kl = (lane >> 4) * 8;
    floatx4 acc[2][4];
    #pragma unroll
    for (int i = 0; i < 2; ++i)
        #pragma unroll
        for (int g = 0; g < 4; ++g) acc[i][g] = 0.f;
    for (int kq = 0; kq < 12; ++kq) {
        int k = w * 384 + kq * 32;
        bf16x8 a[2], bb[4];
        #pragma unroll
        for (int i = 0; i < 2; ++i)
            a[i] = *(const bf16x8*)(xin_r + (size_t)(16 * i + lr) * 1536 + k + kl);
        #pragma unroll
        for (int g = 0; g < 4; ++g)
            bb[g] = *(const bf16x8*)(wcombP + (((size_t)(bx * 4 + g) * 48 + (w * 12 + kq)) * 64 + lane) * 8);
        #pragma unroll
        for (int i = 0; i < 2; ++i)
            #pragma unroll
            for (int g = 0; g < 4; ++g)
                acc[i][g] = __builtin_amdgcn_mfma_f32_16x16x32_bf16(a[i], bb[g], acc[i][g], 0, 0, 0);
    }
    #pragma unroll
    for (int i = 0; i < 2; ++i)
        #pragma unroll
        for (int g = 0; g < 4; ++g)
            #pragma unroll
            for (int r = 0; r < 4; ++r) {
                int m = 16 * i + (lane >> 4) * 4 + r;
                pbuf[w][g * 16 + lr][m] = acc[i][g][r];
            }
    __syncthreads();
    int tid = threadIdx.x;
    #pragma unroll
    for (int o = 0; o < 2; ++o) {
        int pid = tid * 2 + o;          // 0..511
        int m = pid & 31, c = pid >> 5; // m = batch, c = 0..15
        int kcol = bx * 16 + c;
        float gi = 0.f, gf = 0.f, gg = 0.f, go = 0.f;
        #pragma unroll
        for (int ww = 0; ww < 4; ++ww) {
            gi += pbuf[ww][c][m];
            gf += pbuf[ww][16 + c][m];
            gg += pbuf[ww][32 + c][m];
            go += pbuf[ww][48 + c][m];
        }
        const float* eg = eg_t + (size_t)m * 3072;
        gi += eg[kcol];
        gf += eg[768 + kcol];
        gg += eg[1536 + kcol];
        go += eg[2304 + kcol];
        float cst = cbuf[m * 768 + kcol];
        float cn = sigmoidf_(gf) * cst + sigmoidf_(gi) * tanhf(gg);
        float hn = sigmoidf_(go) * tanhf(cn);
        cbuf[m * 768 + kcol] = cn;
        hbuf[m * 768 + kcol] = hn;
        ushort_t hb = f2bf(hn);
        xin_w[(size_t)m * 1536 + NH + kcol] = hb;
        hall_t[(size_t)m * 768 + kcol] = hb;
    }
}

__global__ __launch_bounds__(256) void zero_state(float* __restrict__ h, float* __restrict__ c,
                                                  ushort_t* __restrict__ xin) {
    int i = blockIdx.x * 256 + threadIdx.x;
    if (i < NB * 1536) xin[i] = 0;
    if (i < NB * NH) { h[i] = 0.f; c[i] = 0.f; }
}

__global__ __launch_bounds__(256) void copy_hc(const float* __restrict__ h, const float* __restrict__ c,
                                               float* __restrict__ out) {
    int i = blockIdx.x * 256 + threadIdx.x;
    if (i < NB * NH) {
        out[(size_t)NB * NT * NV + i] = h[i];
        out[(size_t)NB * NT * NV + NB * NH + i] = c[i];
    }
}

extern "C" void kernel_launch(void* const* d_in, const int* in_sizes, int n_in,
                              void* d_out, int out_size, void* d_ws, size_t ws_size,
                              hipStream_t stream) {
    const float* images   = (const float*)d_in[0];
    const int*   captions = (const int*)d_in[1];
    const float* conv1_w  = (const float*)d_in[2];
    const float* bn1_g = (const float*)d_in[3], *bn1_b = (const float*)d_in[4];
    const float* bn1_m = (const float*)d_in[5], *bn1_v = (const float*)d_in[6];
    const float* conv2_w  = (const float*)d_in[7];
    const float* bn2_g = (const float*)d_in[8], *bn2_b = (const float*)d_in[9];
    const float* bn2_m = (const float*)d_in[10], *bn2_v = (const float*)d_in[11];
    const float* conv3_w  = (const float*)d_in[12];
    const float* bn3_g = (const float*)d_in[13], *bn3_b = (const float*)d_in[14];
    const float* bn3_m = (const float*)d_in[15], *bn3_v = (const float*)d_in[16];
    const float* conv4_w  = (const float*)d_in[17];
    const float* bn4_g = (const float*)d_in[18], *bn4_b = (const float*)d_in[19];
    const float* bn4_m = (const float*)d_in[20], *bn4_v = (const float*)d_in[21];
    const float* emb_table = (const float*)d_in[22];
    const float* attn_w   = (const float*)d_in[23];
    const float* w_ih     = (const float*)d_in[24];
    const float* w_hh     = (const float*)d_in[25];
    const float* b_ih     = (const float*)d_in[26];
    const float* b_hh     = (const float*)d_in[27];
    const float* fc_w     = (const float*)d_in[28];
    const float* fc_b     = (const float*)d_in[29];
    float* out = (float*)d_out;

    // ---- workspace layout ----
    char* base = (char*)d_ws;
    size_t off = 0;
    auto alloc = [&](size_t bytes) { char* p = base + off; off += (bytes + 255) & ~(size_t)255; return p; };
    float* s1 = (float*)alloc(64 * 4);   float* bb1 = (float*)alloc(64 * 4);
    float* s2 = (float*)alloc(128 * 4);  float* bb2 = (float*)alloc(128 * 4);
    float* s3 = (float*)alloc(256 * 4);  float* bb3 = (float*)alloc(256 * 4);
    float* s4 = (float*)alloc(768 * 4);  float* bb4 = (float*)alloc(768 * 4);
    ushort_t* c1out = (ushort_t*)alloc((size_t)32 * 34 * 112 * 64 * 2);
    size_t halo_start = off;
    ushort_t* hal2 = (ushort_t*)alloc((size_t)32 * 19 * 58 * 64 * 2);
    ushort_t* hal3 = (ushort_t*)alloc((size_t)32 * 18 * 58 * 128 * 2);
    ushort_t* hal4 = (ushort_t*)alloc((size_t)32 * 10 * 30 * 256 * 2);
    size_t halo_bytes = off - halo_start;
    ushort_t* memv = (ushort_t*)alloc((size_t)32 * 196 * 768 * 2);
    ushort_t* memT = (ushort_t*)alloc((size_t)32 * 96 * 196 * 8 * 2);
    ushort_t* wb1 = (ushort_t*)alloc((size_t)64 * 160 * 2);
    ushort_t* wb2 = (ushort_t*)alloc((size_t)128 * 9 * 64 * 2);
    ushort_t* wb3 = (ushort_t*)alloc((size_t)256 * 9 * 128 * 2);
    ushort_t* wb4 = (ushort_t*)alloc((size_t)768 * 9 * 256 * 2);
    ushort_t* wattnP = (ushort_t*)alloc((size_t)768 * 768 * 2);
    ushort_t* wcombP = (ushort_t*)alloc((size_t)3072 * 1536 * 2);
    ushort_t* wihL = (ushort_t*)alloc((size_t)3072 * 768 * 2);
    ushort_t* e512 = (ushort_t*)alloc((size_t)512 * 768 * 2);
    float* eg   = (float*)alloc((size_t)512 * 3072 * 4);
    ushort_t* Hall = (ushort_t*)alloc((size_t)512 * 768 * 2);
    ushort_t* HallP = (ushort_t*)alloc((size_t)512 * 768 * 2);
    float* hbuf = (float*)alloc(NB * NH * 4);
    float* cbuf = (float*)alloc(NB * NH * 4);
    ushort_t* xinA = (ushort_t*)alloc((size_t)NB * 1536 * 2);
    ushort_t* xinB = (ushort_t*)alloc((size_t)NB * 1536 * 2);
    // big union: im2col (39 MB, dead after conv1_gemm) then packed fc_w (49.2 MB)
    char* ubig = alloc((size_t)NV * NH * 2);
    ushort_t* imcol = (ushort_t*)ubig;
    ushort_t* fcP   = (ushort_t*)ubig;

    // ---- one-time transforms ----
    bn_prep<<<1, 256, 0, stream>>>(bn1_g, bn1_b, bn1_m, bn1_v, s1, bb1, 64);
    bn_prep<<<1, 256, 0, stream>>>(bn2_g, bn2_b, bn2_m, bn2_v, s2, bb2, 128);
    bn_prep<<<1, 256, 0, stream>>>(bn3_g, bn3_b, bn3_m, bn3_v, s3, bb3, 256);
    bn_prep<<<3, 256, 0, stream>>>(bn4_g, bn4_b, bn4_m, bn4_v, s4, bb4, 768);
    cvt_pad<<<(64 * 160 + 255) / 256, 256, 0, stream>>>(conv1_w, wb1);
    cvt_packW_conv<<<(128 * 9 * 64 + 255) / 256, 256, 0, stream>>>(conv2_w, wb2, 64, 128 * 9 * 64);
    cvt_packW_conv<<<(256 * 9 * 128 + 255) / 256, 256, 0, stream>>>(conv3_w, wb3, 128, 256 * 9 * 128);
    cvt_packW_conv<<<(768 * 9 * 256 + 255) / 256, 256, 0, stream>>>(conv4_w, wb4, 256, 768 * 9 * 256);
    cvt_wattnP<<<(768 * 768 + 255) / 256, 256, 0, stream>>>(attn_w, wattnP);
    cvt_wcombP<<<(3072 * 1536 + 255) / 256, 256, 0, stream>>>(w_ih, w_hh, wcombP);
    cvt_rows<<<(3072 * 768 + 255) / 256, 256, 0, stream>>>(w_ih, wihL, 768, 1536, 0, 3072 * 768);
    {
        long long n8 = (long long)(halo_bytes / 8);
        zfill<<<(unsigned)((n8 + 255) / 256), 256, 0, stream>>>((unsigned long long*)hal2, n8);
    }

    // ---- encoder ----
    im2col1<<<(121856 * 160 + 255) / 256, 256, 0, stream>>>(images, imcol);
    conv1_gemm<<<476, 256, 0, stream>>>(imcol, wb1, s1, bb1, c1out);
    // im2col dead -> pack fc_w into the same buffer
    cvt_packB_f32<<<(NV * NH + 255) / 256, 256, 0, stream>>>(fc_w, fcP, 768, 768, NV * NH);
    pool_kernel<<<(32 * 17 * 56 * 8 + 255) / 256, 256, 0, stream>>>(c1out, hal2);
    conv_mfma<64, 19, 58, 1, 16, 56, 128, 0, 18, 58>
        <<<dim3(448, 2), 64, 0, stream>>>(hal2, wb2, s2, bb2, hal3, nullptr);
    conv_mfma<128, 18, 58, 2, 8, 28, 256, 0, 10, 30>
        <<<dim3(112, 4), 64, 0, stream>>>(hal3, wb3, s3, bb3, hal4, nullptr);
    conv_mfma<256, 10, 30, 1, 7, 28, 768, 1, 1, 1>
        <<<dim3(98, 12), 64, 0, stream>>>(hal4, wb4, s4, bb4, memv, memT);

    // ---- decoder precompute ----
    gather_emb<<<(512 * 768) / 256, 256, 0, stream>>>(captions, emb_table, e512);
    gemm_bf16<<<dim3(3072 / 64, 2), 256, 0, stream>>>(
        e512, wihL, b_ih, b_hh, eg, NH, NH, 3072, NH);
    zero_state<<<(NB * 1536 + 255) / 256, 256, 0, stream>>>(hbuf, cbuf, xinA);

    // ---- sequential decoder (xin double-buffered) ----
    ushort_t* xcur = xinA;
    ushort_t* xnxt = xinB;
    for (int t = 0; t < NT; ++t) {
        attn_fused<<<NB, NH, 0, stream>>>(xcur, wattnP, memv, memT);
        step_fused<<<48, 256, 0, stream>>>(
            xcur, wcombP, eg + (size_t)t * NB * 3072, cbuf, hbuf, xnxt,
            Hall + (size_t)t * NB * NH);
        ushort_t* tmp = xcur; xcur = xnxt; xnxt = tmp;
    }

    // ---- vocab projection for all 16 steps at once ----
    cvt_packB_bf16<<<(512 * 768 + 255) / 256, 256, 0, stream>>>(Hall, HallP, 768, 768, 512 * 768);
    gemm_fc<<<dim3(2, 500), 256, 0, stream>>>(HallP, fcP, fc_b, out);

    copy_hc<<<(NB * NH + 255) / 256, 256, 0, stream>>>(hbuf, cbuf, out);
}

// Round 6
// 1139.751 us; speedup vs baseline: 7.5219x; 1.0239x over previous
//
#include <hip/hip_runtime.h>
#include <math.h>

#define NB 32
#define NT 16
#define NH 768
#define NV 32000

typedef short bf16x8 __attribute__((ext_vector_type(8)));
typedef float floatx4 __attribute__((ext_vector_type(4)));
typedef unsigned short ushort_t;

__device__ __forceinline__ float bf2f(unsigned short h) {
    unsigned u = ((unsigned)h) << 16;
    return __builtin_bit_cast(float, u);
}
__device__ __forceinline__ unsigned short f2bf(float f) {
    unsigned u = __builtin_bit_cast(unsigned, f);
    u += 0x7fffu + ((u >> 16) & 1u);
    return (unsigned short)(u >> 16);
}
__device__ __forceinline__ float sigmoidf_(float x) { return 1.f / (1.f + expf(-x)); }

// ---------------- BN scale/bias precompute ----------------
__global__ void bn_prep(const float* __restrict__ g, const float* __restrict__ b,
                        const float* __restrict__ m, const float* __restrict__ v,
                        float* __restrict__ scale, float* __restrict__ bias, int C) {
    int i = blockIdx.x * 256 + threadIdx.x;
    if (i < C) {
        float inv = g[i] * rsqrtf(v[i] + 1e-5f);
        scale[i] = inv;
        bias[i] = b[i] - m[i] * inv;
    }
}

__global__ __launch_bounds__(256) void zfill(unsigned long long* __restrict__ p, long long n) {
    long long i = (long long)blockIdx.x * 256 + threadIdx.x;
    if (i < n) p[i] = 0ULL;
}

// conv weights OIHW f32 -> packed per (nt, tap, kq): idx = ((((nt*9+t)*KQ+kq)*4+j)*64+lane)*8+e
__global__ __launch_bounds__(256) void cvt_packW_conv(const float* __restrict__ w, ushort_t* __restrict__ dst,
                                                      int CIN, int total) {
    int idx = blockIdx.x * 256 + threadIdx.x;
    if (idx >= total) return;
    int e = idx & 7, lane = (idx >> 3) & 63, j = (idx >> 9) & 3;
    int r = idx >> 11;
    int KQ = CIN >> 5;
    int kq = r % KQ; r /= KQ;
    int tap = r % 9; int nt = r / 9;
    int co = nt * 64 + j * 16 + (lane & 15);
    int ci = kq * 32 + (lane >> 4) * 8 + e;
    dst[idx] = f2bf(w[((size_t)co * CIN + ci) * 9 + tap]);
}

// wcombP: block bx (48), gate g (4), kq (48), lane: row = g*768+bx*16+(lane&15); k<768->w_ih ctx-half, else w_hh
__global__ __launch_bounds__(256) void cvt_wcombP(const float* __restrict__ w_ih, const float* __restrict__ w_hh,
                                                  ushort_t* __restrict__ dst) {
    int idx = blockIdx.x * 256 + threadIdx.x;
    if (idx >= 3072 * 1536) return;
    int e = idx & 7, lane = (idx >> 3) & 63;
    int t = idx >> 9;
    int kq = t % 48, gg = t / 48;
    int g = gg & 3, bx = gg >> 2;
    int j = g * 768 + bx * 16 + (lane & 15);
    int k = kq * 32 + (lane >> 4) * 8 + e;
    float v = (k < NH) ? w_ih[(size_t)j * (2 * NH) + NH + k] : w_hh[(size_t)j * NH + (k - NH)];
    dst[idx] = f2bf(v);
}

// wattnP[(k8*768 + tid)*8 + e] = attn_w[tid][k8*8+e]
__global__ __launch_bounds__(256) void cvt_wattnP(const float* __restrict__ w, ushort_t* __restrict__ dst) {
    int idx = blockIdx.x * 256 + threadIdx.x;
    if (idx >= 768 * 768) return;
    int e = idx & 7;
    int tid = (idx >> 3) % 768;
    int k8 = idx / (8 * 768);
    dst[idx] = f2bf(w[(size_t)tid * 768 + k8 * 8 + e]);
}

// conv1 weights: [64][147] f32 -> [64][160] bf16 (zero pad)
__global__ __launch_bounds__(256) void cvt_pad(const float* __restrict__ src, ushort_t* __restrict__ dst) {
    int idx = blockIdx.x * 256 + threadIdx.x;
    if (idx >= 64 * 160) return;
    int co = idx / 160, k = idx % 160;
    dst[idx] = (k < 147) ? f2bf(src[co * 147 + k]) : (ushort_t)0;
}

// ---------------- conv1 im2col: [121856][160] bf16 ----------------
__global__ __launch_bounds__(256) void im2col1(const float* __restrict__ img, ushort_t* __restrict__ A) {
    int idx = blockIdx.x * 256 + threadIdx.x;
    const int total = 121856 * 160;
    if (idx >= total) return;
    int k = idx % 160;
    int m = idx / 160;
    ushort_t v = 0;
    if (k < 147) {
        int b = m / 3808;
        int rm = m % 3808;
        int y = rm / 112, x = rm % 112;
        int ci = k / 49;
        int r = k % 49;
        int ky = r / 7, kx = r % 7;
        int iy = 2 * y - 3 + ky;
        int ix = 2 * x - 3 + kx;
        if ((unsigned)iy < 224u && (unsigned)ix < 224u)
            v = f2bf(img[((size_t)(b * 3 + ci) * 224 + iy) * 224 + ix]);
    }
    A[idx] = v;
}

// ---------------- conv1 GEMM: [121856][160] x [64][160]^T ----------------
__global__ __launch_bounds__(256) void conv1_gemm(
    const ushort_t* __restrict__ A, const ushort_t* __restrict__ Bw,
    const float* __restrict__ scale, const float* __restrict__ bias,
    ushort_t* __restrict__ out) {
    int lane = threadIdx.x & 63, w = threadIdx.x >> 6;
    int m0 = (blockIdx.x * 4 + w) * 64;
    int lr = lane & 15, kl = (lane >> 4) * 8;
    floatx4 acc[4][4];
    #pragma unroll
    for (int i = 0; i < 4; ++i)
        #pragma unroll
        for (int j = 0; j < 4; ++j) acc[i][j] = 0.f;
    #pragma unroll
    for (int k0 = 0; k0 < 160; k0 += 32) {
        bf16x8 a[4], bb[4];
        #pragma unroll
        for (int i = 0; i < 4; ++i) a[i] = *(const bf16x8*)(A + (size_t)(m0 + 16 * i + lr) * 160 + kl + k0);
        #pragma unroll
        for (int j = 0; j < 4; ++j) bb[j] = *(const bf16x8*)(Bw + (size_t)(16 * j + lr) * 160 + kl + k0);
        #pragma unroll
        for (int i = 0; i < 4; ++i)
            #pragma unroll
            for (int j = 0; j < 4; ++j)
                acc[i][j] = __builtin_amdgcn_mfma_f32_16x16x32_bf16(a[i], bb[j], acc[i][j], 0, 0, 0);
    }
    #pragma unroll
    for (int i = 0; i < 4; ++i) {
        #pragma unroll
        for (int r = 0; r < 4; ++r) {
            int m = m0 + 16 * i + (lane >> 4) * 4 + r;
            int b = m / 3808;
            int rm = m % 3808;
            int y = rm / 112, x = rm % 112;
            #pragma unroll
            for (int j = 0; j < 4; ++j) {
                int n = 16 * j + lr;
                float v = fmaxf(acc[i][j][r] * scale[n] + bias[n], 0.f);
                out[((size_t)(b * 34 + y) * 112 + x) * 64 + n] = f2bf(v);
            }
        }
    }
}

// ---------------- maxpool 3x3 s2 p1 ----------------
__global__ __launch_bounds__(256) void pool_kernel(const ushort_t* __restrict__ in,
                                                   ushort_t* __restrict__ hal2) {
    int idx = blockIdx.x * 256 + threadIdx.x;
    const int total = 32 * 17 * 56 * 8;
    if (idx >= total) return;
    int c8 = idx & 7;
    int rest = idx >> 3;
    int x = rest % 56; rest /= 56;
    int y = rest % 17; int b = rest / 17;
    float mx[8];
    #pragma unroll
    for (int j = 0; j < 8; ++j) mx[j] = -INFINITY;
    for (int dy = -1; dy <= 1; ++dy) {
        int iy = 2 * y + dy;
        if ((unsigned)iy >= 34u) continue;
        for (int dx = -1; dx <= 1; ++dx) {
            int ix = 2 * x + dx;
            if ((unsigned)ix >= 112u) continue;
            bf16x8 v = *(const bf16x8*)(in + (((size_t)(b * 34 + iy)) * 112 + ix) * 64 + c8 * 8);
            #pragma unroll
            for (int j = 0; j < 8; ++j) mx[j] = fmaxf(mx[j], bf2f((unsigned short)v[j]));
        }
    }
    bf16x8 o;
    #pragma unroll
    for (int j = 0; j < 8; ++j) o[j] = (short)f2bf(mx[j]);
    *(bf16x8*)(hal2 + (((size_t)(b * 19 + y + 1)) * 58 + (x + 1)) * 64 + c8 * 8) = o;
}

// ---------------- implicit-GEMM 3x3 conv via MFMA, packed weights ----------------
template <int CIN, int HH, int WH, int STRIDE, int HOUT, int WOUT, int COUT, int MEMOUT, int OH, int OW>
__global__ __launch_bounds__(64) void conv_mfma(
    const ushort_t* __restrict__ in, const ushort_t* __restrict__ wtP,
    const float* __restrict__ scale, const float* __restrict__ bias,
    ushort_t* __restrict__ out, ushort_t* __restrict__ memT) {
    int lane = threadIdx.x;
    int mt = blockIdx.x, nt = blockIdx.y;
    int lr = lane & 15, kl = (lane >> 4) * 8;
    int rowoff[4];
    #pragma unroll
    for (int i = 0; i < 4; ++i) {
        int m = mt * 64 + 16 * i + lr;
        int b = m / (HOUT * WOUT);
        int rm = m % (HOUT * WOUT);
        int y = rm / WOUT, x = rm % WOUT;
        rowoff[i] = ((b * HH + y * STRIDE) * WH + x * STRIDE) * CIN + kl;
    }
    floatx4 acc[4][4];
    #pragma unroll
    for (int i = 0; i < 4; ++i)
        #pragma unroll
        for (int j = 0; j < 4; ++j) acc[i][j] = 0.f;

    #pragma unroll
    for (int ky = 0; ky < 3; ++ky) {
        #pragma unroll
        for (int kx = 0; kx < 3; ++kx) {
            int ioff = (ky * WH + kx) * CIN;
            int t = ky * 3 + kx;
            #pragma unroll
            for (int k0 = 0; k0 < CIN; k0 += 32) {
                bf16x8 a[4], bb[4];
                #pragma unroll
                for (int i = 0; i < 4; ++i)
                    a[i] = *(const bf16x8*)(in + rowoff[i] + ioff + k0);
                #pragma unroll
                for (int j = 0; j < 4; ++j)
                    bb[j] = *(const bf16x8*)(wtP + ((((size_t)(nt * 9 + t) * (CIN / 32) + (k0 >> 5)) * 4 + j) * 64 + lane) * 8);
                #pragma unroll
                for (int i = 0; i < 4; ++i)
                    #pragma unroll
                    for (int j = 0; j < 4; ++j)
                        acc[i][j] = __builtin_amdgcn_mfma_f32_16x16x32_bf16(a[i], bb[j], acc[i][j], 0, 0, 0);
            }
        }
    }
    #pragma unroll
    for (int i = 0; i < 4; ++i) {
        #pragma unroll
        for (int r = 0; r < 4; ++r) {
            int m = mt * 64 + 16 * i + (lane >> 4) * 4 + r;
            int b = m / (HOUT * WOUT);
            int rm = m % (HOUT * WOUT);
            int y = rm / WOUT, x = rm % WOUT;
            #pragma unroll
            for (int j = 0; j < 4; ++j) {
                int n = nt * 64 + 16 * j + lr;
                float v = fmaxf(acc[i][j][r] * scale[n] + bias[n], 0.f);
                ushort_t hv = f2bf(v);
                if (MEMOUT) {
                    out[(size_t)m * COUT + n] = hv;   // memory [b][196][768]
                    memT[(((size_t)b * 96 + (n >> 3)) * 196 + rm) * 8 + (n & 7)] = hv;
                } else {
                    out[((size_t)(b * OH + y + 1) * OW + (x + 1)) * COUT + n] = hv;
                }
            }
        }
    }
}

// ---------------- embedding gather -> PACKED bf16 e512P ----------------
// packed idx = (((mt*24+kq)*4+i)*64+lane)*8+e over rows r = t*32+b, cols k
__global__ __launch_bounds__(256) void gather_embP(const int* __restrict__ caps,
                                                   const float* __restrict__ table,
                                                   ushort_t* __restrict__ dst) {
    int idx = blockIdx.x * 256 + threadIdx.x;  // 512*768
    if (idx >= 512 * 768) return;
    int e = idx & 7, lane = (idx >> 3) & 63, i = (idx >> 9) & 3;
    int t2 = idx >> 11;
    int kq = t2 % 24, mt = t2 / 24;
    int r = mt * 64 + i * 16 + (lane & 15);
    int k = kq * 32 + (lane >> 4) * 8 + e;
    int t = r >> 5, b = r & 31;
    dst[idx] = f2bf(table[(size_t)caps[b * NT + t] * NH + k]);
}

// ---------------- fused pack+GEMM: C[M=512][N] = Ap . bf16(B_f32)^T + bias ----------------
// A packed ([8 mt][24 kq][4 i][64 lane][8 e], K=768). B f32 row-major [N][ldb], cols 0..767.
// grid N/64 blocks, block 256 = 4 waves; wave w computes m-tiles {w, w+4}.
// Per K-chunk (32): coalesced f32 B-tile read -> in-register bf16 -> LDS in fragment order.
template <int REMAP>
__global__ __launch_bounds__(256) void gemm_fused(
    const ushort_t* __restrict__ Ap, const float* __restrict__ B,
    const float* __restrict__ bias1, const float* __restrict__ bias2,
    float* __restrict__ C, int ldb, int N) {
    __shared__ ushort_t bl[2048];  // 4 KB: [4 j][64 lane][8 e]
    int tid = threadIdx.x;
    int lane = tid & 63, w = tid >> 6;
    int nt = blockIdx.x;
    // staging coords: thread reads B row (nt*64 + r), 8 cols at c0 within chunk
    int r = tid >> 2, c0 = (tid & 3) * 8;
    const float* bsrc = B + (size_t)(nt * 64 + r) * ldb + c0;
    ushort_t* wslot = bl + (((r >> 4) * 64 + ((r & 15) | ((tid & 3) << 4))) * 8);
    floatx4 acc[2][4][4];
    #pragma unroll
    for (int h = 0; h < 2; ++h)
        #pragma unroll
        for (int i = 0; i < 4; ++i)
            #pragma unroll
            for (int j = 0; j < 4; ++j) acc[h][i][j] = 0.f;
    float4 x0 = *(const float4*)(bsrc);
    float4 x1 = *(const float4*)(bsrc + 4);
    for (int kq = 0; kq < 24; ++kq) {
        __syncthreads();   // previous chunk's compute done
        bf16x8 t8;
        t8[0] = (short)f2bf(x0.x); t8[1] = (short)f2bf(x0.y);
        t8[2] = (short)f2bf(x0.z); t8[3] = (short)f2bf(x0.w);
        t8[4] = (short)f2bf(x1.x); t8[5] = (short)f2bf(x1.y);
        t8[6] = (short)f2bf(x1.z); t8[7] = (short)f2bf(x1.w);
        *(bf16x8*)wslot = t8;
        if (kq < 23) {   // prefetch next chunk while compute runs
            const float* p = bsrc + (size_t)(kq + 1) * 32;
            x0 = *(const float4*)(p);
            x1 = *(const float4*)(p + 4);
        }
        __syncthreads();
        bf16x8 bb[4];
        #pragma unroll
        for (int j = 0; j < 4; ++j) bb[j] = *(const bf16x8*)(bl + ((j * 64 + lane) * 8));
        #pragma unroll
        for (int h = 0; h < 2; ++h) {
            int mt = w + h * 4;
            bf16x8 a[4];
            #pragma unroll
            for (int i = 0; i < 4; ++i)
                a[i] = *(const bf16x8*)(Ap + ((((size_t)mt * 24 + kq) * 4 + i) * 64 + lane) * 8);
            #pragma unroll
            for (int i = 0; i < 4; ++i)
                #pragma unroll
                for (int j = 0; j < 4; ++j)
                    acc[h][i][j] = __builtin_amdgcn_mfma_f32_16x16x32_bf16(a[i], bb[j], acc[h][i][j], 0, 0, 0);
        }
    }
    int lr = lane & 15;
    #pragma unroll
    for (int h = 0; h < 2; ++h) {
        int mt = w + h * 4;
        #pragma unroll
        for (int i = 0; i < 4; ++i) {
            #pragma unroll
            for (int rr = 0; rr < 4; ++rr) {
                int m = mt * 64 + 16 * i + (lane >> 4) * 4 + rr;   // m = t*32+b
                #pragma unroll
                for (int j = 0; j < 4; ++j) {
                    int n = nt * 64 + 16 * j + lr;
                    float v = acc[h][i][j][rr];
                    if (bias1) v += bias1[n];
                    if (bias2) v += bias2[n];
                    if (REMAP) {
                        int t = m >> 5, b = m & 31;
                        C[(size_t)((b << 4) + t) * NV + n] = v;
                    } else {
                        C[(size_t)m * N + n] = v;
                    }
                }
            }
        }
    }
}

// ---------------- fused attention ----------------
// grid 32 (batch), block 768. xin = [ctx | h] bf16 [32][1536] (reads h, writes ctx).
__global__ __launch_bounds__(768) void attn_fused(
    ushort_t* __restrict__ xin, const ushort_t* __restrict__ wattnP,
    const ushort_t* __restrict__ mem, const ushort_t* __restrict__ memT) {
    __shared__ float q[NH];
    __shared__ float sl[196];
    __shared__ float red[16];
    int b = blockIdx.x, tid = threadIdx.x;
    // phase 1: q[tid] = h . attn_w[tid]  (wattnP coalesced per k8)
    {
        const bf16x8* h8 = (const bf16x8*)(xin + (size_t)b * 1536 + NH);
        float acc = 0.f;
        #pragma unroll 4
        for (int k8 = 0; k8 < 96; ++k8) {
            bf16x8 a = h8[k8];
            bf16x8 w = *(const bf16x8*)(wattnP + ((size_t)k8 * 768 + tid) * 8);
            #pragma unroll
            for (int j = 0; j < 8; ++j)
                acc = fmaf(bf2f((unsigned short)a[j]), bf2f((unsigned short)w[j]), acc);
        }
        q[tid] = acc;
    }
    __syncthreads();
    // phase 2: scores via memT (coalesced over m), 2 threads per m
    if (tid < 392) {
        int m = tid >> 1, half = tid & 1;
        const ushort_t* basep = memT + (((size_t)b * 96 + half * 48) * 196 + m) * 8;
        float acc = 0.f;
        #pragma unroll 4
        for (int k8 = 0; k8 < 48; ++k8) {
            bf16x8 v = *(const bf16x8*)(basep + (size_t)k8 * 196 * 8);
            const float* qp = q + (half * 48 + k8) * 8;
            #pragma unroll
            for (int j = 0; j < 8; ++j)
                acc = fmaf(bf2f((unsigned short)v[j]), qp[j], acc);
        }
        acc += __shfl_xor(acc, 1);
        if (!half) sl[m] = acc;
    }
    __syncthreads();
    // phase 3: softmax over 196
    float sc = (tid < 196) ? sl[tid] : -INFINITY;
    float v = sc;
    #pragma unroll
    for (int off = 32; off; off >>= 1) v = fmaxf(v, __shfl_down(v, off));
    if ((tid & 63) == 0) red[tid >> 6] = v;
    __syncthreads();
    if (tid == 0) {
        float m = red[0];
        for (int i = 1; i < 12; ++i) m = fmaxf(m, red[i]);
        red[12] = m;
    }
    __syncthreads();
    float mx = red[12];
    float e = (tid < 196) ? expf(sc - mx) : 0.f;
    __syncthreads();
    v = e;
    #pragma unroll
    for (int off = 32; off; off >>= 1) v += __shfl_down(v, off);
    if ((tid & 63) == 0) red[tid >> 6] = v;
    __syncthreads();
    if (tid == 0) {
        float s = red[0];
        for (int i = 1; i < 12; ++i) s += red[i];
        red[12] = 1.f / s;
    }
    __syncthreads();
    if (tid < 196) sl[tid] = e * red[12];
    __syncthreads();
    // phase 4: ctx[tid] = sum_m p[m]*mem[b][m][tid]
    {
        float acc = 0.f;
        const ushort_t* mb = mem + (size_t)b * 196 * NH + tid;
        #pragma unroll 4
        for (int m = 0; m < 196; ++m) acc = fmaf(sl[m], bf2f(mb[(size_t)m * NH]), acc);
        xin[(size_t)b * 1536 + tid] = f2bf(acc);
    }
}

// ---------------- fused gates GEMM + LSTM cell; writes Hall PACKED ----------------
// grid 48, block 256 (4 waves = 4-way K split). Block bx covers cols bx*16..bx*16+15 of each gate.
__global__ __launch_bounds__(256) void step_fused(
    const ushort_t* __restrict__ xin_r, const ushort_t* __restrict__ wcombP,
    const float* __restrict__ eg_t,
    float* __restrict__ cbuf, float* __restrict__ hbuf,
    ushort_t* __restrict__ xin_w, ushort_t* __restrict__ hallP, int tstep) {
    __shared__ float pbuf[4][64][33];
    int lane = threadIdx.x & 63, w = threadIdx.x >> 6;
    int bx = blockIdx.x;
    int lr = lane & 15, kl = (lane >> 4) * 8;
    floatx4 acc[2][4];
    #pragma unroll
    for (int i = 0; i < 2; ++i)
        #pragma unroll
        for (int g = 0; g < 4; ++g) acc[i][g] = 0.f;
    for (int kq = 0; kq < 12; ++kq) {
        int k = w * 384 + kq * 32;
        bf16x8 a[2], bb[4];
        #pragma unroll
        for (int i = 0; i < 2; ++i)
            a[i] = *(const bf16x8*)(xin_r + (size_t)(16 * i + lr) * 1536 + k + kl);
        #pragma unroll
        for (int g = 0; g < 4; ++g)
            bb[g] = *(const bf16x8*)(wcombP + (((size_t)(bx * 4 + g) * 48 + (w * 12 + kq)) * 64 + lane) * 8);
        #pragma unroll
        for (int i = 0; i < 2; ++i)
            #pragma unroll
            for (int g = 0; g < 4; ++g)
                acc[i][g] = __builtin_amdgcn_mfma_f32_16x16x32_bf16(a[i], bb[g], acc[i][g], 0, 0, 0);
    }
    #pragma unroll
    for (int i = 0; i < 2; ++i)
        #pragma unroll
        for (int g = 0; g < 4; ++g)
            #pragma unroll
            for (int r = 0; r < 4; ++r) {
                int m = 16 * i + (lane >> 4) * 4 + r;
                pbuf[w][g * 16 + lr][m] = acc[i][g][r];
            }
    __syncthreads();
    int tid = threadIdx.x;
    #pragma unroll
    for (int o = 0; o < 2; ++o) {
        int pid = tid * 2 + o;          // 0..511
        int m = pid & 31, c = pid >> 5; // m = batch, c = 0..15
        int kcol = bx * 16 + c;
        float gi = 0.f, gf = 0.f, gg = 0.f, go = 0.f;
        #pragma unroll
        for (int ww = 0; ww < 4; ++ww) {
            gi += pbuf[ww][c][m];
            gf += pbuf[ww][16 + c][m];
            gg += pbuf[ww][32 + c][m];
            go += pbuf[ww][48 + c][m];
        }
        const float* eg = eg_t + (size_t)m * 3072;
        gi += eg[kcol];
        gf += eg[768 + kcol];
        gg += eg[1536 + kcol];
        go += eg[2304 + kcol];
        float cst = cbuf[m * 768 + kcol];
        float cn = sigmoidf_(gf) * cst + sigmoidf_(gi) * tanhf(gg);
        float hn = sigmoidf_(go) * tanhf(cn);
        cbuf[m * 768 + kcol] = cn;
        hbuf[m * 768 + kcol] = hn;
        ushort_t hb = f2bf(hn);
        xin_w[(size_t)m * 1536 + NH + kcol] = hb;
        // packed Hall write: row r = tstep*32+m, col kcol
        int rrow = tstep * 32 + m;
        int mtp = rrow >> 6, ip = (rrow >> 4) & 3, lrp = rrow & 15;
        int kqp = kcol >> 5, hip = (kcol >> 3) & 3, ep = kcol & 7;
        hallP[((((size_t)mtp * 24 + kqp) * 4 + ip) * 64 + (lrp | (hip << 4))) * 8 + ep] = hb;
    }
}

__global__ __launch_bounds__(256) void zero_state(float* __restrict__ h, float* __restrict__ c,
                                                  ushort_t* __restrict__ xin) {
    int i = blockIdx.x * 256 + threadIdx.x;
    if (i < NB * 1536) xin[i] = 0;
    if (i < NB * NH) { h[i] = 0.f; c[i] = 0.f; }
}

__global__ __launch_bounds__(256) void copy_hc(const float* __restrict__ h, const float* __restrict__ c,
                                               float* __restrict__ out) {
    int i = blockIdx.x * 256 + threadIdx.x;
    if (i < NB * NH) {
        out[(size_t)NB * NT * NV + i] = h[i];
        out[(size_t)NB * NT * NV + NB * NH + i] = c[i];
    }
}

extern "C" void kernel_launch(void* const* d_in, const int* in_sizes, int n_in,
                              void* d_out, int out_size, void* d_ws, size_t ws_size,
                              hipStream_t stream) {
    const float* images   = (const float*)d_in[0];
    const int*   captions = (const int*)d_in[1];
    const float* conv1_w  = (const float*)d_in[2];
    const float* bn1_g = (const float*)d_in[3], *bn1_b = (const float*)d_in[4];
    const float* bn1_m = (const float*)d_in[5], *bn1_v = (const float*)d_in[6];
    const float* conv2_w  = (const float*)d_in[7];
    const float* bn2_g = (const float*)d_in[8], *bn2_b = (const float*)d_in[9];
    const float* bn2_m = (const float*)d_in[10], *bn2_v = (const float*)d_in[11];
    const float* conv3_w  = (const float*)d_in[12];
    const float* bn3_g = (const float*)d_in[13], *bn3_b = (const float*)d_in[14];
    const float* bn3_m = (const float*)d_in[15], *bn3_v = (const float*)d_in[16];
    const float* conv4_w  = (const float*)d_in[17];
    const float* bn4_g = (const float*)d_in[18], *bn4_b = (const float*)d_in[19];
    const float* bn4_m = (const float*)d_in[20], *bn4_v = (const float*)d_in[21];
    const float* emb_table = (const float*)d_in[22];
    const float* attn_w   = (const float*)d_in[23];
    const float* w_ih     = (const float*)d_in[24];
    const float* w_hh     = (const float*)d_in[25];
    const float* b_ih     = (const float*)d_in[26];
    const float* b_hh     = (const float*)d_in[27];
    const float* fc_w     = (const float*)d_in[28];
    const float* fc_b     = (const float*)d_in[29];
    float* out = (float*)d_out;

    // ---- workspace layout ----
    char* base = (char*)d_ws;
    size_t off = 0;
    auto alloc = [&](size_t bytes) { char* p = base + off; off += (bytes + 255) & ~(size_t)255; return p; };
    float* s1 = (float*)alloc(64 * 4);   float* bb1 = (float*)alloc(64 * 4);
    float* s2 = (float*)alloc(128 * 4);  float* bb2 = (float*)alloc(128 * 4);
    float* s3 = (float*)alloc(256 * 4);  float* bb3 = (float*)alloc(256 * 4);
    float* s4 = (float*)alloc(768 * 4);  float* bb4 = (float*)alloc(768 * 4);
    ushort_t* c1out = (ushort_t*)alloc((size_t)32 * 34 * 112 * 64 * 2);
    size_t halo_start = off;
    ushort_t* hal2 = (ushort_t*)alloc((size_t)32 * 19 * 58 * 64 * 2);
    ushort_t* hal3 = (ushort_t*)alloc((size_t)32 * 18 * 58 * 128 * 2);
    ushort_t* hal4 = (ushort_t*)alloc((size_t)32 * 10 * 30 * 256 * 2);
    size_t halo_bytes = off - halo_start;
    ushort_t* memv = (ushort_t*)alloc((size_t)32 * 196 * 768 * 2);
    ushort_t* memT = (ushort_t*)alloc((size_t)32 * 96 * 196 * 8 * 2);
    ushort_t* wb1 = (ushort_t*)alloc((size_t)64 * 160 * 2);
    ushort_t* wb2 = (ushort_t*)alloc((size_t)128 * 9 * 64 * 2);
    ushort_t* wb3 = (ushort_t*)alloc((size_t)256 * 9 * 128 * 2);
    ushort_t* wb4 = (ushort_t*)alloc((size_t)768 * 9 * 256 * 2);
    ushort_t* wattnP = (ushort_t*)alloc((size_t)768 * 768 * 2);
    ushort_t* wcombP = (ushort_t*)alloc((size_t)3072 * 1536 * 2);
    ushort_t* e512P = (ushort_t*)alloc((size_t)512 * 768 * 2);
    float* eg   = (float*)alloc((size_t)512 * 3072 * 4);
    ushort_t* HallP = (ushort_t*)alloc((size_t)512 * 768 * 2);
    float* hbuf = (float*)alloc(NB * NH * 4);
    float* cbuf = (float*)alloc(NB * NH * 4);
    ushort_t* xinA = (ushort_t*)alloc((size_t)NB * 1536 * 2);
    ushort_t* xinB = (ushort_t*)alloc((size_t)NB * 1536 * 2);
    ushort_t* imcol = (ushort_t*)alloc((size_t)121856 * 160 * 2);

    // ---- one-time transforms ----
    bn_prep<<<1, 256, 0, stream>>>(bn1_g, bn1_b, bn1_m, bn1_v, s1, bb1, 64);
    bn_prep<<<1, 256, 0, stream>>>(bn2_g, bn2_b, bn2_m, bn2_v, s2, bb2, 128);
    bn_prep<<<1, 256, 0, stream>>>(bn3_g, bn3_b, bn3_m, bn3_v, s3, bb3, 256);
    bn_prep<<<3, 256, 0, stream>>>(bn4_g, bn4_b, bn4_m, bn4_v, s4, bb4, 768);
    cvt_pad<<<(64 * 160 + 255) / 256, 256, 0, stream>>>(conv1_w, wb1);
    cvt_packW_conv<<<(128 * 9 * 64 + 255) / 256, 256, 0, stream>>>(conv2_w, wb2, 64, 128 * 9 * 64);
    cvt_packW_conv<<<(256 * 9 * 128 + 255) / 256, 256, 0, stream>>>(conv3_w, wb3, 128, 256 * 9 * 128);
    cvt_packW_conv<<<(768 * 9 * 256 + 255) / 256, 256, 0, stream>>>(conv4_w, wb4, 256, 768 * 9 * 256);
    cvt_wattnP<<<(768 * 768 + 255) / 256, 256, 0, stream>>>(attn_w, wattnP);
    cvt_wcombP<<<(3072 * 1536 + 255) / 256, 256, 0, stream>>>(w_ih, w_hh, wcombP);
    {
        long long n8 = (long long)(halo_bytes / 8);
        zfill<<<(unsigned)((n8 + 255) / 256), 256, 0, stream>>>((unsigned long long*)hal2, n8);
    }

    // ---- encoder ----
    im2col1<<<(121856 * 160 + 255) / 256, 256, 0, stream>>>(images, imcol);
    conv1_gemm<<<476, 256, 0, stream>>>(imcol, wb1, s1, bb1, c1out);
    pool_kernel<<<(32 * 17 * 56 * 8 + 255) / 256, 256, 0, stream>>>(c1out, hal2);
    conv_mfma<64, 19, 58, 1, 16, 56, 128, 0, 18, 58>
        <<<dim3(448, 2), 64, 0, stream>>>(hal2, wb2, s2, bb2, hal3, nullptr);
    conv_mfma<128, 18, 58, 2, 8, 28, 256, 0, 10, 30>
        <<<dim3(112, 4), 64, 0, stream>>>(hal3, wb3, s3, bb3, hal4, nullptr);
    conv_mfma<256, 10, 30, 1, 7, 28, 768, 1, 1, 1>
        <<<dim3(98, 12), 64, 0, stream>>>(hal4, wb4, s4, bb4, memv, memT);

    // ---- decoder precompute: eg = e @ w_ih[:, :768]^T + b_ih + b_hh (fused pack+GEMM) ----
    gather_embP<<<(512 * 768) / 256, 256, 0, stream>>>(captions, emb_table, e512P);
    gemm_fused<0><<<48, 256, 0, stream>>>(e512P, w_ih, b_ih, b_hh, eg, 2 * NH, 3072);
    zero_state<<<(NB * 1536 + 255) / 256, 256, 0, stream>>>(hbuf, cbuf, xinA);

    // ---- sequential decoder (xin double-buffered) ----
    ushort_t* xcur = xinA;
    ushort_t* xnxt = xinB;
    for (int t = 0; t < NT; ++t) {
        attn_fused<<<NB, NH, 0, stream>>>(xcur, wattnP, memv, memT);
        step_fused<<<48, 256, 0, stream>>>(
            xcur, wcombP, eg + (size_t)t * NB * 3072, cbuf, hbuf, xnxt, HallP, t);
        ushort_t* tmp = xcur; xcur = xnxt; xnxt = tmp;
    }

    // ---- vocab projection for all 16 steps at once (fused pack+GEMM) ----
    gemm_fused<1><<<500, 256, 0, stream>>>(HallP, fc_w, fc_b, nullptr, out, NH, NV);

    copy_hc<<<(NB * NH + 255) / 256, 256, 0, stream>>>(hbuf, cbuf, out);
}

// Round 7
// 958.728 us; speedup vs baseline: 8.9421x; 1.1888x over previous
//
#include <hip/hip_runtime.h>
#include <math.h>

#define NB 32
#define NT 16
#define NH 768
#define NV 32000

typedef short bf16x8 __attribute__((ext_vector_type(8)));
typedef float floatx4 __attribute__((ext_vector_type(4)));
typedef unsigned short ushort_t;

__device__ __forceinline__ float bf2f(unsigned short h) {
    unsigned u = ((unsigned)h) << 16;
    return __builtin_bit_cast(float, u);
}
__device__ __forceinline__ unsigned short f2bf(float f) {
    unsigned u = __builtin_bit_cast(unsigned, f);
    u += 0x7fffu + ((u >> 16) & 1u);
    return (unsigned short)(u >> 16);
}
__device__ __forceinline__ float sigmoidf_(float x) { return 1.f / (1.f + expf(-x)); }

// ---------------- BN scale/bias precompute ----------------
__global__ void bn_prep(const float* __restrict__ g, const float* __restrict__ b,
                        const float* __restrict__ m, const float* __restrict__ v,
                        float* __restrict__ scale, float* __restrict__ bias, int C) {
    int i = blockIdx.x * 256 + threadIdx.x;
    if (i < C) {
        float inv = g[i] * rsqrtf(v[i] + 1e-5f);
        scale[i] = inv;
        bias[i] = b[i] - m[i] * inv;
    }
}

__global__ __launch_bounds__(256) void zfill(unsigned long long* __restrict__ p, long long n) {
    long long i = (long long)blockIdx.x * 256 + threadIdx.x;
    if (i < n) p[i] = 0ULL;
}

// conv weights OIHW f32 -> packed per (nt, tap, kq): idx = ((((nt*9+t)*KQ+kq)*4+j)*64+lane)*8+e
__global__ __launch_bounds__(256) void cvt_packW_conv(const float* __restrict__ w, ushort_t* __restrict__ dst,
                                                      int CIN, int total) {
    int idx = blockIdx.x * 256 + threadIdx.x;
    if (idx >= total) return;
    int e = idx & 7, lane = (idx >> 3) & 63, j = (idx >> 9) & 3;
    int r = idx >> 11;
    int KQ = CIN >> 5;
    int kq = r % KQ; r /= KQ;
    int tap = r % 9; int nt = r / 9;
    int co = nt * 64 + j * 16 + (lane & 15);
    int ci = kq * 32 + (lane >> 4) * 8 + e;
    dst[idx] = f2bf(w[((size_t)co * CIN + ci) * 9 + tap]);
}

// wcombP: block bx (48), gate g (4), kq (48), lane: row = g*768+bx*16+(lane&15); k<768->w_ih ctx-half, else w_hh
__global__ __launch_bounds__(256) void cvt_wcombP(const float* __restrict__ w_ih, const float* __restrict__ w_hh,
                                                  ushort_t* __restrict__ dst) {
    int idx = blockIdx.x * 256 + threadIdx.x;
    if (idx >= 3072 * 1536) return;
    int e = idx & 7, lane = (idx >> 3) & 63;
    int t = idx >> 9;
    int kq = t % 48, gg = t / 48;
    int g = gg & 3, bx = gg >> 2;
    int j = g * 768 + bx * 16 + (lane & 15);
    int k = kq * 32 + (lane >> 4) * 8 + e;
    float v = (k < NH) ? w_ih[(size_t)j * (2 * NH) + NH + k] : w_hh[(size_t)j * NH + (k - NH)];
    dst[idx] = f2bf(v);
}

// wattnT packed for kmat: fragment holds W^T[n][k] = attn_w[k][n]
__global__ __launch_bounds__(256) void cvt_wattnTP(const float* __restrict__ w, ushort_t* __restrict__ dst) {
    int idx = blockIdx.x * 256 + threadIdx.x;
    if (idx >= 768 * 768) return;
    int e = idx & 7, lane = (idx >> 3) & 63, j = (idx >> 9) & 3;
    int t = idx >> 11;
    int kq = t % 24, nt = t / 24;
    int n = nt * 64 + 16 * j + (lane & 15);
    int k = kq * 32 + (lane >> 4) * 8 + e;
    dst[idx] = f2bf(w[(size_t)k * 768 + n]);
}

// conv1 weights: [64][147] f32 -> [64][160] bf16 (zero pad)
__global__ __launch_bounds__(256) void cvt_pad(const float* __restrict__ src, ushort_t* __restrict__ dst) {
    int idx = blockIdx.x * 256 + threadIdx.x;
    if (idx >= 64 * 160) return;
    int co = idx / 160, k = idx % 160;
    dst[idx] = (k < 147) ? f2bf(src[co * 147 + k]) : (ushort_t)0;
}

// ---------------- conv1 im2col: [121856][160] bf16 ----------------
__global__ __launch_bounds__(256) void im2col1(const float* __restrict__ img, ushort_t* __restrict__ A) {
    int idx = blockIdx.x * 256 + threadIdx.x;
    const int total = 121856 * 160;
    if (idx >= total) return;
    int k = idx % 160;
    int m = idx / 160;
    ushort_t v = 0;
    if (k < 147) {
        int b = m / 3808;
        int rm = m % 3808;
        int y = rm / 112, x = rm % 112;
        int ci = k / 49;
        int r = k % 49;
        int ky = r / 7, kx = r % 7;
        int iy = 2 * y - 3 + ky;
        int ix = 2 * x - 3 + kx;
        if ((unsigned)iy < 224u && (unsigned)ix < 224u)
            v = f2bf(img[((size_t)(b * 3 + ci) * 224 + iy) * 224 + ix]);
    }
    A[idx] = v;
}

// ---------------- conv1 GEMM: [121856][160] x [64][160]^T ----------------
__global__ __launch_bounds__(256) void conv1_gemm(
    const ushort_t* __restrict__ A, const ushort_t* __restrict__ Bw,
    const float* __restrict__ scale, const float* __restrict__ bias,
    ushort_t* __restrict__ out) {
    int lane = threadIdx.x & 63, w = threadIdx.x >> 6;
    int m0 = (blockIdx.x * 4 + w) * 64;
    int lr = lane & 15, kl = (lane >> 4) * 8;
    floatx4 acc[4][4];
    #pragma unroll
    for (int i = 0; i < 4; ++i)
        #pragma unroll
        for (int j = 0; j < 4; ++j) acc[i][j] = 0.f;
    #pragma unroll
    for (int k0 = 0; k0 < 160; k0 += 32) {
        bf16x8 a[4], bb[4];
        #pragma unroll
        for (int i = 0; i < 4; ++i) a[i] = *(const bf16x8*)(A + (size_t)(m0 + 16 * i + lr) * 160 + kl + k0);
        #pragma unroll
        for (int j = 0; j < 4; ++j) bb[j] = *(const bf16x8*)(Bw + (size_t)(16 * j + lr) * 160 + kl + k0);
        #pragma unroll
        for (int i = 0; i < 4; ++i)
            #pragma unroll
            for (int j = 0; j < 4; ++j)
                acc[i][j] = __builtin_amdgcn_mfma_f32_16x16x32_bf16(a[i], bb[j], acc[i][j], 0, 0, 0);
    }
    #pragma unroll
    for (int i = 0; i < 4; ++i) {
        #pragma unroll
        for (int r = 0; r < 4; ++r) {
            int m = m0 + 16 * i + (lane >> 4) * 4 + r;
            int b = m / 3808;
            int rm = m % 3808;
            int y = rm / 112, x = rm % 112;
            #pragma unroll
            for (int j = 0; j < 4; ++j) {
                int n = 16 * j + lr;
                float v = fmaxf(acc[i][j][r] * scale[n] + bias[n], 0.f);
                out[((size_t)(b * 34 + y) * 112 + x) * 64 + n] = f2bf(v);
            }
        }
    }
}

// ---------------- maxpool 3x3 s2 p1 ----------------
__global__ __launch_bounds__(256) void pool_kernel(const ushort_t* __restrict__ in,
                                                   ushort_t* __restrict__ hal2) {
    int idx = blockIdx.x * 256 + threadIdx.x;
    const int total = 32 * 17 * 56 * 8;
    if (idx >= total) return;
    int c8 = idx & 7;
    int rest = idx >> 3;
    int x = rest % 56; rest /= 56;
    int y = rest % 17; int b = rest / 17;
    float mx[8];
    #pragma unroll
    for (int j = 0; j < 8; ++j) mx[j] = -INFINITY;
    for (int dy = -1; dy <= 1; ++dy) {
        int iy = 2 * y + dy;
        if ((unsigned)iy >= 34u) continue;
        for (int dx = -1; dx <= 1; ++dx) {
            int ix = 2 * x + dx;
            if ((unsigned)ix >= 112u) continue;
            bf16x8 v = *(const bf16x8*)(in + (((size_t)(b * 34 + iy)) * 112 + ix) * 64 + c8 * 8);
            #pragma unroll
            for (int j = 0; j < 8; ++j) mx[j] = fmaxf(mx[j], bf2f((unsigned short)v[j]));
        }
    }
    bf16x8 o;
    #pragma unroll
    for (int j = 0; j < 8; ++j) o[j] = (short)f2bf(mx[j]);
    *(bf16x8*)(hal2 + (((size_t)(b * 19 + y + 1)) * 58 + (x + 1)) * 64 + c8 * 8) = o;
}

// ---------------- implicit-GEMM 3x3 conv via MFMA, packed weights ----------------
template <int CIN, int HH, int WH, int STRIDE, int HOUT, int WOUT, int COUT, int MEMOUT, int OH, int OW>
__global__ __launch_bounds__(64) void conv_mfma(
    const ushort_t* __restrict__ in, const ushort_t* __restrict__ wtP,
    const float* __restrict__ scale, const float* __restrict__ bias,
    ushort_t* __restrict__ out) {
    int lane = threadIdx.x;
    int mt = blockIdx.x, nt = blockIdx.y;
    int lr = lane & 15, kl = (lane >> 4) * 8;
    int rowoff[4];
    #pragma unroll
    for (int i = 0; i < 4; ++i) {
        int m = mt * 64 + 16 * i + lr;
        int b = m / (HOUT * WOUT);
        int rm = m % (HOUT * WOUT);
        int y = rm / WOUT, x = rm % WOUT;
        rowoff[i] = ((b * HH + y * STRIDE) * WH + x * STRIDE) * CIN + kl;
    }
    floatx4 acc[4][4];
    #pragma unroll
    for (int i = 0; i < 4; ++i)
        #pragma unroll
        for (int j = 0; j < 4; ++j) acc[i][j] = 0.f;

    #pragma unroll
    for (int ky = 0; ky < 3; ++ky) {
        #pragma unroll
        for (int kx = 0; kx < 3; ++kx) {
            int ioff = (ky * WH + kx) * CIN;
            int t = ky * 3 + kx;
            #pragma unroll
            for (int k0 = 0; k0 < CIN; k0 += 32) {
                bf16x8 a[4], bb[4];
                #pragma unroll
                for (int i = 0; i < 4; ++i)
                    a[i] = *(const bf16x8*)(in + rowoff[i] + ioff + k0);
                #pragma unroll
                for (int j = 0; j < 4; ++j)
                    bb[j] = *(const bf16x8*)(wtP + ((((size_t)(nt * 9 + t) * (CIN / 32) + (k0 >> 5)) * 4 + j) * 64 + lane) * 8);
                #pragma unroll
                for (int i = 0; i < 4; ++i)
                    #pragma unroll
                    for (int j = 0; j < 4; ++j)
                        acc[i][j] = __builtin_amdgcn_mfma_f32_16x16x32_bf16(a[i], bb[j], acc[i][j], 0, 0, 0);
            }
        }
    }
    #pragma unroll
    for (int i = 0; i < 4; ++i) {
        #pragma unroll
        for (int r = 0; r < 4; ++r) {
            int m = mt * 64 + 16 * i + (lane >> 4) * 4 + r;
            int b = m / (HOUT * WOUT);
            int rm = m % (HOUT * WOUT);
            int y = rm / WOUT, x = rm % WOUT;
            #pragma unroll
            for (int j = 0; j < 4; ++j) {
                int n = nt * 64 + 16 * j + lr;
                float v = fmaxf(acc[i][j][r] * scale[n] + bias[n], 0.f);
                ushort_t hv = f2bf(v);
                if (MEMOUT) {
                    out[(size_t)m * COUT + n] = hv;   // memory [b][196][768]
                } else {
                    out[((size_t)(b * OH + y + 1) * OW + (x + 1)) * COUT + n] = hv;
                }
            }
        }
    }
}

// ---------------- kmat: K~[b] = mem[b] @ attn_w  -> KT layout [b][96][196][8] bf16 ----------------
// M = 32*196 = 6272 rows of memv, N = 768. grid (98, 12), block 64.
__global__ __launch_bounds__(64) void kmat_gemm(
    const ushort_t* __restrict__ memv, const ushort_t* __restrict__ Bp,
    ushort_t* __restrict__ KT) {
    int lane = threadIdx.x;
    int mt = blockIdx.x, nt = blockIdx.y;
    int lr = lane & 15, kl = (lane >> 4) * 8;
    floatx4 acc[4][4];
    #pragma unroll
    for (int i = 0; i < 4; ++i)
        #pragma unroll
        for (int j = 0; j < 4; ++j) acc[i][j] = 0.f;
    for (int kq = 0; kq < 24; ++kq) {
        bf16x8 a[4], bb[4];
        #pragma unroll
        for (int i = 0; i < 4; ++i)
            a[i] = *(const bf16x8*)(memv + (size_t)(mt * 64 + 16 * i + lr) * 768 + kq * 32 + kl);
        #pragma unroll
        for (int j = 0; j < 4; ++j)
            bb[j] = *(const bf16x8*)(Bp + (((size_t)(nt * 24 + kq) * 4 + j) * 64 + lane) * 8);
        #pragma unroll
        for (int i = 0; i < 4; ++i)
            #pragma unroll
            for (int j = 0; j < 4; ++j)
                acc[i][j] = __builtin_amdgcn_mfma_f32_16x16x32_bf16(a[i], bb[j], acc[i][j], 0, 0, 0);
    }
    #pragma unroll
    for (int i = 0; i < 4; ++i) {
        #pragma unroll
        for (int r = 0; r < 4; ++r) {
            int mg = mt * 64 + 16 * i + (lane >> 4) * 4 + r;
            int b = mg / 196, m = mg % 196;
            #pragma unroll
            for (int j = 0; j < 4; ++j) {
                int n = nt * 64 + 16 * j + lr;
                KT[(((size_t)b * 96 + (n >> 3)) * 196 + m) * 8 + (n & 7)] = f2bf(acc[i][j][r]);
            }
        }
    }
}

// ---------------- embedding gather -> PACKED bf16 e512P ----------------
__global__ __launch_bounds__(256) void gather_embP(const int* __restrict__ caps,
                                                   const float* __restrict__ table,
                                                   ushort_t* __restrict__ dst) {
    int idx = blockIdx.x * 256 + threadIdx.x;  // 512*768
    if (idx >= 512 * 768) return;
    int e = idx & 7, lane = (idx >> 3) & 63, i = (idx >> 9) & 3;
    int t2 = idx >> 11;
    int kq = t2 % 24, mt = t2 / 24;
    int r = mt * 64 + i * 16 + (lane & 15);
    int k = kq * 32 + (lane >> 4) * 8 + e;
    int t = r >> 5, b = r & 31;
    dst[idx] = f2bf(table[(size_t)caps[b * NT + t] * NH + k]);
}

// ---------------- 2-stage staged pack+GEMM: C[512][N] = Ap . bf16(B_f32)^T + bias ----------------
// A packed ([8 mt][24 kq][4 i][64 lane][8 e], K=768). B f32 row-major [N][ldb], cols 0..767.
// grid N/64, block 256 = 4 waves; wave w -> m-tiles {w, w+4}. LDS stages K-halves (384) => 48KB.
template <int REMAP>
__global__ __launch_bounds__(256) void gemm_staged(
    const ushort_t* __restrict__ Ap, const float* __restrict__ B,
    const float* __restrict__ bias1, const float* __restrict__ bias2,
    float* __restrict__ C, int ldb, int N) {
    __shared__ ushort_t bl[12 * 2048];  // 49152 B: [12 kq][4 j][64 lane][8 e]
    int tid = threadIdx.x;
    int lane = tid & 63, w = tid >> 6;
    int nt = blockIdx.x;
    int r = tid >> 2, c0 = (tid & 3) * 8;
    const float* bsrc = B + (size_t)(nt * 64 + r) * ldb + c0;
    ushort_t* wbase = bl + (((r >> 4) * 64 + ((r & 15) | ((tid & 3) << 4))) * 8);
    floatx4 acc[2][4][4];
    #pragma unroll
    for (int h = 0; h < 2; ++h)
        #pragma unroll
        for (int i = 0; i < 4; ++i)
            #pragma unroll
            for (int j = 0; j < 4; ++j) acc[h][i][j] = 0.f;

    bf16x8 v[12];
    // load stage 0
    #pragma unroll
    for (int kk = 0; kk < 12; ++kk) {
        const float* p = bsrc + (size_t)kk * 32;
        float4 x0 = *(const float4*)p, x1 = *(const float4*)(p + 4);
        bf16x8 t8;
        t8[0] = (short)f2bf(x0.x); t8[1] = (short)f2bf(x0.y);
        t8[2] = (short)f2bf(x0.z); t8[3] = (short)f2bf(x0.w);
        t8[4] = (short)f2bf(x1.x); t8[5] = (short)f2bf(x1.y);
        t8[6] = (short)f2bf(x1.z); t8[7] = (short)f2bf(x1.w);
        v[kk] = t8;
    }
    #pragma unroll
    for (int s = 0; s < 2; ++s) {
        if (s) __syncthreads();       // stage-0 LDS reads done before overwrite
        #pragma unroll
        for (int kk = 0; kk < 12; ++kk) *(bf16x8*)(wbase + kk * 2048) = v[kk];
        __syncthreads();
        if (s == 0) {
            // issue stage-1 loads; they fly under stage-0 MFMA
            #pragma unroll
            for (int kk = 0; kk < 12; ++kk) {
                const float* p = bsrc + (size_t)(12 + kk) * 32;
                float4 x0 = *(const float4*)p, x1 = *(const float4*)(p + 4);
                bf16x8 t8;
                t8[0] = (short)f2bf(x0.x); t8[1] = (short)f2bf(x0.y);
                t8[2] = (short)f2bf(x0.z); t8[3] = (short)f2bf(x0.w);
                t8[4] = (short)f2bf(x1.x); t8[5] = (short)f2bf(x1.y);
                t8[6] = (short)f2bf(x1.z); t8[7] = (short)f2bf(x1.w);
                v[kk] = t8;
            }
        }
        #pragma unroll
        for (int kk = 0; kk < 12; ++kk) {
            int kq = s * 12 + kk;
            bf16x8 bb[4];
            #pragma unroll
            for (int j = 0; j < 4; ++j) bb[j] = *(const bf16x8*)(bl + ((kk * 4 + j) * 64 + lane) * 8);
            #pragma unroll
            for (int h = 0; h < 2; ++h) {
                int mt = w + h * 4;
                bf16x8 a[4];
                #pragma unroll
                for (int i = 0; i < 4; ++i)
                    a[i] = *(const bf16x8*)(Ap + ((((size_t)mt * 24 + kq) * 4 + i) * 64 + lane) * 8);
                #pragma unroll
                for (int i = 0; i < 4; ++i)
                    #pragma unroll
                    for (int j = 0; j < 4; ++j)
                        acc[h][i][j] = __builtin_amdgcn_mfma_f32_16x16x32_bf16(a[i], bb[j], acc[h][i][j], 0, 0, 0);
            }
        }
    }
    int lr = lane & 15;
    #pragma unroll
    for (int h = 0; h < 2; ++h) {
        int mt = w + h * 4;
        #pragma unroll
        for (int i = 0; i < 4; ++i) {
            #pragma unroll
            for (int rr = 0; rr < 4; ++rr) {
                int m = mt * 64 + 16 * i + (lane >> 4) * 4 + rr;   // m = t*32+b
                #pragma unroll
                for (int j = 0; j < 4; ++j) {
                    int n = nt * 64 + 16 * j + lr;
                    float vv = acc[h][i][j][rr];
                    if (bias1) vv += bias1[n];
                    if (bias2) vv += bias2[n];
                    if (REMAP) {
                        int t = m >> 5, b = m & 31;
                        C[(size_t)((b << 4) + t) * NV + n] = vv;
                    } else {
                        C[(size_t)m * N + n] = vv;
                    }
                }
            }
        }
    }
}

// ---------------- attention step (no q-proj: scores = h . K~[b]) ----------------
// grid 32 (batch), block 768. xin = [ctx | h] bf16 [32][1536] (reads h, writes ctx).
__global__ __launch_bounds__(768) void attn2(
    ushort_t* __restrict__ xin, const ushort_t* __restrict__ KT,
    const ushort_t* __restrict__ mem) {
    __shared__ float hq[NH];
    __shared__ float sl[196];
    __shared__ float red[16];
    int b = blockIdx.x, tid = threadIdx.x;
    hq[tid] = bf2f(xin[(size_t)b * 1536 + NH + tid]);
    __syncthreads();
    // scores: 2 threads per m, coalesced KT rows
    if (tid < 392) {
        int m = tid >> 1, half = tid & 1;
        const ushort_t* basep = KT + (((size_t)b * 96 + half * 48) * 196 + m) * 8;
        float acc = 0.f;
        #pragma unroll 4
        for (int k8 = 0; k8 < 48; ++k8) {
            bf16x8 v = *(const bf16x8*)(basep + (size_t)k8 * 196 * 8);
            const float* qp = hq + (half * 48 + k8) * 8;
            #pragma unroll
            for (int j = 0; j < 8; ++j)
                acc = fmaf(bf2f((unsigned short)v[j]), qp[j], acc);
        }
        acc += __shfl_xor(acc, 1);
        if (!half) sl[m] = acc;
    }
    __syncthreads();
    // softmax over 196
    float sc = (tid < 196) ? sl[tid] : -INFINITY;
    float v = sc;
    #pragma unroll
    for (int off = 32; off; off >>= 1) v = fmaxf(v, __shfl_down(v, off));
    if ((tid & 63) == 0) red[tid >> 6] = v;
    __syncthreads();
    if (tid == 0) {
        float m = red[0];
        for (int i = 1; i < 12; ++i) m = fmaxf(m, red[i]);
        red[12] = m;
    }
    __syncthreads();
    float mx = red[12];
    float e = (tid < 196) ? expf(sc - mx) : 0.f;
    __syncthreads();
    v = e;
    #pragma unroll
    for (int off = 32; off; off >>= 1) v += __shfl_down(v, off);
    if ((tid & 63) == 0) red[tid >> 6] = v;
    __syncthreads();
    if (tid == 0) {
        float s = red[0];
        for (int i = 1; i < 12; ++i) s += red[i];
        red[12] = 1.f / s;
    }
    __syncthreads();
    if (tid < 196) sl[tid] = e * red[12];
    __syncthreads();
    // ctx[tid] = sum_m p[m]*mem[b][m][tid]
    {
        float acc = 0.f;
        const ushort_t* mb = mem + (size_t)b * 196 * NH + tid;
        #pragma unroll 4
        for (int m = 0; m < 196; ++m) acc = fmaf(sl[m], bf2f(mb[(size_t)m * NH]), acc);
        xin[(size_t)b * 1536 + tid] = f2bf(acc);
    }
}

// ---------------- fused gates GEMM + LSTM cell; writes Hall PACKED ----------------
// grid 48, block 256 (4 waves = 4-way K split). Block bx covers cols bx*16..bx*16+15 of each gate.
__global__ __launch_bounds__(256) void step_fused(
    const ushort_t* __restrict__ xin_r, const ushort_t* __restrict__ wcombP,
    const float* __restrict__ eg_t,
    float* __restrict__ cbuf, float* __restrict__ hbuf,
    ushort_t* __restrict__ xin_w, ushort_t* __restrict__ hallP, int tstep) {
    __shared__ float pbuf[4][64][33];
    int lane = threadIdx.x & 63, w = threadIdx.x >> 6;
    int bx = blockIdx.x;
    int lr = lane & 15, kl = (lane >> 4) * 8;
    floatx4 acc[2][4];
    #pragma unroll
    for (int i = 0; i < 2; ++i)
        #pragma unroll
        for (int g = 0; g < 4; ++g) acc[i][g] = 0.f;
    for (int kq = 0; kq < 12; ++kq) {
        int k = w * 384 + kq * 32;
        bf16x8 a[2], bb[4];
        #pragma unroll
        for (int i = 0; i < 2; ++i)
            a[i] = *(const bf16x8*)(xin_r + (size_t)(16 * i + lr) * 1536 + k + kl);
        #pragma unroll
        for (int g = 0; g < 4; ++g)
            bb[g] = *(const bf16x8*)(wcombP + (((size_t)(bx * 4 + g) * 48 + (w * 12 + kq)) * 64 + lane) * 8);
        #pragma unroll
        for (int i = 0; i < 2; ++i)
            #pragma unroll
            for (int g = 0; g < 4; ++g)
                acc[i][g] = __builtin_amdgcn_mfma_f32_16x16x32_bf16(a[i], bb[g], acc[i][g], 0, 0, 0);
    }
    #pragma unroll
    for (int i = 0; i < 2; ++i)
        #pragma unroll
        for (int g = 0; g < 4; ++g)
            #pragma unroll
            for (int r = 0; r < 4; ++r) {
                int m = 16 * i + (lane >> 4) * 4 + r;
                pbuf[w][g * 16 + lr][m] = acc[i][g][r];
            }
    __syncthreads();
    int tid = threadIdx.x;
    #pragma unroll
    for (int o = 0; o < 2; ++o) {
        int pid = tid * 2 + o;          // 0..511
        int m = pid & 31, c = pid >> 5; // m = batch, c = 0..15
        int kcol = bx * 16 + c;
        float gi = 0.f, gf = 0.f, gg = 0.f, go = 0.f;
        #pragma unroll
        for (int ww = 0; ww < 4; ++ww) {
            gi += pbuf[ww][c][m];
            gf += pbuf[ww][16 + c][m];
            gg += pbuf[ww][32 + c][m];
            go += pbuf[ww][48 + c][m];
        }
        const float* eg = eg_t + (size_t)m * 3072;
        gi += eg[kcol];
        gf += eg[768 + kcol];
        gg += eg[1536 + kcol];
        go += eg[2304 + kcol];
        float cst = cbuf[m * 768 + kcol];
        float cn = sigmoidf_(gf) * cst + sigmoidf_(gi) * tanhf(gg);
        float hn = sigmoidf_(go) * tanhf(cn);
        cbuf[m * 768 + kcol] = cn;
        hbuf[m * 768 + kcol] = hn;
        ushort_t hb = f2bf(hn);
        xin_w[(size_t)m * 1536 + NH + kcol] = hb;
        int rrow = tstep * 32 + m;
        int mtp = rrow >> 6, ip = (rrow >> 4) & 3, lrp = rrow & 15;
        int kqp = kcol >> 5, hip = (kcol >> 3) & 3, ep = kcol & 7;
        hallP[((((size_t)mtp * 24 + kqp) * 4 + ip) * 64 + (lrp | (hip << 4))) * 8 + ep] = hb;
    }
}

__global__ __launch_bounds__(256) void zero_state(float* __restrict__ h, float* __restrict__ c,
                                                  ushort_t* __restrict__ xin) {
    int i = blockIdx.x * 256 + threadIdx.x;
    if (i < NB * 1536) xin[i] = 0;
    if (i < NB * NH) { h[i] = 0.f; c[i] = 0.f; }
}

__global__ __launch_bounds__(256) void copy_hc(const float* __restrict__ h, const float* __restrict__ c,
                                               float* __restrict__ out) {
    int i = blockIdx.x * 256 + threadIdx.x;
    if (i < NB * NH) {
        out[(size_t)NB * NT * NV + i] = h[i];
        out[(size_t)NB * NT * NV + NB * NH + i] = c[i];
    }
}

extern "C" void kernel_launch(void* const* d_in, const int* in_sizes, int n_in,
                              void* d_out, int out_size, void* d_ws, size_t ws_size,
                              hipStream_t stream) {
    const float* images   = (const float*)d_in[0];
    const int*   captions = (const int*)d_in[1];
    const float* conv1_w  = (const float*)d_in[2];
    const float* bn1_g = (const float*)d_in[3], *bn1_b = (const float*)d_in[4];
    const float* bn1_m = (const float*)d_in[5], *bn1_v = (const float*)d_in[6];
    const float* conv2_w  = (const float*)d_in[7];
    const float* bn2_g = (const float*)d_in[8], *bn2_b = (const float*)d_in[9];
    const float* bn2_m = (const float*)d_in[10], *bn2_v = (const float*)d_in[11];
    const float* conv3_w  = (const float*)d_in[12];
    const float* bn3_g = (const float*)d_in[13], *bn3_b = (const float*)d_in[14];
    const float* bn3_m = (const float*)d_in[15], *bn3_v = (const float*)d_in[16];
    const float* conv4_w  = (const float*)d_in[17];
    const float* bn4_g = (const float*)d_in[18], *bn4_b = (const float*)d_in[19];
    const float* bn4_m = (const float*)d_in[20], *bn4_v = (const float*)d_in[21];
    const float* emb_table = (const float*)d_in[22];
    const float* attn_w   = (const float*)d_in[23];
    const float* w_ih     = (const float*)d_in[24];
    const float* w_hh     = (const float*)d_in[25];
    const float* b_ih     = (const float*)d_in[26];
    const float* b_hh     = (const float*)d_in[27];
    const float* fc_w     = (const float*)d_in[28];
    const float* fc_b     = (const float*)d_in[29];
    float* out = (float*)d_out;

    // ---- workspace layout ----
    char* base = (char*)d_ws;
    size_t off = 0;
    auto alloc = [&](size_t bytes) { char* p = base + off; off += (bytes + 255) & ~(size_t)255; return p; };
    float* s1 = (float*)alloc(64 * 4);   float* bb1 = (float*)alloc(64 * 4);
    float* s2 = (float*)alloc(128 * 4);  float* bb2 = (float*)alloc(128 * 4);
    float* s3 = (float*)alloc(256 * 4);  float* bb3 = (float*)alloc(256 * 4);
    float* s4 = (float*)alloc(768 * 4);  float* bb4 = (float*)alloc(768 * 4);
    ushort_t* c1out = (ushort_t*)alloc((size_t)32 * 34 * 112 * 64 * 2);
    size_t halo_start = off;
    ushort_t* hal2 = (ushort_t*)alloc((size_t)32 * 19 * 58 * 64 * 2);
    ushort_t* hal3 = (ushort_t*)alloc((size_t)32 * 18 * 58 * 128 * 2);
    ushort_t* hal4 = (ushort_t*)alloc((size_t)32 * 10 * 30 * 256 * 2);
    size_t halo_bytes = off - halo_start;
    ushort_t* memv = (ushort_t*)alloc((size_t)32 * 196 * 768 * 2);
    ushort_t* KT   = (ushort_t*)alloc((size_t)32 * 96 * 196 * 8 * 2);
    ushort_t* wb1 = (ushort_t*)alloc((size_t)64 * 160 * 2);
    ushort_t* wb2 = (ushort_t*)alloc((size_t)128 * 9 * 64 * 2);
    ushort_t* wb3 = (ushort_t*)alloc((size_t)256 * 9 * 128 * 2);
    ushort_t* wb4 = (ushort_t*)alloc((size_t)768 * 9 * 256 * 2);
    ushort_t* wattnTP = (ushort_t*)alloc((size_t)768 * 768 * 2);
    ushort_t* wcombP = (ushort_t*)alloc((size_t)3072 * 1536 * 2);
    ushort_t* e512P = (ushort_t*)alloc((size_t)512 * 768 * 2);
    float* eg   = (float*)alloc((size_t)512 * 3072 * 4);
    ushort_t* HallP = (ushort_t*)alloc((size_t)512 * 768 * 2);
    float* hbuf = (float*)alloc(NB * NH * 4);
    float* cbuf = (float*)alloc(NB * NH * 4);
    ushort_t* xinA = (ushort_t*)alloc((size_t)NB * 1536 * 2);
    ushort_t* xinB = (ushort_t*)alloc((size_t)NB * 1536 * 2);
    ushort_t* imcol = (ushort_t*)alloc((size_t)121856 * 160 * 2);

    // ---- one-time transforms ----
    bn_prep<<<1, 256, 0, stream>>>(bn1_g, bn1_b, bn1_m, bn1_v, s1, bb1, 64);
    bn_prep<<<1, 256, 0, stream>>>(bn2_g, bn2_b, bn2_m, bn2_v, s2, bb2, 128);
    bn_prep<<<1, 256, 0, stream>>>(bn3_g, bn3_b, bn3_m, bn3_v, s3, bb3, 256);
    bn_prep<<<3, 256, 0, stream>>>(bn4_g, bn4_b, bn4_m, bn4_v, s4, bb4, 768);
    cvt_pad<<<(64 * 160 + 255) / 256, 256, 0, stream>>>(conv1_w, wb1);
    cvt_packW_conv<<<(128 * 9 * 64 + 255) / 256, 256, 0, stream>>>(conv2_w, wb2, 64, 128 * 9 * 64);
    cvt_packW_conv<<<(256 * 9 * 128 + 255) / 256, 256, 0, stream>>>(conv3_w, wb3, 128, 256 * 9 * 128);
    cvt_packW_conv<<<(768 * 9 * 256 + 255) / 256, 256, 0, stream>>>(conv4_w, wb4, 256, 768 * 9 * 256);
    cvt_wattnTP<<<(768 * 768 + 255) / 256, 256, 0, stream>>>(attn_w, wattnTP);
    cvt_wcombP<<<(3072 * 1536 + 255) / 256, 256, 0, stream>>>(w_ih, w_hh, wcombP);
    {
        long long n8 = (long long)(halo_bytes / 8);
        zfill<<<(unsigned)((n8 + 255) / 256), 256, 0, stream>>>((unsigned long long*)hal2, n8);
    }

    // ---- encoder ----
    im2col1<<<(121856 * 160 + 255) / 256, 256, 0, stream>>>(images, imcol);
    conv1_gemm<<<476, 256, 0, stream>>>(imcol, wb1, s1, bb1, c1out);
    pool_kernel<<<(32 * 17 * 56 * 8 + 255) / 256, 256, 0, stream>>>(c1out, hal2);
    conv_mfma<64, 19, 58, 1, 16, 56, 128, 0, 18, 58>
        <<<dim3(448, 2), 64, 0, stream>>>(hal2, wb2, s2, bb2, hal3);
    conv_mfma<128, 18, 58, 2, 8, 28, 256, 0, 10, 30>
        <<<dim3(112, 4), 64, 0, stream>>>(hal3, wb3, s3, bb3, hal4);
    conv_mfma<256, 10, 30, 1, 7, 28, 768, 1, 1, 1>
        <<<dim3(98, 12), 64, 0, stream>>>(hal4, wb4, s4, bb4, memv);

    // ---- attention K~ precompute: KT = mem @ attn_w ----
    kmat_gemm<<<dim3(98, 12), 64, 0, stream>>>(memv, wattnTP, KT);

    // ---- decoder precompute: eg = e @ w_ih[:, :768]^T + b_ih + b_hh ----
    gather_embP<<<(512 * 768) / 256, 256, 0, stream>>>(captions, emb_table, e512P);
    gemm_staged<0><<<48, 256, 0, stream>>>(e512P, w_ih, b_ih, b_hh, eg, 2 * NH, 3072);
    zero_state<<<(NB * 1536 + 255) / 256, 256, 0, stream>>>(hbuf, cbuf, xinA);

    // ---- sequential decoder (xin double-buffered) ----
    ushort_t* xcur = xinA;
    ushort_t* xnxt = xinB;
    for (int t = 0; t < NT; ++t) {
        attn2<<<NB, NH, 0, stream>>>(xcur, KT, memv);
        step_fused<<<48, 256, 0, stream>>>(
            xcur, wcombP, eg + (size_t)t * NB * 3072, cbuf, hbuf, xnxt, HallP, t);
        ushort_t* tmp = xcur; xcur = xnxt; xnxt = tmp;
    }

    // ---- vocab projection for all 16 steps at once ----
    gemm_staged<1><<<500, 256, 0, stream>>>(HallP, fc_w, fc_b, nullptr, out, NH, NV);

    copy_hc<<<(NB * NH + 255) / 256, 256, 0, stream>>>(hbuf, cbuf, out);
}

// Round 8
// 923.282 us; speedup vs baseline: 9.2854x; 1.0384x over previous
//
#include <hip/hip_runtime.h>
#include <math.h>

#define NB 32
#define NT 16
#define NH 768
#define NV 32000

typedef short bf16x8 __attribute__((ext_vector_type(8)));
typedef float floatx4 __attribute__((ext_vector_type(4)));
typedef unsigned short ushort_t;

__device__ __forceinline__ float bf2f(unsigned short h) {
    unsigned u = ((unsigned)h) << 16;
    return __builtin_bit_cast(float, u);
}
__device__ __forceinline__ unsigned short f2bf(float f) {
    unsigned u = __builtin_bit_cast(unsigned, f);
    u += 0x7fffu + ((u >> 16) & 1u);
    return (unsigned short)(u >> 16);
}
__device__ __forceinline__ float sigmoidf_(float x) { return 1.f / (1.f + expf(-x)); }

__device__ __forceinline__ bf16x8 cvt8(float4 a, float4 b) {
    bf16x8 t;
    t[0] = (short)f2bf(a.x); t[1] = (short)f2bf(a.y);
    t[2] = (short)f2bf(a.z); t[3] = (short)f2bf(a.w);
    t[4] = (short)f2bf(b.x); t[5] = (short)f2bf(b.y);
    t[6] = (short)f2bf(b.z); t[7] = (short)f2bf(b.w);
    return t;
}

// ---------------- merged BN scale/bias precompute (all 4 layers) ----------------
__global__ __launch_bounds__(256) void bn_prep4(
    const float* __restrict__ g1, const float* __restrict__ b1, const float* __restrict__ m1, const float* __restrict__ v1,
    const float* __restrict__ g2, const float* __restrict__ b2, const float* __restrict__ m2, const float* __restrict__ v2,
    const float* __restrict__ g3, const float* __restrict__ b3, const float* __restrict__ m3, const float* __restrict__ v3,
    const float* __restrict__ g4, const float* __restrict__ b4, const float* __restrict__ m4, const float* __restrict__ v4,
    float* __restrict__ s1, float* __restrict__ o1, float* __restrict__ s2, float* __restrict__ o2,
    float* __restrict__ s3, float* __restrict__ o3, float* __restrict__ s4, float* __restrict__ o4) {
    int i = blockIdx.x * 256 + threadIdx.x;
    const float *g, *b, *m, *v;
    float *s, *o;
    int c;
    if (i < 64)        { g = g1; b = b1; m = m1; v = v1; s = s1; o = o1; c = i; }
    else if (i < 192)  { g = g2; b = b2; m = m2; v = v2; s = s2; o = o2; c = i - 64; }
    else if (i < 448)  { g = g3; b = b3; m = m3; v = v3; s = s3; o = o3; c = i - 192; }
    else if (i < 1216) { g = g4; b = b4; m = m4; v = v4; s = s4; o = o4; c = i - 448; }
    else return;
    float inv = g[c] * rsqrtf(v[c] + 1e-5f);
    s[c] = inv;
    o[c] = b[c] - m[c] * inv;
}

__global__ __launch_bounds__(256) void zfill(unsigned long long* __restrict__ p, long long n) {
    long long i = (long long)blockIdx.x * 256 + threadIdx.x;
    if (i < n) p[i] = 0ULL;
}

// conv weights OIHW f32 -> packed per (nt, tap, kq)
__global__ __launch_bounds__(256) void cvt_packW_conv(const float* __restrict__ w, ushort_t* __restrict__ dst,
                                                      int CIN, int total) {
    int idx = blockIdx.x * 256 + threadIdx.x;
    if (idx >= total) return;
    int e = idx & 7, lane = (idx >> 3) & 63, j = (idx >> 9) & 3;
    int r = idx >> 11;
    int KQ = CIN >> 5;
    int kq = r % KQ; r /= KQ;
    int tap = r % 9; int nt = r / 9;
    int co = nt * 64 + j * 16 + (lane & 15);
    int ci = kq * 32 + (lane >> 4) * 8 + e;
    dst[idx] = f2bf(w[((size_t)co * CIN + ci) * 9 + tap]);
}

// wcombP pack
__global__ __launch_bounds__(256) void cvt_wcombP(const float* __restrict__ w_ih, const float* __restrict__ w_hh,
                                                  ushort_t* __restrict__ dst) {
    int idx = blockIdx.x * 256 + threadIdx.x;
    if (idx >= 3072 * 1536) return;
    int e = idx & 7, lane = (idx >> 3) & 63;
    int t = idx >> 9;
    int kq = t % 48, gg = t / 48;
    int g = gg & 3, bx = gg >> 2;
    int j = g * 768 + bx * 16 + (lane & 15);
    int k = kq * 32 + (lane >> 4) * 8 + e;
    float v = (k < NH) ? w_ih[(size_t)j * (2 * NH) + NH + k] : w_hh[(size_t)j * NH + (k - NH)];
    dst[idx] = f2bf(v);
}

// wattnT packed for kmat: fragment holds W^T[n][k] = attn_w[k][n]
__global__ __launch_bounds__(256) void cvt_wattnTP(const float* __restrict__ w, ushort_t* __restrict__ dst) {
    int idx = blockIdx.x * 256 + threadIdx.x;
    if (idx >= 768 * 768) return;
    int e = idx & 7, lane = (idx >> 3) & 63, j = (idx >> 9) & 3;
    int t = idx >> 11;
    int kq = t % 24, nt = t / 24;
    int n = nt * 64 + 16 * j + (lane & 15);
    int k = kq * 32 + (lane >> 4) * 8 + e;
    dst[idx] = f2bf(w[(size_t)k * 768 + n]);
}

// conv1 weights: [64][147] f32 -> [64][160] bf16 (zero pad)
__global__ __launch_bounds__(256) void cvt_pad(const float* __restrict__ src, ushort_t* __restrict__ dst) {
    int idx = blockIdx.x * 256 + threadIdx.x;
    if (idx >= 64 * 160) return;
    int co = idx / 160, k = idx % 160;
    dst[idx] = (k < 147) ? f2bf(src[co * 147 + k]) : (ushort_t)0;
}

// ---------------- conv1 im2col: [121856][160] bf16 ----------------
__global__ __launch_bounds__(256) void im2col1(const float* __restrict__ img, ushort_t* __restrict__ A) {
    int idx = blockIdx.x * 256 + threadIdx.x;
    const int total = 121856 * 160;
    if (idx >= total) return;
    int k = idx % 160;
    int m = idx / 160;
    ushort_t v = 0;
    if (k < 147) {
        int b = m / 3808;
        int rm = m % 3808;
        int y = rm / 112, x = rm % 112;
        int ci = k / 49;
        int r = k % 49;
        int ky = r / 7, kx = r % 7;
        int iy = 2 * y - 3 + ky;
        int ix = 2 * x - 3 + kx;
        if ((unsigned)iy < 224u && (unsigned)ix < 224u)
            v = f2bf(img[((size_t)(b * 3 + ci) * 224 + iy) * 224 + ix]);
    }
    A[idx] = v;
}

// ---------------- conv1 GEMM ----------------
__global__ __launch_bounds__(256) void conv1_gemm(
    const ushort_t* __restrict__ A, const ushort_t* __restrict__ Bw,
    const float* __restrict__ scale, const float* __restrict__ bias,
    ushort_t* __restrict__ out) {
    int lane = threadIdx.x & 63, w = threadIdx.x >> 6;
    int m0 = (blockIdx.x * 4 + w) * 64;
    int lr = lane & 15, kl = (lane >> 4) * 8;
    floatx4 acc[4][4];
    #pragma unroll
    for (int i = 0; i < 4; ++i)
        #pragma unroll
        for (int j = 0; j < 4; ++j) acc[i][j] = 0.f;
    #pragma unroll
    for (int k0 = 0; k0 < 160; k0 += 32) {
        bf16x8 a[4], bb[4];
        #pragma unroll
        for (int i = 0; i < 4; ++i) a[i] = *(const bf16x8*)(A + (size_t)(m0 + 16 * i + lr) * 160 + kl + k0);
        #pragma unroll
        for (int j = 0; j < 4; ++j) bb[j] = *(const bf16x8*)(Bw + (size_t)(16 * j + lr) * 160 + kl + k0);
        #pragma unroll
        for (int i = 0; i < 4; ++i)
            #pragma unroll
            for (int j = 0; j < 4; ++j)
                acc[i][j] = __builtin_amdgcn_mfma_f32_16x16x32_bf16(a[i], bb[j], acc[i][j], 0, 0, 0);
    }
    #pragma unroll
    for (int i = 0; i < 4; ++i) {
        #pragma unroll
        for (int r = 0; r < 4; ++r) {
            int m = m0 + 16 * i + (lane >> 4) * 4 + r;
            int b = m / 3808;
            int rm = m % 3808;
            int y = rm / 112, x = rm % 112;
            #pragma unroll
            for (int j = 0; j < 4; ++j) {
                int n = 16 * j + lr;
                float v = fmaxf(acc[i][j][r] * scale[n] + bias[n], 0.f);
                out[((size_t)(b * 34 + y) * 112 + x) * 64 + n] = f2bf(v);
            }
        }
    }
}

// ---------------- maxpool 3x3 s2 p1 ----------------
__global__ __launch_bounds__(256) void pool_kernel(const ushort_t* __restrict__ in,
                                                   ushort_t* __restrict__ hal2) {
    int idx = blockIdx.x * 256 + threadIdx.x;
    const int total = 32 * 17 * 56 * 8;
    if (idx >= total) return;
    int c8 = idx & 7;
    int rest = idx >> 3;
    int x = rest % 56; rest /= 56;
    int y = rest % 17; int b = rest / 17;
    float mx[8];
    #pragma unroll
    for (int j = 0; j < 8; ++j) mx[j] = -INFINITY;
    for (int dy = -1; dy <= 1; ++dy) {
        int iy = 2 * y + dy;
        if ((unsigned)iy >= 34u) continue;
        for (int dx = -1; dx <= 1; ++dx) {
            int ix = 2 * x + dx;
            if ((unsigned)ix >= 112u) continue;
            bf16x8 v = *(const bf16x8*)(in + (((size_t)(b * 34 + iy)) * 112 + ix) * 64 + c8 * 8);
            #pragma unroll
            for (int j = 0; j < 8; ++j) mx[j] = fmaxf(mx[j], bf2f((unsigned short)v[j]));
        }
    }
    bf16x8 o;
    #pragma unroll
    for (int j = 0; j < 8; ++j) o[j] = (short)f2bf(mx[j]);
    *(bf16x8*)(hal2 + (((size_t)(b * 19 + y + 1)) * 58 + (x + 1)) * 64 + c8 * 8) = o;
}

// ---------------- implicit-GEMM 3x3 conv via MFMA, packed weights ----------------
template <int CIN, int HH, int WH, int STRIDE, int HOUT, int WOUT, int COUT, int MEMOUT, int OH, int OW>
__global__ __launch_bounds__(64) void conv_mfma(
    const ushort_t* __restrict__ in, const ushort_t* __restrict__ wtP,
    const float* __restrict__ scale, const float* __restrict__ bias,
    ushort_t* __restrict__ out) {
    int lane = threadIdx.x;
    int mt = blockIdx.x, nt = blockIdx.y;
    int lr = lane & 15, kl = (lane >> 4) * 8;
    int rowoff[4];
    #pragma unroll
    for (int i = 0; i < 4; ++i) {
        int m = mt * 64 + 16 * i + lr;
        int b = m / (HOUT * WOUT);
        int rm = m % (HOUT * WOUT);
        int y = rm / WOUT, x = rm % WOUT;
        rowoff[i] = ((b * HH + y * STRIDE) * WH + x * STRIDE) * CIN + kl;
    }
    floatx4 acc[4][4];
    #pragma unroll
    for (int i = 0; i < 4; ++i)
        #pragma unroll
        for (int j = 0; j < 4; ++j) acc[i][j] = 0.f;

    #pragma unroll
    for (int ky = 0; ky < 3; ++ky) {
        #pragma unroll
        for (int kx = 0; kx < 3; ++kx) {
            int ioff = (ky * WH + kx) * CIN;
            int t = ky * 3 + kx;
            #pragma unroll
            for (int k0 = 0; k0 < CIN; k0 += 32) {
                bf16x8 a[4], bb[4];
                #pragma unroll
                for (int i = 0; i < 4; ++i)
                    a[i] = *(const bf16x8*)(in + rowoff[i] + ioff + k0);
                #pragma unroll
                for (int j = 0; j < 4; ++j)
                    bb[j] = *(const bf16x8*)(wtP + ((((size_t)(nt * 9 + t) * (CIN / 32) + (k0 >> 5)) * 4 + j) * 64 + lane) * 8);
                #pragma unroll
                for (int i = 0; i < 4; ++i)
                    #pragma unroll
                    for (int j = 0; j < 4; ++j)
                        acc[i][j] = __builtin_amdgcn_mfma_f32_16x16x32_bf16(a[i], bb[j], acc[i][j], 0, 0, 0);
            }
        }
    }
    #pragma unroll
    for (int i = 0; i < 4; ++i) {
        #pragma unroll
        for (int r = 0; r < 4; ++r) {
            int m = mt * 64 + 16 * i + (lane >> 4) * 4 + r;
            int b = m / (HOUT * WOUT);
            int rm = m % (HOUT * WOUT);
            int y = rm / WOUT, x = rm % WOUT;
            #pragma unroll
            for (int j = 0; j < 4; ++j) {
                int n = nt * 64 + 16 * j + lr;
                float v = fmaxf(acc[i][j][r] * scale[n] + bias[n], 0.f);
                ushort_t hv = f2bf(v);
                if (MEMOUT) {
                    out[(size_t)m * COUT + n] = hv;   // memory [b][196][768]
                } else {
                    out[((size_t)(b * OH + y + 1) * OW + (x + 1)) * COUT + n] = hv;
                }
            }
        }
    }
}

// ---------------- kmat: K~[b] = mem[b] @ attn_w  -> KT layout [b][96][196][8] bf16 ----------------
__global__ __launch_bounds__(64) void kmat_gemm(
    const ushort_t* __restrict__ memv, const ushort_t* __restrict__ Bp,
    ushort_t* __restrict__ KT) {
    int lane = threadIdx.x;
    int mt = blockIdx.x, nt = blockIdx.y;
    int lr = lane & 15, kl = (lane >> 4) * 8;
    floatx4 acc[4][4];
    #pragma unroll
    for (int i = 0; i < 4; ++i)
        #pragma unroll
        for (int j = 0; j < 4; ++j) acc[i][j] = 0.f;
    for (int kq = 0; kq < 24; ++kq) {
        bf16x8 a[4], bb[4];
        #pragma unroll
        for (int i = 0; i < 4; ++i)
            a[i] = *(const bf16x8*)(memv + (size_t)(mt * 64 + 16 * i + lr) * 768 + kq * 32 + kl);
        #pragma unroll
        for (int j = 0; j < 4; ++j)
            bb[j] = *(const bf16x8*)(Bp + (((size_t)(nt * 24 + kq) * 4 + j) * 64 + lane) * 8);
        #pragma unroll
        for (int i = 0; i < 4; ++i)
            #pragma unroll
            for (int j = 0; j < 4; ++j)
                acc[i][j] = __builtin_amdgcn_mfma_f32_16x16x32_bf16(a[i], bb[j], acc[i][j], 0, 0, 0);
    }
    #pragma unroll
    for (int i = 0; i < 4; ++i) {
        #pragma unroll
        for (int r = 0; r < 4; ++r) {
            int mg = mt * 64 + 16 * i + (lane >> 4) * 4 + r;
            int b = mg / 196, m = mg % 196;
            #pragma unroll
            for (int j = 0; j < 4; ++j) {
                int n = nt * 64 + 16 * j + lr;
                KT[(((size_t)b * 96 + (n >> 3)) * 196 + m) * 8 + (n & 7)] = f2bf(acc[i][j][r]);
            }
        }
    }
}

// ---------------- embedding gather -> PACKED bf16 e512P ----------------
__global__ __launch_bounds__(256) void gather_embP(const int* __restrict__ caps,
                                                   const float* __restrict__ table,
                                                   ushort_t* __restrict__ dst) {
    int idx = blockIdx.x * 256 + threadIdx.x;  // 512*768
    if (idx >= 512 * 768) return;
    int e = idx & 7, lane = (idx >> 3) & 63, i = (idx >> 9) & 3;
    int t2 = idx >> 11;
    int kq = t2 % 24, mt = t2 / 24;
    int r = mt * 64 + i * 16 + (lane & 15);
    int k = kq * 32 + (lane >> 4) * 8 + e;
    int t = r >> 5, b = r & 31;
    dst[idx] = f2bf(table[(size_t)caps[b * NT + t] * NH + k]);
}

// ---------------- pipelined pack+GEMM: C[512][N] = Ap . bf16(B_f32)^T + bias ----------------
// Ping-pong 4KB LDS buffers, ONE barrier per 32-K chunk, depth-2 register prefetch
// (chunk j+3 issued while computing chunk j -> ~2 compute-phases of load flight).
// A packed ([8 mt][24 kq][4 i][64 lane][8 e], K=768). B f32 row-major [N][ldb], cols 0..767.
// grid N/64, block 256 = 4 waves; wave w -> m-tiles {w, w+4}.
template <int REMAP>
__global__ __launch_bounds__(256) void gemm_pipe(
    const ushort_t* __restrict__ Ap, const float* __restrict__ B,
    const float* __restrict__ bias1, const float* __restrict__ bias2,
    float* __restrict__ C, int ldb, int N) {
    __shared__ ushort_t bl[2][2048];  // 2 x 4KB, fragment order [4 j][64 lane][8 e]
    int tid = threadIdx.x;
    int lane = tid & 63, w = tid >> 6;
    int nt = blockIdx.x;
    int r = tid >> 2, c0 = (tid & 3) * 8;
    const float* bsrc = B + (size_t)(nt * 64 + r) * ldb + c0;
    int slotoff = (((r >> 4) * 64 + ((r & 15) | ((tid & 3) << 4))) * 8);
    ushort_t* slot0 = &bl[0][0] + slotoff;
    ushort_t* slot1 = &bl[1][0] + slotoff;
    floatx4 acc[2][4][4];
    #pragma unroll
    for (int h = 0; h < 2; ++h)
        #pragma unroll
        for (int i = 0; i < 4; ++i)
            #pragma unroll
            for (int j = 0; j < 4; ++j) acc[h][i][j] = 0.f;

    // prologue: chunk 0 -> buf0; prefetch chunks 1 (fa) and 2 (fb) into regs
    float4 p0a = *(const float4*)(bsrc),      p0b = *(const float4*)(bsrc + 4);
    float4 fa0 = *(const float4*)(bsrc + 32), fa1 = *(const float4*)(bsrc + 36);
    float4 fb0 = *(const float4*)(bsrc + 64), fb1 = *(const float4*)(bsrc + 68);
    *(bf16x8*)slot0 = cvt8(p0a, p0b);

    for (int j = 0; j < 24; ++j) {
        __syncthreads();
        if (j < 23) {
            // write chunk j+1 into buf (j+1)&1
            *(bf16x8*)((j & 1) ? slot0 : slot1) = cvt8(fa0, fa1);
            fa0 = fb0; fa1 = fb1;
        }
        if (j < 21) {
            const float* p = bsrc + (size_t)(j + 3) * 32;
            fb0 = *(const float4*)p;
            fb1 = *(const float4*)(p + 4);
        }
        const ushort_t* rb = &bl[j & 1][0];
        bf16x8 bb[4];
        #pragma unroll
        for (int j4 = 0; j4 < 4; ++j4) bb[j4] = *(const bf16x8*)(rb + (j4 * 64 + lane) * 8);
        #pragma unroll
        for (int h = 0; h < 2; ++h) {
            int mt = w + h * 4;
            bf16x8 a[4];
            #pragma unroll
            for (int i = 0; i < 4; ++i)
                a[i] = *(const bf16x8*)(Ap + ((((size_t)mt * 24 + j) * 4 + i) * 64 + lane) * 8);
            #pragma unroll
            for (int i = 0; i < 4; ++i)
                #pragma unroll
                for (int j4 = 0; j4 < 4; ++j4)
                    acc[h][i][j4] = __builtin_amdgcn_mfma_f32_16x16x32_bf16(a[i], bb[j4], acc[h][i][j4], 0, 0, 0);
        }
    }
    int lr = lane & 15;
    #pragma unroll
    for (int h = 0; h < 2; ++h) {
        int mt = w + h * 4;
        #pragma unroll
        for (int i = 0; i < 4; ++i) {
            #pragma unroll
            for (int rr = 0; rr < 4; ++rr) {
                int m = mt * 64 + 16 * i + (lane >> 4) * 4 + rr;   // m = t*32+b
                #pragma unroll
                for (int j4 = 0; j4 < 4; ++j4) {
                    int n = nt * 64 + 16 * j4 + lr;
                    float vv = acc[h][i][j4][rr];
                    if (bias1) vv += bias1[n];
                    if (bias2) vv += bias2[n];
                    if (REMAP) {
                        int t = m >> 5, b = m & 31;
                        C[(size_t)((b << 4) + t) * NV + n] = vv;
                    } else {
                        C[(size_t)m * N + n] = vv;
                    }
                }
            }
        }
    }
}

// ---------------- attention step (scores = h . K~[b]) ----------------
__global__ __launch_bounds__(768) void attn2(
    ushort_t* __restrict__ xin, const ushort_t* __restrict__ KT,
    const ushort_t* __restrict__ mem) {
    __shared__ float hq[NH];
    __shared__ float sl[196];
    __shared__ float red[16];
    int b = blockIdx.x, tid = threadIdx.x;
    hq[tid] = bf2f(xin[(size_t)b * 1536 + NH + tid]);
    __syncthreads();
    if (tid < 392) {
        int m = tid >> 1, half = tid & 1;
        const ushort_t* basep = KT + (((size_t)b * 96 + half * 48) * 196 + m) * 8;
        float acc = 0.f;
        #pragma unroll 4
        for (int k8 = 0; k8 < 48; ++k8) {
            bf16x8 v = *(const bf16x8*)(basep + (size_t)k8 * 196 * 8);
            const float* qp = hq + (half * 48 + k8) * 8;
            #pragma unroll
            for (int j = 0; j < 8; ++j)
                acc = fmaf(bf2f((unsigned short)v[j]), qp[j], acc);
        }
        acc += __shfl_xor(acc, 1);
        if (!half) sl[m] = acc;
    }
    __syncthreads();
    float sc = (tid < 196) ? sl[tid] : -INFINITY;
    float v = sc;
    #pragma unroll
    for (int off = 32; off; off >>= 1) v = fmaxf(v, __shfl_down(v, off));
    if ((tid & 63) == 0) red[tid >> 6] = v;
    __syncthreads();
    if (tid == 0) {
        float m = red[0];
        for (int i = 1; i < 12; ++i) m = fmaxf(m, red[i]);
        red[12] = m;
    }
    __syncthreads();
    float mx = red[12];
    float e = (tid < 196) ? expf(sc - mx) : 0.f;
    __syncthreads();
    v = e;
    #pragma unroll
    for (int off = 32; off; off >>= 1) v += __shfl_down(v, off);
    if ((tid & 63) == 0) red[tid >> 6] = v;
    __syncthreads();
    if (tid == 0) {
        float s = red[0];
        for (int i = 1; i < 12; ++i) s += red[i];
        red[12] = 1.f / s;
    }
    __syncthreads();
    if (tid < 196) sl[tid] = e * red[12];
    __syncthreads();
    {
        float acc = 0.f;
        const ushort_t* mb = mem + (size_t)b * 196 * NH + tid;
        #pragma unroll 4
        for (int m = 0; m < 196; ++m) acc = fmaf(sl[m], bf2f(mb[(size_t)m * NH]), acc);
        xin[(size_t)b * 1536 + tid] = f2bf(acc);
    }
}

// ---------------- fused gates GEMM + LSTM cell; writes Hall PACKED ----------------
__global__ __launch_bounds__(256) void step_fused(
    const ushort_t* __restrict__ xin_r, const ushort_t* __restrict__ wcombP,
    const float* __restrict__ eg_t,
    float* __restrict__ cbuf, float* __restrict__ hbuf,
    ushort_t* __restrict__ xin_w, ushort_t* __restrict__ hallP, int tstep) {
    __shared__ float pbuf[4][64][33];
    int lane = threadIdx.x & 63, w = threadIdx.x >> 6;
    int bx = blockIdx.x;
    int lr = lane & 15, kl = (lane >> 4) * 8;
    floatx4 acc[2][4];
    #pragma unroll
    for (int i = 0; i < 2; ++i)
        #pragma unroll
        for (int g = 0; g < 4; ++g) acc[i][g] = 0.f;
    for (int kq = 0; kq < 12; ++kq) {
        int k = w * 384 + kq * 32;
        bf16x8 a[2], bb[4];
        #pragma unroll
        for (int i = 0; i < 2; ++i)
            a[i] = *(const bf16x8*)(xin_r + (size_t)(16 * i + lr) * 1536 + k + kl);
        #pragma unroll
        for (int g = 0; g < 4; ++g)
            bb[g] = *(const bf16x8*)(wcombP + (((size_t)(bx * 4 + g) * 48 + (w * 12 + kq)) * 64 + lane) * 8);
        #pragma unroll
        for (int i = 0; i < 2; ++i)
            #pragma unroll
            for (int g = 0; g < 4; ++g)
                acc[i][g] = __builtin_amdgcn_mfma_f32_16x16x32_bf16(a[i], bb[g], acc[i][g], 0, 0, 0);
    }
    #pragma unroll
    for (int i = 0; i < 2; ++i)
        #pragma unroll
        for (int g = 0; g < 4; ++g)
            #pragma unroll
            for (int r = 0; r < 4; ++r) {
                int m = 16 * i + (lane >> 4) * 4 + r;
                pbuf[w][g * 16 + lr][m] = acc[i][g][r];
            }
    __syncthreads();
    int tid = threadIdx.x;
    #pragma unroll
    for (int o = 0; o < 2; ++o) {
        int pid = tid * 2 + o;          // 0..511
        int m = pid & 31, c = pid >> 5; // m = batch, c = 0..15
        int kcol = bx * 16 + c;
        float gi = 0.f, gf = 0.f, gg = 0.f, go = 0.f;
        #pragma unroll
        for (int ww = 0; ww < 4; ++ww) {
            gi += pbuf[ww][c][m];
            gf += pbuf[ww][16 + c][m];
            gg += pbuf[ww][32 + c][m];
            go += pbuf[ww][48 + c][m];
        }
        const float* eg = eg_t + (size_t)m * 3072;
        gi += eg[kcol];
        gf += eg[768 + kcol];
        gg += eg[1536 + kcol];
        go += eg[2304 + kcol];
        float cst = cbuf[m * 768 + kcol];
        float cn = sigmoidf_(gf) * cst + sigmoidf_(gi) * tanhf(gg);
        float hn = sigmoidf_(go) * tanhf(cn);
        cbuf[m * 768 + kcol] = cn;
        hbuf[m * 768 + kcol] = hn;
        ushort_t hb = f2bf(hn);
        xin_w[(size_t)m * 1536 + NH + kcol] = hb;
        int rrow = tstep * 32 + m;
        int mtp = rrow >> 6, ip = (rrow >> 4) & 3, lrp = rrow & 15;
        int kqp = kcol >> 5, hip = (kcol >> 3) & 3, ep = kcol & 7;
        hallP[((((size_t)mtp * 24 + kqp) * 4 + ip) * 64 + (lrp | (hip << 4))) * 8 + ep] = hb;
    }
}

__global__ __launch_bounds__(256) void zero_state(float* __restrict__ h, float* __restrict__ c,
                                                  ushort_t* __restrict__ xin) {
    int i = blockIdx.x * 256 + threadIdx.x;
    if (i < NB * 1536) xin[i] = 0;
    if (i < NB * NH) { h[i] = 0.f; c[i] = 0.f; }
}

__global__ __launch_bounds__(256) void copy_hc(const float* __restrict__ h, const float* __restrict__ c,
                                               float* __restrict__ out) {
    int i = blockIdx.x * 256 + threadIdx.x;
    if (i < NB * NH) {
        out[(size_t)NB * NT * NV + i] = h[i];
        out[(size_t)NB * NT * NV + NB * NH + i] = c[i];
    }
}

extern "C" void kernel_launch(void* const* d_in, const int* in_sizes, int n_in,
                              void* d_out, int out_size, void* d_ws, size_t ws_size,
                              hipStream_t stream) {
    const float* images   = (const float*)d_in[0];
    const int*   captions = (const int*)d_in[1];
    const float* conv1_w  = (const float*)d_in[2];
    const float* bn1_g = (const float*)d_in[3], *bn1_b = (const float*)d_in[4];
    const float* bn1_m = (const float*)d_in[5], *bn1_v = (const float*)d_in[6];
    const float* conv2_w  = (const float*)d_in[7];
    const float* bn2_g = (const float*)d_in[8], *bn2_b = (const float*)d_in[9];
    const float* bn2_m = (const float*)d_in[10], *bn2_v = (const float*)d_in[11];
    const float* conv3_w  = (const float*)d_in[12];
    const float* bn3_g = (const float*)d_in[13], *bn3_b = (const float*)d_in[14];
    const float* bn3_m = (const float*)d_in[15], *bn3_v = (const float*)d_in[16];
    const float* conv4_w  = (const float*)d_in[17];
    const float* bn4_g = (const float*)d_in[18], *bn4_b = (const float*)d_in[19];
    const float* bn4_m = (const float*)d_in[20], *bn4_v = (const float*)d_in[21];
    const float* emb_table = (const float*)d_in[22];
    const float* attn_w   = (const float*)d_in[23];
    const float* w_ih     = (const float*)d_in[24];
    const float* w_hh     = (const float*)d_in[25];
    const float* b_ih     = (const float*)d_in[26];
    const float* b_hh     = (const float*)d_in[27];
    const float* fc_w     = (const float*)d_in[28];
    const float* fc_b     = (const float*)d_in[29];
    float* out = (float*)d_out;

    // ---- workspace layout ----
    char* base = (char*)d_ws;
    size_t off = 0;
    auto alloc = [&](size_t bytes) { char* p = base + off; off += (bytes + 255) & ~(size_t)255; return p; };
    float* s1 = (float*)alloc(64 * 4);   float* bb1 = (float*)alloc(64 * 4);
    float* s2 = (float*)alloc(128 * 4);  float* bb2 = (float*)alloc(128 * 4);
    float* s3 = (float*)alloc(256 * 4);  float* bb3 = (float*)alloc(256 * 4);
    float* s4 = (float*)alloc(768 * 4);  float* bb4 = (float*)alloc(768 * 4);
    ushort_t* c1out = (ushort_t*)alloc((size_t)32 * 34 * 112 * 64 * 2);
    size_t halo_start = off;
    ushort_t* hal2 = (ushort_t*)alloc((size_t)32 * 19 * 58 * 64 * 2);
    ushort_t* hal3 = (ushort_t*)alloc((size_t)32 * 18 * 58 * 128 * 2);
    ushort_t* hal4 = (ushort_t*)alloc((size_t)32 * 10 * 30 * 256 * 2);
    size_t halo_bytes = off - halo_start;
    ushort_t* memv = (ushort_t*)alloc((size_t)32 * 196 * 768 * 2);
    ushort_t* KT   = (ushort_t*)alloc((size_t)32 * 96 * 196 * 8 * 2);
    ushort_t* wb1 = (ushort_t*)alloc((size_t)64 * 160 * 2);
    ushort_t* wb2 = (ushort_t*)alloc((size_t)128 * 9 * 64 * 2);
    ushort_t* wb3 = (ushort_t*)alloc((size_t)256 * 9 * 128 * 2);
    ushort_t* wb4 = (ushort_t*)alloc((size_t)768 * 9 * 256 * 2);
    ushort_t* wattnTP = (ushort_t*)alloc((size_t)768 * 768 * 2);
    ushort_t* wcombP = (ushort_t*)alloc((size_t)3072 * 1536 * 2);
    ushort_t* e512P = (ushort_t*)alloc((size_t)512 * 768 * 2);
    float* eg   = (float*)alloc((size_t)512 * 3072 * 4);
    ushort_t* HallP = (ushort_t*)alloc((size_t)512 * 768 * 2);
    float* hbuf = (float*)alloc(NB * NH * 4);
    float* cbuf = (float*)alloc(NB * NH * 4);
    ushort_t* xinA = (ushort_t*)alloc((size_t)NB * 1536 * 2);
    ushort_t* xinB = (ushort_t*)alloc((size_t)NB * 1536 * 2);
    ushort_t* imcol = (ushort_t*)alloc((size_t)121856 * 160 * 2);

    // ---- one-time transforms ----
    bn_prep4<<<5, 256, 0, stream>>>(bn1_g, bn1_b, bn1_m, bn1_v,
                                    bn2_g, bn2_b, bn2_m, bn2_v,
                                    bn3_g, bn3_b, bn3_m, bn3_v,
                                    bn4_g, bn4_b, bn4_m, bn4_v,
                                    s1, bb1, s2, bb2, s3, bb3, s4, bb4);
    cvt_pad<<<(64 * 160 + 255) / 256, 256, 0, stream>>>(conv1_w, wb1);
    cvt_packW_conv<<<(128 * 9 * 64 + 255) / 256, 256, 0, stream>>>(conv2_w, wb2, 64, 128 * 9 * 64);
    cvt_packW_conv<<<(256 * 9 * 128 + 255) / 256, 256, 0, stream>>>(conv3_w, wb3, 128, 256 * 9 * 128);
    cvt_packW_conv<<<(768 * 9 * 256 + 255) / 256, 256, 0, stream>>>(conv4_w, wb4, 256, 768 * 9 * 256);
    cvt_wattnTP<<<(768 * 768 + 255) / 256, 256, 0, stream>>>(attn_w, wattnTP);
    cvt_wcombP<<<(3072 * 1536 + 255) / 256, 256, 0, stream>>>(w_ih, w_hh, wcombP);
    {
        long long n8 = (long long)(halo_bytes / 8);
        zfill<<<(unsigned)((n8 + 255) / 256), 256, 0, stream>>>((unsigned long long*)hal2, n8);
    }

    // ---- encoder ----
    im2col1<<<(121856 * 160 + 255) / 256, 256, 0, stream>>>(images, imcol);
    conv1_gemm<<<476, 256, 0, stream>>>(imcol, wb1, s1, bb1, c1out);
    pool_kernel<<<(32 * 17 * 56 * 8 + 255) / 256, 256, 0, stream>>>(c1out, hal2);
    conv_mfma<64, 19, 58, 1, 16, 56, 128, 0, 18, 58>
        <<<dim3(448, 2), 64, 0, stream>>>(hal2, wb2, s2, bb2, hal3);
    conv_mfma<128, 18, 58, 2, 8, 28, 256, 0, 10, 30>
        <<<dim3(112, 4), 64, 0, stream>>>(hal3, wb3, s3, bb3, hal4);
    conv_mfma<256, 10, 30, 1, 7, 28, 768, 1, 1, 1>
        <<<dim3(98, 12), 64, 0, stream>>>(hal4, wb4, s4, bb4, memv);

    // ---- attention K~ precompute: KT = mem @ attn_w ----
    kmat_gemm<<<dim3(98, 12), 64, 0, stream>>>(memv, wattnTP, KT);

    // ---- decoder precompute: eg = e @ w_ih[:, :768]^T + b_ih + b_hh ----
    gather_embP<<<(512 * 768) / 256, 256, 0, stream>>>(captions, emb_table, e512P);
    gemm_pipe<0><<<48, 256, 0, stream>>>(e512P, w_ih, b_ih, b_hh, eg, 2 * NH, 3072);
    zero_state<<<(NB * 1536 + 255) / 256, 256, 0, stream>>>(hbuf, cbuf, xinA);

    // ---- sequential decoder (xin double-buffered) ----
    ushort_t* xcur = xinA;
    ushort_t* xnxt = xinB;
    for (int t = 0; t < NT; ++t) {
        attn2<<<NB, NH, 0, stream>>>(xcur, KT, memv);
        step_fused<<<48, 256, 0, stream>>>(
            xcur, wcombP, eg + (size_t)t * NB * 3072, cbuf, hbuf, xnxt, HallP, t);
        ushort_t* tmp = xcur; xcur = xnxt; xnxt = tmp;
    }

    // ---- vocab projection for all 16 steps at once ----
    gemm_pipe<1><<<500, 256, 0, stream>>>(HallP, fc_w, fc_b, nullptr, out, NH, NV);

    copy_hc<<<(NB * NH + 255) / 256, 256, 0, stream>>>(hbuf, cbuf, out);
}